// Round 6
// baseline (798.930 us; speedup 1.0000x reference)
//
#include <hip/hip_runtime.h>
#include <hip/hip_bf16.h>
#include <math.h>

#define BB 8
#define NN 1024
#define KNNK 20
#define LDC 512

typedef __attribute__((ext_vector_type(8))) short bfrag8;
typedef __attribute__((ext_vector_type(4))) float facc4;

struct bh8 { __hip_bfloat16 h[8]; };

// ---------------- fp32 -> bf16 convert (8 elems/thread) ----------------
__global__ __launch_bounds__(256) void f2bf_k(const float* __restrict__ in,
                                              __hip_bfloat16* __restrict__ out, int n) {
    int i = (blockIdx.x * 256 + threadIdx.x) * 8;
    if (i >= n) return;
    float4 a = *(const float4*)(in + i);
    float4 b = *(const float4*)(in + i + 4);
    bh8 v;
    v.h[0] = __float2bfloat16(a.x); v.h[1] = __float2bfloat16(a.y);
    v.h[2] = __float2bfloat16(a.z); v.h[3] = __float2bfloat16(a.w);
    v.h[4] = __float2bfloat16(b.x); v.h[5] = __float2bfloat16(b.y);
    v.h[6] = __float2bfloat16(b.z); v.h[7] = __float2bfloat16(b.w);
    *(bh8*)(out + i) = v;
}

// ---------------- shared top-20 selection from LDS dist[16][1024] ----------------
__device__ __forceinline__ void select20_lds(const float (*dist)[1024], int q0, int w, int lane,
                                             int* __restrict__ idxout) {
    for (int qq = w * 4; qq < w * 4 + 4; qq++) {
        float d[16];
#pragma unroll
        for (int j = 0; j < 16; j++) d[j] = dist[qq][lane + 64 * j];
        for (int t = 0; t < KNNK; t++) {
            float bv = d[0]; int bj = 0;
#pragma unroll
            for (int j = 1; j < 16; j++) if (d[j] > bv) { bv = d[j]; bj = j; }
            int bm = bj * 64 + lane;
            for (int s = 1; s < 64; s <<= 1) {
                float ov = __shfl_xor(bv, s);
                int   om = __shfl_xor(bm, s);
                if (ov > bv || (ov == bv && om < bm)) { bv = ov; bm = om; }
            }
            if (lane == 0) idxout[(q0 + qq) * KNNK + t] = bm;
            if ((bm & 63) == lane) {
                int slot = bm >> 6;
#pragma unroll
                for (int j = 0; j < 16; j++) if (j == slot) d[j] = -INFINITY;
            }
        }
    }
}

// ---------------- fused kNN stage 1 (C=3): dist in LDS, never touches HBM ----------------
__global__ __launch_bounds__(256) void knn3_fused(const float* __restrict__ x,
                                                  int* __restrict__ idxout) {
    __shared__ float dist[16][1024];
    int tid = threadIdx.x;
    int q0 = blockIdx.x * 16;
    int b = q0 >> 10;
    const float* xb = x + (size_t)b * NN * 3;
    int lane = tid & 63, w = tid >> 6;
    float qx[16], qy[16], qz[16];
#pragma unroll
    for (int q = 0; q < 16; q++) {
        const float* qr = xb + (size_t)((q0 & (NN - 1)) + q) * 3;
        qx[q] = qr[0]; qy[q] = qr[1]; qz[q] = qr[2];
    }
#pragma unroll
    for (int cq = 0; cq < 4; cq++) {
        int cand = w * 256 + cq * 64 + lane;
        const float* cr = xb + (size_t)cand * 3;
        float cx = cr[0], cy = cr[1], cz = cr[2];
        float sqc = 0.f;
        sqc += cx * cx; sqc += cy * cy; sqc += cz * cz;   // same order as old sqnorm_k
#pragma unroll
        for (int q = 0; q < 16; q++) {
            float d = qx[q] * cx + qy[q] * cy + qz[q] * cz;  // same order as old dist3_k
            dist[q][cand] = 2.f * d - sqc;
        }
    }
    __syncthreads();
    select20_lds(dist, q0, w, lane, idxout);
}

// ---------------- fused kNN stages 2-4: dist in LDS ----------------
// block = 16 queries x 1024 candidates; wave w covers cands [w*256, w*256+256)
template<int C>
__global__ __launch_bounds__(256) void knn_fused(const float* __restrict__ xt, int off,
                                                 int* __restrict__ idxout) {
    __shared__ float dist[16][1024];
    __shared__ __align__(16) float qs[16][C];
    int tid = threadIdx.x;
    int q0 = blockIdx.x * 16;
    int b = q0 >> 10;
    const float* xb = xt + (size_t)b * NN * LDC + off;
    for (int j = tid; j < 16 * (C / 4); j += 256) {
        int p = j / (C / 4), c4 = j % (C / 4);
        *(float4*)&qs[p][4 * c4] = *(const float4*)(xb + (size_t)((q0 & (NN - 1)) + p) * LDC + 4 * c4);
    }
    __syncthreads();
    int lane = tid & 63, w = tid >> 6;
    float acc[4][16];
    float sq[4];
#pragma unroll
    for (int cq = 0; cq < 4; cq++) {
        sq[cq] = 0.f;
#pragma unroll
        for (int q = 0; q < 16; q++) acc[cq][q] = 0.f;
    }
    const float* rbase = xb + (size_t)(w * 256 + lane) * LDC;
    for (int c4 = 0; c4 < C / 4; c4++) {
        float4 rv[4];
#pragma unroll
        for (int cq = 0; cq < 4; cq++)
            rv[cq] = *(const float4*)(rbase + (size_t)(cq * 64) * LDC + 4 * c4);
#pragma unroll
        for (int cq = 0; cq < 4; cq++) {
            float4 v = rv[cq];
            sq[cq] += v.x * v.x;   // same element order as old sqnorm_k scalar loop
            sq[cq] += v.y * v.y;
            sq[cq] += v.z * v.z;
            sq[cq] += v.w * v.w;
        }
#pragma unroll
        for (int q = 0; q < 16; q++) {
            float4 qv = *(const float4*)&qs[q][4 * c4];
#pragma unroll
            for (int cq = 0; cq < 4; cq++)
                acc[cq][q] += rv[cq].x * qv.x + rv[cq].y * qv.y + rv[cq].z * qv.z + rv[cq].w * qv.w;
        }
    }
#pragma unroll
    for (int cq = 0; cq < 4; cq++) {
        int cand = w * 256 + cq * 64 + lane;
#pragma unroll
        for (int q = 0; q < 16; q++)
            dist[q][cand] = 2.f * acc[cq][q] - sq[cq];
    }
    __syncthreads();
    select20_lds(dist, q0, w, lane, idxout);
}

// ---------------- stage-1 z-gemm (C=3) ----------------
__global__ __launch_bounds__(256) void zgemm3_k(const float* __restrict__ x, const float* __restrict__ w1,
                                                float* __restrict__ zf) {
    int i = blockIdx.x * 256 + threadIdx.x;
    int n = i >> 7, j = i & 127;
    const float* wr = w1 + (j < 64 ? j * 6 : (j - 64) * 6 + 3);
    const float* xr = x + n * 3;
    zf[(size_t)n * 128 + j] = wr[0] * xr[0] + wr[1] * xr[1] + wr[2] * xr[2];
}

// ---------------- z-gemm: zf[n][j] = (j<O ? Wa_j : Wb_{j-O}) . x[n] ----------------
template<int C, int O2>
__global__ __launch_bounds__(256) void zgemm_k(const float* __restrict__ xt, int off,
                                               const float* __restrict__ w,
                                               float* __restrict__ zf) {
    constexpr int O = O2 / 2;
    __shared__ __align__(16) float xs[16][C];
    int p0 = blockIdx.x * 16;
    int tid = threadIdx.x;
    for (int j = tid; j < 16 * (C / 4); j += 256) {
        int p = j / (C / 4), c4 = j % (C / 4);
        *(float4*)&xs[p][4 * c4] = *(const float4*)(xt + (size_t)(p0 + p) * LDC + off + 4 * c4);
    }
    __syncthreads();
    if constexpr (O2 > 256) {
        const float* wr0 = w + (size_t)tid * 2 * C;
        const float* wr1 = wr0 + C;
        float acc0[16], acc1[16];
#pragma unroll
        for (int p = 0; p < 16; p++) { acc0[p] = 0.f; acc1[p] = 0.f; }
        for (int c4 = 0; c4 < C / 4; c4++) {
            float4 w0 = *(const float4*)(wr0 + 4 * c4);
            float4 w1v = *(const float4*)(wr1 + 4 * c4);
#pragma unroll
            for (int p = 0; p < 16; p++) {
                float4 xv = *(const float4*)&xs[p][4 * c4];
                acc0[p] += w0.x * xv.x + w0.y * xv.y + w0.z * xv.z + w0.w * xv.w;
                acc1[p] += w1v.x * xv.x + w1v.y * xv.y + w1v.z * xv.z + w1v.w * xv.w;
            }
        }
#pragma unroll
        for (int p = 0; p < 16; p++) {
            zf[(size_t)(p0 + p) * O2 + tid]       = acc0[p];
            zf[(size_t)(p0 + p) * O2 + 256 + tid] = acc1[p];
        }
    } else {
        for (int j = tid; j < O2; j += 256) {
            const float* wr = w + (j < O ? (size_t)j * 2 * C : (size_t)(j - O) * 2 * C + C);
            float acc[16];
#pragma unroll
            for (int p = 0; p < 16; p++) acc[p] = 0.f;
            for (int c4 = 0; c4 < C / 4; c4++) {
                float4 wv = *(const float4*)(wr + 4 * c4);
#pragma unroll
                for (int p = 0; p < 16; p++) {
                    float4 xv = *(const float4*)&xs[p][4 * c4];
                    acc[p] += wv.x * xv.x + wv.y * xv.y + wv.z * xv.z + wv.w * xv.w;
                }
            }
#pragma unroll
            for (int p = 0; p < 16; p++) zf[(size_t)(p0 + p) * O2 + j] = acc[p];
        }
    }
}

// ---------------- gather + stats ----------------
template<int O2>
__global__ __launch_bounds__(256) void gatherstats_k(const float* __restrict__ zf,
                                                     const int* __restrict__ idx,
                                                     float* __restrict__ ymax, float* __restrict__ ymin,
                                                     float* __restrict__ psum, float* __restrict__ psumsq) {
    constexpr int O = O2 / 2;
    int wv = threadIdx.x >> 6, lane = threadIdx.x & 63;
    int n = blockIdx.x * 4 + wv;
    int b = n >> 10;
    const float* zbatch = zf + (size_t)b * NN * O2;
    int nb[KNNK];
#pragma unroll
    for (int k = 0; k < KNNK; k++) nb[k] = idx[n * KNNK + k];
#pragma unroll
    for (int ch = 0; ch < O / 64; ch++) {
        int o = ch * 64 + lane;
        float g[KNNK];
#pragma unroll
        for (int k = 0; k < KNNK; k++) g[k] = zbatch[(size_t)nb[k] * O2 + o];
        float mx = -INFINITY, mn = INFINITY, s = 0.f, ss = 0.f;
#pragma unroll
        for (int k = 0; k < KNNK; k++) {
            float v = g[k];
            mx = fmaxf(mx, v); mn = fminf(mn, v); s += v; ss += v * v;
        }
        float zn  = zf[(size_t)n * O2 + o];
        float zbn = zf[(size_t)n * O2 + O + o];
        float d = zbn - zn;
        mx += d; mn += d;
        ss = ss + 2.f * d * s + (float)KNNK * d * d;
        s  = s + (float)KNNK * d;
        ymax  [(size_t)n * O + o] = mx;
        ymin  [(size_t)n * O + o] = mn;
        psum  [(size_t)n * O + o] = s;
        psumsq[(size_t)n * O + o] = ss;
    }
}

// ---------------- BN reduce pass 1 ----------------
__global__ __launch_bounds__(256) void bnred1_k(const float* __restrict__ pn, const float* __restrict__ pq,
                                                int O, float* __restrict__ r1s, float* __restrict__ r1q) {
    __shared__ float ls[4][64], lq[4][64];
    int lane = threadIdx.x & 63, wv = threadIdx.x >> 6;
    int o = blockIdx.x * 64 + lane;
    int n0 = blockIdx.y * 256;
    float s = 0.f, q = 0.f;
    for (int r = wv; r < 256; r += 4) {
        s += pn[(size_t)(n0 + r) * O + o];
        q += pq[(size_t)(n0 + r) * O + o];
    }
    ls[wv][lane] = s; lq[wv][lane] = q;
    __syncthreads();
    if (wv == 0) {
        s = ls[0][lane] + ls[1][lane] + ls[2][lane] + ls[3][lane];
        q = lq[0][lane] + lq[1][lane] + lq[2][lane] + lq[3][lane];
        r1s[(size_t)blockIdx.y * O + o] = s;
        r1q[(size_t)blockIdx.y * O + o] = q;
    }
}

// ---------------- BN reduce pass 2 + scale/shift ----------------
__global__ __launch_bounds__(64) void bnred2_k(const float* __restrict__ r1s, const float* __restrict__ r1q,
                                               const float* __restrict__ g, const float* __restrict__ beta,
                                               int O, double invM,
                                               float* __restrict__ s_out, float* __restrict__ t_out) {
    int o = blockIdx.x, lane = threadIdx.x;
    double s = 0.0, q = 0.0;
    if (lane < 32) { s = r1s[(size_t)lane * O + o]; q = r1q[(size_t)lane * O + o]; }
#pragma unroll
    for (int m = 1; m < 32; m <<= 1) { s += __shfl_xor(s, m); q += __shfl_xor(q, m); }
    if (lane == 0) {
        double mean = s * invM;
        double var = q * invM - mean * mean;
        float inv = (float)(1.0 / sqrt(var + 1e-5));
        float sc = g[o] * inv;
        s_out[o] = sc;
        t_out[o] = beta[o] - (float)mean * sc;
    }
}

// ---------------- BN+lrelu on max/min (monotone), write into cat buffer ----------------
template<int O>
__global__ void epilogue_k(const float* __restrict__ ymax, const float* __restrict__ ymin,
                           const float* __restrict__ s, const float* __restrict__ t,
                           float* __restrict__ xtcat, int off_out) {
    int i = blockIdx.x * blockDim.x + threadIdx.x;
    if (i >= BB * NN * O) return;
    int bn = i / O;
    int o = i & (O - 1);
    float sc = s[o];
    float v = sc >= 0.f ? ymax[i] : ymin[i];
    float y = sc * v + t[o];
    y = y >= 0.f ? y : 0.2f * y;
    xtcat[(size_t)bn * LDC + off_out + o] = y;
}

// ---------------- stage 5: bf16 MFMA GEMM w/ fused per-16-row stats ----------------
__global__ __launch_bounds__(256) void gemm5_mfma(const __hip_bfloat16* __restrict__ xbf,
                                                  const __hip_bfloat16* __restrict__ wbf,
                                                  float* __restrict__ pmax, float* __restrict__ pmn,
                                                  float* __restrict__ ps, float* __restrict__ pq) {
    __shared__ __hip_bfloat16 A[128][72];
    __shared__ __hip_bfloat16 W[128][72];
    int mt = blockIdx.x >> 2, nt = blockIdx.x & 3;
    int tid = threadIdx.x;
    int lane = tid & 63, wvx = tid >> 6;
    int mw = wvx >> 1, nw = wvx & 1;
    int m0 = lane & 15, qd = lane >> 4;
    int r = tid & 127, hf = tid >> 7;
    facc4 acc[4][4];
    facc4 zz = {0.f, 0.f, 0.f, 0.f};
#pragma unroll
    for (int mi = 0; mi < 4; mi++)
#pragma unroll
        for (int ni = 0; ni < 4; ni++) acc[mi][ni] = zz;
    for (int kc = 0; kc < 8; kc++) {
        const __hip_bfloat16* ap = xbf + (size_t)(mt * 128 + r) * 512 + kc * 64 + hf * 32;
        const __hip_bfloat16* wp = wbf + (size_t)(nt * 128 + r) * 512 + kc * 64 + hf * 32;
#pragma unroll
        for (int u = 0; u < 4; u++) {
            bh8 av = *(const bh8*)(ap + 8 * u);
            bh8 wv = *(const bh8*)(wp + 8 * u);
            *(bh8*)&A[r][hf * 32 + 8 * u] = av;
            *(bh8*)&W[r][hf * 32 + 8 * u] = wv;
        }
        __syncthreads();
#pragma unroll
        for (int kk = 0; kk < 2; kk++) {
            bfrag8 af[4], bf[4];
#pragma unroll
            for (int mi = 0; mi < 4; mi++)
                af[mi] = *(const bfrag8*)&A[64 * mw + 16 * mi + m0][32 * kk + 8 * qd];
#pragma unroll
            for (int ni = 0; ni < 4; ni++)
                bf[ni] = *(const bfrag8*)&W[64 * nw + 16 * ni + m0][32 * kk + 8 * qd];
#pragma unroll
            for (int mi = 0; mi < 4; mi++)
#pragma unroll
                for (int ni = 0; ni < 4; ni++)
                    acc[mi][ni] = __builtin_amdgcn_mfma_f32_16x16x32_bf16(af[mi], bf[ni], acc[mi][ni], 0, 0, 0);
        }
        __syncthreads();
    }
#pragma unroll
    for (int mi = 0; mi < 4; mi++) {
        int grp = mt * 8 + mw * 4 + mi;
#pragma unroll
        for (int ni = 0; ni < 4; ni++) {
            float mx = -INFINITY, mn = INFINITY, s = 0.f, ss = 0.f;
#pragma unroll
            for (int rg = 0; rg < 4; rg++) {
                float v = acc[mi][ni][rg];
                mx = fmaxf(mx, v); mn = fminf(mn, v); s += v; ss += v * v;
            }
#pragma unroll
            for (int m = 16; m < 64; m <<= 1) {
                mx = fmaxf(mx, __shfl_xor(mx, m));
                mn = fminf(mn, __shfl_xor(mn, m));
                s += __shfl_xor(s, m);
                ss += __shfl_xor(ss, m);
            }
            if (qd == 0) {
                int o = nt * 128 + nw * 64 + ni * 16 + m0;
                pmax[(size_t)grp * 512 + o] = mx;
                pmn [(size_t)grp * 512 + o] = mn;
                ps  [(size_t)grp * 512 + o] = s;
                pq  [(size_t)grp * 512 + o] = ss;
            }
        }
    }
}

// ---------------- stage-5 BN stats from the 512 per-group partials ----------------
__global__ __launch_bounds__(256) void bnstat5_k(const float* __restrict__ ps, const float* __restrict__ pq,
                                                 const float* __restrict__ g, const float* __restrict__ beta,
                                                 float* __restrict__ s_out, float* __restrict__ t_out) {
    __shared__ double lds_s[4][64], lds_q[4][64];
    int lane = threadIdx.x & 63, wv = threadIdx.x >> 6;
    int o = blockIdx.x * 64 + lane;
    double s = 0.0, q = 0.0;
    for (int r = wv; r < 512; r += 4) {
        s += ps[(size_t)r * 512 + o];
        q += pq[(size_t)r * 512 + o];
    }
    lds_s[wv][lane] = s; lds_q[wv][lane] = q;
    __syncthreads();
    if (wv == 0) {
        s = lds_s[0][lane] + lds_s[1][lane] + lds_s[2][lane] + lds_s[3][lane];
        q = lds_q[0][lane] + lds_q[1][lane] + lds_q[2][lane] + lds_q[3][lane];
        double invM = 1.0 / (BB * NN);
        double mean = s * invM;
        double var = q * invM - mean * mean;
        float inv = (float)(1.0 / sqrt(var + 1e-5));
        float sc = g[o] * inv;
        s_out[o] = sc;
        t_out[o] = beta[o] - (float)mean * sc;
    }
}

// ---------------- per-batch max/min reduce + BN + lrelu + feat @ wemb^T ----------------
__global__ __launch_bounds__(256) void featgemm_k(const float* __restrict__ pmax, const float* __restrict__ pmn,
                                                  const float* __restrict__ s, const float* __restrict__ t,
                                                  const float* __restrict__ wemb, float* __restrict__ out) {
    __shared__ __align__(16) float feat[512];
    int b = blockIdx.x, tid = threadIdx.x;
    for (int o = tid; o < 512; o += 256) {
        float mx = -INFINITY, mn = INFINITY;
        for (int r = b * 64; r < (b + 1) * 64; r++) {
            mx = fmaxf(mx, pmax[(size_t)r * 512 + o]);
            mn = fminf(mn, pmn [(size_t)r * 512 + o]);
        }
        float sc = s[o];
        float v = sc >= 0.f ? mx : mn;
        float y = sc * v + t[o];
        feat[o] = y >= 0.f ? y : 0.2f * y;
    }
    __syncthreads();
    const float4* wr = (const float4*)(wemb + (size_t)tid * 512);
    float acc = 0.f;
    for (int c4 = 0; c4 < 128; c4++) {
        float4 wv = wr[c4];
        float4 fv = *(const float4*)&feat[c4 * 4];
        acc += wv.x * fv.x + wv.y * fv.y + wv.z * fv.z + wv.w * fv.w;
    }
    out[(size_t)b * 256 + tid] = acc;
}

extern "C" void kernel_launch(void* const* d_in, const int* in_sizes, int n_in,
                              void* d_out, int out_size, void* d_ws, size_t ws_size,
                              hipStream_t stream) {
    const float* x    = (const float*)d_in[0];
    const float* w1   = (const float*)d_in[1];
    const float* g1   = (const float*)d_in[2];
    const float* b1   = (const float*)d_in[3];
    const float* w2   = (const float*)d_in[4];
    const float* g2   = (const float*)d_in[5];
    const float* b2   = (const float*)d_in[6];
    const float* w3   = (const float*)d_in[7];
    const float* g3   = (const float*)d_in[8];
    const float* b3   = (const float*)d_in[9];
    const float* w4   = (const float*)d_in[10];
    const float* g4   = (const float*)d_in[11];
    const float* b4   = (const float*)d_in[12];
    const float* w5   = (const float*)d_in[13];
    const float* g5   = (const float*)d_in[14];
    const float* b5   = (const float*)d_in[15];
    const float* wemb = (const float*)d_in[16];
    float* out = (float*)d_out;

    float* fws    = (float*)d_ws;
    float* xtcat  = fws;                                 // 4,194,304
    float* ymax   = xtcat + (size_t)BB * NN * 512;       // 2,097,152
    float* ymin   = ymax + (size_t)BB * NN * 256;        // 2,097,152
    float* psum   = ymin + (size_t)BB * NN * 256;        // 2,097,152
    float* psumsq = psum + (size_t)BB * NN * 256;        // 2,097,152
    float* pmax   = ymax;                                // alias: stage-5 partials, 512*512 each
    float* pmn    = pmax + 512 * 512;
    float* ps5    = pmn + 512 * 512;
    float* pq5    = ps5 + 512 * 512;
    float* sqn    = psumsq + (size_t)BB * NN * 256;      // 8192 (unused now)
    float* s_arr  = sqn + BB * NN;                       // 512
    float* t_arr  = s_arr + 512;                         // 512
    float* r1s    = t_arr + 512;                         // 32*512
    float* r1q    = r1s + 32 * 512;                      // 32*512
    int*   idxb   = (int*)(r1q + 32 * 512);              // 8192*20 ints
    float* zfull  = (float*)(idxb + BB * NN * KNNK);     // 8192*512
    __hip_bfloat16* xbf  = (__hip_bfloat16*)(zfull + (size_t)BB * NN * 512);  // 8192*512 bf16
    __hip_bfloat16* w5bf = xbf + (size_t)BB * NN * 512;                       // 512*512 bf16

    const double invM_edge = 1.0 / ((double)BB * NN * KNNK);
    const int nbn = BB * NN;

    // ---- Stage 1: in = x (B,N,3), out ch [0,64) ----
    knn3_fused<<<nbn / 16, 256, 0, stream>>>(x, idxb);
    zgemm3_k<<<nbn * 128 / 256, 256, 0, stream>>>(x, w1, zfull);
    gatherstats_k<128><<<nbn / 4, 256, 0, stream>>>(zfull, idxb, ymax, ymin, psum, psumsq);
    bnred1_k<<<dim3(1, 32), 256, 0, stream>>>(psum, psumsq, 64, r1s, r1q);
    bnred2_k<<<64, 64, 0, stream>>>(r1s, r1q, g1, b1, 64, invM_edge, s_arr, t_arr);
    epilogue_k<64><<<(nbn * 64 + 255) / 256, 256, 0, stream>>>(ymax, ymin, s_arr, t_arr, xtcat, 0);

    // ---- Stage 2: in ch [0,64), out [64,128) ----
    knn_fused<64><<<nbn / 16, 256, 0, stream>>>(xtcat, 0, idxb);
    zgemm_k<64, 128><<<nbn / 16, 256, 0, stream>>>(xtcat, 0, w2, zfull);
    gatherstats_k<128><<<nbn / 4, 256, 0, stream>>>(zfull, idxb, ymax, ymin, psum, psumsq);
    bnred1_k<<<dim3(1, 32), 256, 0, stream>>>(psum, psumsq, 64, r1s, r1q);
    bnred2_k<<<64, 64, 0, stream>>>(r1s, r1q, g2, b2, 64, invM_edge, s_arr, t_arr);
    epilogue_k<64><<<(nbn * 64 + 255) / 256, 256, 0, stream>>>(ymax, ymin, s_arr, t_arr, xtcat, 64);

    // ---- Stage 3: in ch [64,128), out [128,256) ----
    knn_fused<64><<<nbn / 16, 256, 0, stream>>>(xtcat, 64, idxb);
    zgemm_k<64, 256><<<nbn / 16, 256, 0, stream>>>(xtcat, 64, w3, zfull);
    gatherstats_k<256><<<nbn / 4, 256, 0, stream>>>(zfull, idxb, ymax, ymin, psum, psumsq);
    bnred1_k<<<dim3(2, 32), 256, 0, stream>>>(psum, psumsq, 128, r1s, r1q);
    bnred2_k<<<128, 64, 0, stream>>>(r1s, r1q, g3, b3, 128, invM_edge, s_arr, t_arr);
    epilogue_k<128><<<(nbn * 128 + 255) / 256, 256, 0, stream>>>(ymax, ymin, s_arr, t_arr, xtcat, 128);

    // ---- Stage 4: in ch [128,256), out [256,512) ----
    knn_fused<128><<<nbn / 16, 256, 0, stream>>>(xtcat, 128, idxb);
    zgemm_k<128, 512><<<nbn / 16, 256, 0, stream>>>(xtcat, 128, w4, zfull);
    gatherstats_k<512><<<nbn / 4, 256, 0, stream>>>(zfull, idxb, ymax, ymin, psum, psumsq);
    bnred1_k<<<dim3(4, 32), 256, 0, stream>>>(psum, psumsq, 256, r1s, r1q);
    bnred2_k<<<256, 64, 0, stream>>>(r1s, r1q, g4, b4, 256, invM_edge, s_arr, t_arr);
    epilogue_k<256><<<(nbn * 256 + 255) / 256, 256, 0, stream>>>(ymax, ymin, s_arr, t_arr, xtcat, 256);

    // ---- Stage 5: bf16 converts, MFMA GEMM+stats, tiny reductions ----
    f2bf_k<<<512 * 512 / (256 * 8), 256, 0, stream>>>(w5, w5bf, 512 * 512);
    f2bf_k<<<nbn * 512 / (256 * 8), 256, 0, stream>>>(xtcat, xbf, nbn * 512);
    gemm5_mfma<<<256, 256, 0, stream>>>(xbf, w5bf, pmax, pmn, ps5, pq5);
    bnstat5_k<<<8, 256, 0, stream>>>(ps5, pq5, g5, b5, s_arr, t_arr);
    featgemm_k<<<BB, 256, 0, stream>>>(pmax, pmn, s_arr, t_arr, wemb, out);
}

// Round 7
// 742.548 us; speedup vs baseline: 1.0759x; 1.0759x over previous
//
#include <hip/hip_runtime.h>
#include <hip/hip_bf16.h>
#include <math.h>

#define BB 8
#define NN 1024
#define KNNK 20
#define LDC 512

typedef __attribute__((ext_vector_type(8))) short bfrag8;
typedef __attribute__((ext_vector_type(4))) float facc4;

struct bh8 { __hip_bfloat16 h[8]; };

// ---------------- fp32 -> bf16 convert (8 elems/thread) ----------------
__global__ __launch_bounds__(256) void f2bf_k(const float* __restrict__ in,
                                              __hip_bfloat16* __restrict__ out, int n) {
    int i = (blockIdx.x * 256 + threadIdx.x) * 8;
    if (i >= n) return;
    float4 a = *(const float4*)(in + i);
    float4 b = *(const float4*)(in + i + 4);
    bh8 v;
    v.h[0] = __float2bfloat16(a.x); v.h[1] = __float2bfloat16(a.y);
    v.h[2] = __float2bfloat16(a.z); v.h[3] = __float2bfloat16(a.w);
    v.h[4] = __float2bfloat16(b.x); v.h[5] = __float2bfloat16(b.y);
    v.h[6] = __float2bfloat16(b.z); v.h[7] = __float2bfloat16(b.w);
    *(bh8*)(out + i) = v;
}

// ---------------- per-stage transpose: xtcat[b][n][off+c] -> xT[b][c][n] ----------------
template<int C>
__global__ __launch_bounds__(256) void transpose_k(const float* __restrict__ xt, int off,
                                                   float* __restrict__ xT) {
    __shared__ float tile[64][65];
    int nt = blockIdx.x;                 // 128 n-tiles (8192/64)
    int ct = blockIdx.y;                 // C/64 c-tiles
    int n_glob = nt * 64;
    int b = n_glob >> 10;
    int c0 = ct * 64;
    int t = threadIdx.x;
    int r = t >> 4, cq = t & 15;
#pragma unroll
    for (int i = 0; i < 4; i++) {
        int row = i * 16 + r;
        float4 v = *(const float4*)(xt + (size_t)(n_glob + row) * LDC + off + c0 + 4 * cq);
        tile[row][4 * cq + 0] = v.x; tile[row][4 * cq + 1] = v.y;
        tile[row][4 * cq + 2] = v.z; tile[row][4 * cq + 3] = v.w;
    }
    __syncthreads();
#pragma unroll
    for (int i = 0; i < 4; i++) {
        int c = i * 16 + r;
        float4 o;
        o.x = tile[4 * cq + 0][c]; o.y = tile[4 * cq + 1][c];
        o.z = tile[4 * cq + 2][c]; o.w = tile[4 * cq + 3][c];
        *(float4*)(xT + ((size_t)b * C + c0 + c) * 1024 + (n_glob & (NN - 1)) + 4 * cq) = o;
    }
}

// ---------------- top-20 selection, 4 interleaved query chains per wave ----------------
__device__ __forceinline__ void select20_x4(const float (*dist)[1024], int q0, int w, int lane,
                                            int* __restrict__ idxout) {
    float d[4][16];
#pragma unroll
    for (int qi = 0; qi < 4; qi++)
#pragma unroll
        for (int j = 0; j < 16; j++) d[qi][j] = dist[w * 4 + qi][lane + 64 * j];
    for (int t = 0; t < KNNK; t++) {
#pragma unroll
        for (int qi = 0; qi < 4; qi++) {
            float bv = d[qi][0]; int bj = 0;
#pragma unroll
            for (int j = 1; j < 16; j++) if (d[qi][j] > bv) { bv = d[qi][j]; bj = j; }
            int bm = bj * 64 + lane;
#pragma unroll
            for (int s = 1; s < 64; s <<= 1) {
                float ov = __shfl_xor(bv, s);
                int   om = __shfl_xor(bm, s);
                if (ov > bv || (ov == bv && om < bm)) { bv = ov; bm = om; }
            }
            if (lane == 0) idxout[(q0 + w * 4 + qi) * KNNK + t] = bm;
            if ((bm & 63) == lane) {
                int slot = bm >> 6;
#pragma unroll
                for (int j = 0; j < 16; j++) if (j == slot) d[qi][j] = -INFINITY;
            }
        }
    }
}

// ---------------- fused kNN stage 1 (C=3) ----------------
__global__ __launch_bounds__(256) void knn3_fused(const float* __restrict__ x,
                                                  int* __restrict__ idxout) {
    __shared__ float dist[16][1024];
    int tid = threadIdx.x;
    int q0 = blockIdx.x * 16;
    int b = q0 >> 10;
    const float* xb = x + (size_t)b * NN * 3;
    int lane = tid & 63, w = tid >> 6;
    float qx[16], qy[16], qz[16];
#pragma unroll
    for (int q = 0; q < 16; q++) {
        const float* qr = xb + (size_t)((q0 & (NN - 1)) + q) * 3;
        qx[q] = qr[0]; qy[q] = qr[1]; qz[q] = qr[2];
    }
#pragma unroll
    for (int cq = 0; cq < 4; cq++) {
        int cand = w * 256 + cq * 64 + lane;
        const float* cr = xb + (size_t)cand * 3;
        float cx = cr[0], cy = cr[1], cz = cr[2];
        float sqc = 0.f;
        sqc += cx * cx; sqc += cy * cy; sqc += cz * cz;
#pragma unroll
        for (int q = 0; q < 16; q++) {
            float d = qx[q] * cx + qy[q] * cy + qz[q] * cz;
            dist[q][cand] = 2.f * d - sqc;
        }
    }
    __syncthreads();
    select20_x4(dist, q0, w, lane, idxout);
}

// ---------------- fused kNN stages 2-4: coalesced candidate loads from xT ----------------
// block = 16 queries x 1024 candidates; lane owns 4 consecutive candidates
template<int C>
__global__ __launch_bounds__(256) void knn_fused(const float* __restrict__ xT,
                                                 const float* __restrict__ xt, int off,
                                                 int* __restrict__ idxout) {
    __shared__ float dist[16][1024];
    __shared__ __align__(16) float qs[16][C];
    int tid = threadIdx.x;
    int q0 = blockIdx.x * 16;
    int b = q0 >> 10;
    const float* xb = xt + (size_t)b * NN * LDC + off;
    for (int j = tid; j < 16 * (C / 4); j += 256) {
        int p = j / (C / 4), c4 = j % (C / 4);
        *(float4*)&qs[p][4 * c4] = *(const float4*)(xb + (size_t)((q0 & (NN - 1)) + p) * LDC + 4 * c4);
    }
    __syncthreads();
    int lane = tid & 63, w = tid >> 6;
    int cand0 = w * 256 + 4 * lane;
    const float* xTb = xT + (size_t)b * C * 1024;
    float acc[4][16];
    float sq[4] = {0.f, 0.f, 0.f, 0.f};
#pragma unroll
    for (int j = 0; j < 4; j++)
#pragma unroll
        for (int q = 0; q < 16; q++) acc[j][q] = 0.f;
    for (int cg = 0; cg < C / 4; cg++) {
        float4 r0 = *(const float4*)(xTb + (size_t)(4 * cg + 0) * 1024 + cand0);
        float4 r1 = *(const float4*)(xTb + (size_t)(4 * cg + 1) * 1024 + cand0);
        float4 r2 = *(const float4*)(xTb + (size_t)(4 * cg + 2) * 1024 + cand0);
        float4 r3 = *(const float4*)(xTb + (size_t)(4 * cg + 3) * 1024 + cand0);
        // rc[j][ch]: candidate j's 4 consecutive channels (same 4-wide grouping as round-6)
        float rc[4][4] = {{r0.x, r1.x, r2.x, r3.x}, {r0.y, r1.y, r2.y, r3.y},
                          {r0.z, r1.z, r2.z, r3.z}, {r0.w, r1.w, r2.w, r3.w}};
#pragma unroll
        for (int j = 0; j < 4; j++) {
            sq[j] += rc[j][0] * rc[j][0];
            sq[j] += rc[j][1] * rc[j][1];
            sq[j] += rc[j][2] * rc[j][2];
            sq[j] += rc[j][3] * rc[j][3];
        }
#pragma unroll
        for (int q = 0; q < 16; q++) {
            float4 qv = *(const float4*)&qs[q][4 * cg];
#pragma unroll
            for (int j = 0; j < 4; j++)
                acc[j][q] += rc[j][0] * qv.x + rc[j][1] * qv.y + rc[j][2] * qv.z + rc[j][3] * qv.w;
        }
    }
#pragma unroll
    for (int q = 0; q < 16; q++) {
        float4 dv;
        dv.x = 2.f * acc[0][q] - sq[0];
        dv.y = 2.f * acc[1][q] - sq[1];
        dv.z = 2.f * acc[2][q] - sq[2];
        dv.w = 2.f * acc[3][q] - sq[3];
        *(float4*)&dist[q][cand0] = dv;
    }
    __syncthreads();
    select20_x4(dist, q0, w, lane, idxout);
}

// ---------------- stage-1 z-gemm (C=3) ----------------
__global__ __launch_bounds__(256) void zgemm3_k(const float* __restrict__ x, const float* __restrict__ w1,
                                                float* __restrict__ zf) {
    int i = blockIdx.x * 256 + threadIdx.x;
    int n = i >> 7, j = i & 127;
    const float* wr = w1 + (j < 64 ? j * 6 : (j - 64) * 6 + 3);
    const float* xr = x + n * 3;
    zf[(size_t)n * 128 + j] = wr[0] * xr[0] + wr[1] * xr[1] + wr[2] * xr[2];
}

// ---------------- z-gemm: zf[n][j] = (j<O ? Wa_j : Wb_{j-O}) . x[n] ----------------
template<int C, int O2>
__global__ __launch_bounds__(256) void zgemm_k(const float* __restrict__ xt, int off,
                                               const float* __restrict__ w,
                                               float* __restrict__ zf) {
    constexpr int O = O2 / 2;
    __shared__ __align__(16) float xs[16][C];
    int p0 = blockIdx.x * 16;
    int tid = threadIdx.x;
    for (int j = tid; j < 16 * (C / 4); j += 256) {
        int p = j / (C / 4), c4 = j % (C / 4);
        *(float4*)&xs[p][4 * c4] = *(const float4*)(xt + (size_t)(p0 + p) * LDC + off + 4 * c4);
    }
    __syncthreads();
    if constexpr (O2 > 256) {
        const float* wr0 = w + (size_t)tid * 2 * C;
        const float* wr1 = wr0 + C;
        float acc0[16], acc1[16];
#pragma unroll
        for (int p = 0; p < 16; p++) { acc0[p] = 0.f; acc1[p] = 0.f; }
        for (int c4 = 0; c4 < C / 4; c4++) {
            float4 w0 = *(const float4*)(wr0 + 4 * c4);
            float4 w1v = *(const float4*)(wr1 + 4 * c4);
#pragma unroll
            for (int p = 0; p < 16; p++) {
                float4 xv = *(const float4*)&xs[p][4 * c4];
                acc0[p] += w0.x * xv.x + w0.y * xv.y + w0.z * xv.z + w0.w * xv.w;
                acc1[p] += w1v.x * xv.x + w1v.y * xv.y + w1v.z * xv.z + w1v.w * xv.w;
            }
        }
#pragma unroll
        for (int p = 0; p < 16; p++) {
            zf[(size_t)(p0 + p) * O2 + tid]       = acc0[p];
            zf[(size_t)(p0 + p) * O2 + 256 + tid] = acc1[p];
        }
    } else {
        for (int j = tid; j < O2; j += 256) {
            const float* wr = w + (j < O ? (size_t)j * 2 * C : (size_t)(j - O) * 2 * C + C);
            float acc[16];
#pragma unroll
            for (int p = 0; p < 16; p++) acc[p] = 0.f;
            for (int c4 = 0; c4 < C / 4; c4++) {
                float4 wv = *(const float4*)(wr + 4 * c4);
#pragma unroll
                for (int p = 0; p < 16; p++) {
                    float4 xv = *(const float4*)&xs[p][4 * c4];
                    acc[p] += wv.x * xv.x + wv.y * xv.y + wv.z * xv.z + wv.w * xv.w;
                }
            }
#pragma unroll
            for (int p = 0; p < 16; p++) zf[(size_t)(p0 + p) * O2 + j] = acc[p];
        }
    }
}

// ---------------- gather + stats ----------------
template<int O2>
__global__ __launch_bounds__(256) void gatherstats_k(const float* __restrict__ zf,
                                                     const int* __restrict__ idx,
                                                     float* __restrict__ ymax, float* __restrict__ ymin,
                                                     float* __restrict__ psum, float* __restrict__ psumsq) {
    constexpr int O = O2 / 2;
    int wv = threadIdx.x >> 6, lane = threadIdx.x & 63;
    int n = blockIdx.x * 4 + wv;
    int b = n >> 10;
    const float* zbatch = zf + (size_t)b * NN * O2;
    int nb[KNNK];
#pragma unroll
    for (int k = 0; k < KNNK; k++) nb[k] = idx[n * KNNK + k];
#pragma unroll
    for (int ch = 0; ch < O / 64; ch++) {
        int o = ch * 64 + lane;
        float g[KNNK];
#pragma unroll
        for (int k = 0; k < KNNK; k++) g[k] = zbatch[(size_t)nb[k] * O2 + o];
        float mx = -INFINITY, mn = INFINITY, s = 0.f, ss = 0.f;
#pragma unroll
        for (int k = 0; k < KNNK; k++) {
            float v = g[k];
            mx = fmaxf(mx, v); mn = fminf(mn, v); s += v; ss += v * v;
        }
        float zn  = zf[(size_t)n * O2 + o];
        float zbn = zf[(size_t)n * O2 + O + o];
        float d = zbn - zn;
        mx += d; mn += d;
        ss = ss + 2.f * d * s + (float)KNNK * d * d;
        s  = s + (float)KNNK * d;
        ymax  [(size_t)n * O + o] = mx;
        ymin  [(size_t)n * O + o] = mn;
        psum  [(size_t)n * O + o] = s;
        psumsq[(size_t)n * O + o] = ss;
    }
}

// ---------------- BN reduce pass 1 ----------------
__global__ __launch_bounds__(256) void bnred1_k(const float* __restrict__ pn, const float* __restrict__ pq,
                                                int O, float* __restrict__ r1s, float* __restrict__ r1q) {
    __shared__ float ls[4][64], lq[4][64];
    int lane = threadIdx.x & 63, wv = threadIdx.x >> 6;
    int o = blockIdx.x * 64 + lane;
    int n0 = blockIdx.y * 256;
    float s = 0.f, q = 0.f;
    for (int r = wv; r < 256; r += 4) {
        s += pn[(size_t)(n0 + r) * O + o];
        q += pq[(size_t)(n0 + r) * O + o];
    }
    ls[wv][lane] = s; lq[wv][lane] = q;
    __syncthreads();
    if (wv == 0) {
        s = ls[0][lane] + ls[1][lane] + ls[2][lane] + ls[3][lane];
        q = lq[0][lane] + lq[1][lane] + lq[2][lane] + lq[3][lane];
        r1s[(size_t)blockIdx.y * O + o] = s;
        r1q[(size_t)blockIdx.y * O + o] = q;
    }
}

// ---------------- BN reduce pass 2 + scale/shift ----------------
__global__ __launch_bounds__(64) void bnred2_k(const float* __restrict__ r1s, const float* __restrict__ r1q,
                                               const float* __restrict__ g, const float* __restrict__ beta,
                                               int O, double invM,
                                               float* __restrict__ s_out, float* __restrict__ t_out) {
    int o = blockIdx.x, lane = threadIdx.x;
    double s = 0.0, q = 0.0;
    if (lane < 32) { s = r1s[(size_t)lane * O + o]; q = r1q[(size_t)lane * O + o]; }
#pragma unroll
    for (int m = 1; m < 32; m <<= 1) { s += __shfl_xor(s, m); q += __shfl_xor(q, m); }
    if (lane == 0) {
        double mean = s * invM;
        double var = q * invM - mean * mean;
        float inv = (float)(1.0 / sqrt(var + 1e-5));
        float sc = g[o] * inv;
        s_out[o] = sc;
        t_out[o] = beta[o] - (float)mean * sc;
    }
}

// ---------------- BN+lrelu on max/min (monotone), write into cat buffer ----------------
template<int O>
__global__ void epilogue_k(const float* __restrict__ ymax, const float* __restrict__ ymin,
                           const float* __restrict__ s, const float* __restrict__ t,
                           float* __restrict__ xtcat, int off_out) {
    int i = blockIdx.x * blockDim.x + threadIdx.x;
    if (i >= BB * NN * O) return;
    int bn = i / O;
    int o = i & (O - 1);
    float sc = s[o];
    float v = sc >= 0.f ? ymax[i] : ymin[i];
    float y = sc * v + t[o];
    y = y >= 0.f ? y : 0.2f * y;
    xtcat[(size_t)bn * LDC + off_out + o] = y;
}

// ---------------- stage 5: bf16 MFMA GEMM w/ fused per-16-row stats ----------------
__global__ __launch_bounds__(256) void gemm5_mfma(const __hip_bfloat16* __restrict__ xbf,
                                                  const __hip_bfloat16* __restrict__ wbf,
                                                  float* __restrict__ pmax, float* __restrict__ pmn,
                                                  float* __restrict__ ps, float* __restrict__ pq) {
    __shared__ __hip_bfloat16 A[128][72];
    __shared__ __hip_bfloat16 W[128][72];
    int mt = blockIdx.x >> 2, nt = blockIdx.x & 3;
    int tid = threadIdx.x;
    int lane = tid & 63, wvx = tid >> 6;
    int mw = wvx >> 1, nw = wvx & 1;
    int m0 = lane & 15, qd = lane >> 4;
    int r = tid & 127, hf = tid >> 7;
    facc4 acc[4][4];
    facc4 zz = {0.f, 0.f, 0.f, 0.f};
#pragma unroll
    for (int mi = 0; mi < 4; mi++)
#pragma unroll
        for (int ni = 0; ni < 4; ni++) acc[mi][ni] = zz;
    for (int kc = 0; kc < 8; kc++) {
        const __hip_bfloat16* ap = xbf + (size_t)(mt * 128 + r) * 512 + kc * 64 + hf * 32;
        const __hip_bfloat16* wp = wbf + (size_t)(nt * 128 + r) * 512 + kc * 64 + hf * 32;
#pragma unroll
        for (int u = 0; u < 4; u++) {
            bh8 av = *(const bh8*)(ap + 8 * u);
            bh8 wv = *(const bh8*)(wp + 8 * u);
            *(bh8*)&A[r][hf * 32 + 8 * u] = av;
            *(bh8*)&W[r][hf * 32 + 8 * u] = wv;
        }
        __syncthreads();
#pragma unroll
        for (int kk = 0; kk < 2; kk++) {
            bfrag8 af[4], bf[4];
#pragma unroll
            for (int mi = 0; mi < 4; mi++)
                af[mi] = *(const bfrag8*)&A[64 * mw + 16 * mi + m0][32 * kk + 8 * qd];
#pragma unroll
            for (int ni = 0; ni < 4; ni++)
                bf[ni] = *(const bfrag8*)&W[64 * nw + 16 * ni + m0][32 * kk + 8 * qd];
#pragma unroll
            for (int mi = 0; mi < 4; mi++)
#pragma unroll
                for (int ni = 0; ni < 4; ni++)
                    acc[mi][ni] = __builtin_amdgcn_mfma_f32_16x16x32_bf16(af[mi], bf[ni], acc[mi][ni], 0, 0, 0);
        }
        __syncthreads();
    }
#pragma unroll
    for (int mi = 0; mi < 4; mi++) {
        int grp = mt * 8 + mw * 4 + mi;
#pragma unroll
        for (int ni = 0; ni < 4; ni++) {
            float mx = -INFINITY, mn = INFINITY, s = 0.f, ss = 0.f;
#pragma unroll
            for (int rg = 0; rg < 4; rg++) {
                float v = acc[mi][ni][rg];
                mx = fmaxf(mx, v); mn = fminf(mn, v); s += v; ss += v * v;
            }
#pragma unroll
            for (int m = 16; m < 64; m <<= 1) {
                mx = fmaxf(mx, __shfl_xor(mx, m));
                mn = fminf(mn, __shfl_xor(mn, m));
                s += __shfl_xor(s, m);
                ss += __shfl_xor(ss, m);
            }
            if (qd == 0) {
                int o = nt * 128 + nw * 64 + ni * 16 + m0;
                pmax[(size_t)grp * 512 + o] = mx;
                pmn [(size_t)grp * 512 + o] = mn;
                ps  [(size_t)grp * 512 + o] = s;
                pq  [(size_t)grp * 512 + o] = ss;
            }
        }
    }
}

// ---------------- stage-5 BN stats from the 512 per-group partials ----------------
__global__ __launch_bounds__(256) void bnstat5_k(const float* __restrict__ ps, const float* __restrict__ pq,
                                                 const float* __restrict__ g, const float* __restrict__ beta,
                                                 float* __restrict__ s_out, float* __restrict__ t_out) {
    __shared__ double lds_s[4][64], lds_q[4][64];
    int lane = threadIdx.x & 63, wv = threadIdx.x >> 6;
    int o = blockIdx.x * 64 + lane;
    double s = 0.0, q = 0.0;
    for (int r = wv; r < 512; r += 4) {
        s += ps[(size_t)r * 512 + o];
        q += pq[(size_t)r * 512 + o];
    }
    lds_s[wv][lane] = s; lds_q[wv][lane] = q;
    __syncthreads();
    if (wv == 0) {
        s = lds_s[0][lane] + lds_s[1][lane] + lds_s[2][lane] + lds_s[3][lane];
        q = lds_q[0][lane] + lds_q[1][lane] + lds_q[2][lane] + lds_q[3][lane];
        double invM = 1.0 / (BB * NN);
        double mean = s * invM;
        double var = q * invM - mean * mean;
        float inv = (float)(1.0 / sqrt(var + 1e-5));
        float sc = g[o] * inv;
        s_out[o] = sc;
        t_out[o] = beta[o] - (float)mean * sc;
    }
}

// ---------------- per-batch max/min reduce + BN + lrelu + feat @ wemb^T ----------------
__global__ __launch_bounds__(256) void featgemm_k(const float* __restrict__ pmax, const float* __restrict__ pmn,
                                                  const float* __restrict__ s, const float* __restrict__ t,
                                                  const float* __restrict__ wemb, float* __restrict__ out) {
    __shared__ __align__(16) float feat[512];
    int b = blockIdx.x, tid = threadIdx.x;
    for (int o = tid; o < 512; o += 256) {
        float mx = -INFINITY, mn = INFINITY;
        for (int r = b * 64; r < (b + 1) * 64; r++) {
            mx = fmaxf(mx, pmax[(size_t)r * 512 + o]);
            mn = fminf(mn, pmn [(size_t)r * 512 + o]);
        }
        float sc = s[o];
        float v = sc >= 0.f ? mx : mn;
        float y = sc * v + t[o];
        feat[o] = y >= 0.f ? y : 0.2f * y;
    }
    __syncthreads();
    const float4* wr = (const float4*)(wemb + (size_t)tid * 512);
    float acc = 0.f;
    for (int c4 = 0; c4 < 128; c4++) {
        float4 wv = wr[c4];
        float4 fv = *(const float4*)&feat[c4 * 4];
        acc += wv.x * fv.x + wv.y * fv.y + wv.z * fv.z + wv.w * fv.w;
    }
    out[(size_t)b * 256 + tid] = acc;
}

extern "C" void kernel_launch(void* const* d_in, const int* in_sizes, int n_in,
                              void* d_out, int out_size, void* d_ws, size_t ws_size,
                              hipStream_t stream) {
    const float* x    = (const float*)d_in[0];
    const float* w1   = (const float*)d_in[1];
    const float* g1   = (const float*)d_in[2];
    const float* b1   = (const float*)d_in[3];
    const float* w2   = (const float*)d_in[4];
    const float* g2   = (const float*)d_in[5];
    const float* b2   = (const float*)d_in[6];
    const float* w3   = (const float*)d_in[7];
    const float* g3   = (const float*)d_in[8];
    const float* b3   = (const float*)d_in[9];
    const float* w4   = (const float*)d_in[10];
    const float* g4   = (const float*)d_in[11];
    const float* b4   = (const float*)d_in[12];
    const float* w5   = (const float*)d_in[13];
    const float* g5   = (const float*)d_in[14];
    const float* b5   = (const float*)d_in[15];
    const float* wemb = (const float*)d_in[16];
    float* out = (float*)d_out;

    float* fws    = (float*)d_ws;
    float* xtcat  = fws;                                 // 4,194,304
    float* ymax   = xtcat + (size_t)BB * NN * 512;       // 2,097,152
    float* ymin   = ymax + (size_t)BB * NN * 256;        // 2,097,152
    float* psum   = ymin + (size_t)BB * NN * 256;        // 2,097,152
    float* psumsq = psum + (size_t)BB * NN * 256;        // 2,097,152
    float* xTbuf  = ymax;                                // alias: <=4MB, dead until gatherstats
    float* pmax   = ymax;                                // alias: stage-5 partials, 512*512 each
    float* pmn    = pmax + 512 * 512;
    float* ps5    = pmn + 512 * 512;
    float* pq5    = ps5 + 512 * 512;
    float* sqn    = psumsq + (size_t)BB * NN * 256;      // 8192 (unused)
    float* s_arr  = sqn + BB * NN;                       // 512
    float* t_arr  = s_arr + 512;                         // 512
    float* r1s    = t_arr + 512;                         // 32*512
    float* r1q    = r1s + 32 * 512;                      // 32*512
    int*   idxb   = (int*)(r1q + 32 * 512);              // 8192*20 ints
    float* zfull  = (float*)(idxb + BB * NN * KNNK);     // 8192*512
    __hip_bfloat16* xbf  = (__hip_bfloat16*)(zfull + (size_t)BB * NN * 512);  // 8192*512 bf16
    __hip_bfloat16* w5bf = xbf + (size_t)BB * NN * 512;                       // 512*512 bf16

    const double invM_edge = 1.0 / ((double)BB * NN * KNNK);
    const int nbn = BB * NN;

    // ---- Stage 1: in = x (B,N,3), out ch [0,64) ----
    knn3_fused<<<nbn / 16, 256, 0, stream>>>(x, idxb);
    zgemm3_k<<<nbn * 128 / 256, 256, 0, stream>>>(x, w1, zfull);
    gatherstats_k<128><<<nbn / 4, 256, 0, stream>>>(zfull, idxb, ymax, ymin, psum, psumsq);
    bnred1_k<<<dim3(1, 32), 256, 0, stream>>>(psum, psumsq, 64, r1s, r1q);
    bnred2_k<<<64, 64, 0, stream>>>(r1s, r1q, g1, b1, 64, invM_edge, s_arr, t_arr);
    epilogue_k<64><<<(nbn * 64 + 255) / 256, 256, 0, stream>>>(ymax, ymin, s_arr, t_arr, xtcat, 0);

    // ---- Stage 2: in ch [0,64), out [64,128) ----
    transpose_k<64><<<dim3(128, 1), 256, 0, stream>>>(xtcat, 0, xTbuf);
    knn_fused<64><<<nbn / 16, 256, 0, stream>>>(xTbuf, xtcat, 0, idxb);
    zgemm_k<64, 128><<<nbn / 16, 256, 0, stream>>>(xtcat, 0, w2, zfull);
    gatherstats_k<128><<<nbn / 4, 256, 0, stream>>>(zfull, idxb, ymax, ymin, psum, psumsq);
    bnred1_k<<<dim3(1, 32), 256, 0, stream>>>(psum, psumsq, 64, r1s, r1q);
    bnred2_k<<<64, 64, 0, stream>>>(r1s, r1q, g2, b2, 64, invM_edge, s_arr, t_arr);
    epilogue_k<64><<<(nbn * 64 + 255) / 256, 256, 0, stream>>>(ymax, ymin, s_arr, t_arr, xtcat, 64);

    // ---- Stage 3: in ch [64,128), out [128,256) ----
    transpose_k<64><<<dim3(128, 1), 256, 0, stream>>>(xtcat, 64, xTbuf);
    knn_fused<64><<<nbn / 16, 256, 0, stream>>>(xTbuf, xtcat, 64, idxb);
    zgemm_k<64, 256><<<nbn / 16, 256, 0, stream>>>(xtcat, 64, w3, zfull);
    gatherstats_k<256><<<nbn / 4, 256, 0, stream>>>(zfull, idxb, ymax, ymin, psum, psumsq);
    bnred1_k<<<dim3(2, 32), 256, 0, stream>>>(psum, psumsq, 128, r1s, r1q);
    bnred2_k<<<128, 64, 0, stream>>>(r1s, r1q, g3, b3, 128, invM_edge, s_arr, t_arr);
    epilogue_k<128><<<(nbn * 128 + 255) / 256, 256, 0, stream>>>(ymax, ymin, s_arr, t_arr, xtcat, 128);

    // ---- Stage 4: in ch [128,256), out [256,512) ----
    transpose_k<128><<<dim3(128, 2), 256, 0, stream>>>(xtcat, 128, xTbuf);
    knn_fused<128><<<nbn / 16, 256, 0, stream>>>(xTbuf, xtcat, 128, idxb);
    zgemm_k<128, 512><<<nbn / 16, 256, 0, stream>>>(xtcat, 128, w4, zfull);
    gatherstats_k<512><<<nbn / 4, 256, 0, stream>>>(zfull, idxb, ymax, ymin, psum, psumsq);
    bnred1_k<<<dim3(4, 32), 256, 0, stream>>>(psum, psumsq, 256, r1s, r1q);
    bnred2_k<<<256, 64, 0, stream>>>(r1s, r1q, g4, b4, 256, invM_edge, s_arr, t_arr);
    epilogue_k<256><<<(nbn * 256 + 255) / 256, 256, 0, stream>>>(ymax, ymin, s_arr, t_arr, xtcat, 256);

    // ---- Stage 5: bf16 converts, MFMA GEMM+stats, tiny reductions ----
    f2bf_k<<<512 * 512 / (256 * 8), 256, 0, stream>>>(w5, w5bf, 512 * 512);
    f2bf_k<<<nbn * 512 / (256 * 8), 256, 0, stream>>>(xtcat, xbf, nbn * 512);
    gemm5_mfma<<<256, 256, 0, stream>>>(xbf, w5bf, pmax, pmn, ps5, pq5);
    bnstat5_k<<<8, 256, 0, stream>>>(ps5, pq5, g5, b5, s_arr, t_arr);
    featgemm_k<<<BB, 256, 0, stream>>>(pmax, pmn, s_arr, t_arr, wemb, out);
}

// Round 8
// 624.572 us; speedup vs baseline: 1.2792x; 1.1889x over previous
//
#include <hip/hip_runtime.h>
#include <hip/hip_bf16.h>
#include <math.h>

#define BB 8
#define NN 1024
#define KNNK 20
#define LDC 512

typedef __attribute__((ext_vector_type(8))) short bfrag8;
typedef __attribute__((ext_vector_type(4))) float facc4;

struct bh8 { __hip_bfloat16 h[8]; };

__device__ __forceinline__ bh8 cvt8(float4 a, float4 b) {
    bh8 v;
    v.h[0] = __float2bfloat16(a.x); v.h[1] = __float2bfloat16(a.y);
    v.h[2] = __float2bfloat16(a.z); v.h[3] = __float2bfloat16(a.w);
    v.h[4] = __float2bfloat16(b.x); v.h[5] = __float2bfloat16(b.y);
    v.h[6] = __float2bfloat16(b.z); v.h[7] = __float2bfloat16(b.w);
    return v;
}

// ---------------- fp32 -> bf16 convert (8 elems/thread) ----------------
__global__ __launch_bounds__(256) void f2bf_k(const float* __restrict__ in,
                                              __hip_bfloat16* __restrict__ out, int n) {
    int i = (blockIdx.x * 256 + threadIdx.x) * 8;
    if (i >= n) return;
    float4 a = *(const float4*)(in + i);
    float4 b = *(const float4*)(in + i + 4);
    *(bh8*)(out + i) = cvt8(a, b);
}

// ---------------- top-20 selection, 2 interleaved query chains per wave ----------------
__device__ __forceinline__ void select20_x2(const float (*dist)[1024], int q0, int w, int lane,
                                            int* __restrict__ idxout) {
    float d[2][16];
#pragma unroll
    for (int qi = 0; qi < 2; qi++)
#pragma unroll
        for (int j = 0; j < 16; j++) d[qi][j] = dist[w * 2 + qi][lane + 64 * j];
    for (int t = 0; t < KNNK; t++) {
#pragma unroll
        for (int qi = 0; qi < 2; qi++) {
            float bv = d[qi][0]; int bj = 0;
#pragma unroll
            for (int j = 1; j < 16; j++) if (d[qi][j] > bv) { bv = d[qi][j]; bj = j; }
            int bm = bj * 64 + lane;
#pragma unroll
            for (int s = 1; s < 64; s <<= 1) {
                float ov = __shfl_xor(bv, s);
                int   om = __shfl_xor(bm, s);
                if (ov > bv || (ov == bv && om < bm)) { bv = ov; bm = om; }
            }
            if (lane == 0) idxout[(q0 + w * 2 + qi) * KNNK + t] = bm;
            if ((bm & 63) == lane) {
                int slot = bm >> 6;
#pragma unroll
                for (int j = 0; j < 16; j++) if (j == slot) d[qi][j] = -INFINITY;
            }
        }
    }
}

// ---------------- fused kNN stage 1 (C=3), 8 queries/block ----------------
__global__ __launch_bounds__(256, 4) void knn3_fused(const float* __restrict__ x,
                                                     int* __restrict__ idxout) {
    __shared__ float dist[8][1024];
    int tid = threadIdx.x;
    int q0 = blockIdx.x * 8;
    int b = q0 >> 10;
    const float* xb = x + (size_t)b * NN * 3;
    int lane = tid & 63, w = tid >> 6;
    float qx[8], qy[8], qz[8];
#pragma unroll
    for (int q = 0; q < 8; q++) {
        const float* qr = xb + (size_t)((q0 & (NN - 1)) + q) * 3;
        qx[q] = qr[0]; qy[q] = qr[1]; qz[q] = qr[2];
    }
#pragma unroll
    for (int cq = 0; cq < 4; cq++) {
        int cand = w * 256 + cq * 64 + lane;
        const float* cr = xb + (size_t)cand * 3;
        float cx = cr[0], cy = cr[1], cz = cr[2];
        float sqc = 0.f;
        sqc += cx * cx; sqc += cy * cy; sqc += cz * cz;
#pragma unroll
        for (int q = 0; q < 8; q++) {
            float d = qx[q] * cx + qy[q] * cy + qz[q] * cz;
            dist[q][cand] = 2.f * d - sqc;
        }
    }
    __syncthreads();
    select20_x2(dist, q0, w, lane, idxout);
}

// ---------------- fused kNN stages 2-4, 8 queries/block, coalesced from xT ----------------
template<int C>
__global__ __launch_bounds__(256, 4) void knn_fused(const float* __restrict__ xT,
                                                    const float* __restrict__ xt, int off,
                                                    int* __restrict__ idxout) {
    __shared__ float dist[8][1024];
    __shared__ __align__(16) float qs[8][C];
    int tid = threadIdx.x;
    int q0 = blockIdx.x * 8;
    int b = q0 >> 10;
    const float* xb = xt + (size_t)b * NN * LDC + off;
    for (int j = tid; j < 8 * (C / 4); j += 256) {
        int p = j / (C / 4), c4 = j % (C / 4);
        *(float4*)&qs[p][4 * c4] = *(const float4*)(xb + (size_t)((q0 & (NN - 1)) + p) * LDC + 4 * c4);
    }
    __syncthreads();
    int lane = tid & 63, w = tid >> 6;
    int cand0 = w * 256 + 4 * lane;
    const float* xTb = xT + (size_t)b * C * 1024;
    float acc[4][8];
    float sq[4] = {0.f, 0.f, 0.f, 0.f};
#pragma unroll
    for (int j = 0; j < 4; j++)
#pragma unroll
        for (int q = 0; q < 8; q++) acc[j][q] = 0.f;
    for (int cg = 0; cg < C / 4; cg++) {
        float4 r0 = *(const float4*)(xTb + (size_t)(4 * cg + 0) * 1024 + cand0);
        float4 r1 = *(const float4*)(xTb + (size_t)(4 * cg + 1) * 1024 + cand0);
        float4 r2 = *(const float4*)(xTb + (size_t)(4 * cg + 2) * 1024 + cand0);
        float4 r3 = *(const float4*)(xTb + (size_t)(4 * cg + 3) * 1024 + cand0);
        float rc[4][4] = {{r0.x, r1.x, r2.x, r3.x}, {r0.y, r1.y, r2.y, r3.y},
                          {r0.z, r1.z, r2.z, r3.z}, {r0.w, r1.w, r2.w, r3.w}};
#pragma unroll
        for (int j = 0; j < 4; j++) {
            sq[j] += rc[j][0] * rc[j][0];
            sq[j] += rc[j][1] * rc[j][1];
            sq[j] += rc[j][2] * rc[j][2];
            sq[j] += rc[j][3] * rc[j][3];
        }
#pragma unroll
        for (int q = 0; q < 8; q++) {
            float4 qv = *(const float4*)&qs[q][4 * cg];
#pragma unroll
            for (int j = 0; j < 4; j++)
                acc[j][q] += rc[j][0] * qv.x + rc[j][1] * qv.y + rc[j][2] * qv.z + rc[j][3] * qv.w;
        }
    }
#pragma unroll
    for (int q = 0; q < 8; q++) {
        float4 dv;
        dv.x = 2.f * acc[0][q] - sq[0];
        dv.y = 2.f * acc[1][q] - sq[1];
        dv.z = 2.f * acc[2][q] - sq[2];
        dv.w = 2.f * acc[3][q] - sq[3];
        *(float4*)&dist[q][cand0] = dv;
    }
    __syncthreads();
    select20_x2(dist, q0, w, lane, idxout);
}

// ---------------- stage-1 z-gemm (C=3) ----------------
__global__ __launch_bounds__(256) void zgemm3_k(const float* __restrict__ x, const float* __restrict__ w1,
                                                float* __restrict__ zf) {
    int i = blockIdx.x * 256 + threadIdx.x;
    int n = i >> 7, j = i & 127;
    const float* wr = w1 + (j < 64 ? j * 6 : (j - 64) * 6 + 3);
    const float* xr = x + n * 3;
    zf[(size_t)n * 128 + j] = wr[0] * xr[0] + wr[1] * xr[1] + wr[2] * xr[2];
}

// ---------------- z-gemm (fp32, stages 2-3) ----------------
template<int C, int O2>
__global__ __launch_bounds__(256) void zgemm_k(const float* __restrict__ xt, int off,
                                               const float* __restrict__ w,
                                               float* __restrict__ zf) {
    constexpr int O = O2 / 2;
    __shared__ __align__(16) float xs[16][C];
    int p0 = blockIdx.x * 16;
    int tid = threadIdx.x;
    for (int j = tid; j < 16 * (C / 4); j += 256) {
        int p = j / (C / 4), c4 = j % (C / 4);
        *(float4*)&xs[p][4 * c4] = *(const float4*)(xt + (size_t)(p0 + p) * LDC + off + 4 * c4);
    }
    __syncthreads();
    for (int j = tid; j < O2; j += 256) {
        const float* wr = w + (j < O ? (size_t)j * 2 * C : (size_t)(j - O) * 2 * C + C);
        float acc[16];
#pragma unroll
        for (int p = 0; p < 16; p++) acc[p] = 0.f;
        for (int c4 = 0; c4 < C / 4; c4++) {
            float4 wv = *(const float4*)(wr + 4 * c4);
#pragma unroll
            for (int p = 0; p < 16; p++) {
                float4 xv = *(const float4*)&xs[p][4 * c4];
                acc[p] += wv.x * xv.x + wv.y * xv.y + wv.z * xv.z + wv.w * xv.w;
            }
        }
#pragma unroll
        for (int p = 0; p < 16; p++) zf[(size_t)(p0 + p) * O2 + j] = acc[p];
    }
}

// ---------------- stage-4 z-gemm: bf16 MFMA (z4 feeds only stage 5; no kNN downstream) ----------------
// M=8192 (64 mtiles), N=512 (4 ntiles), K=128. W-row remap j<256->Wa_j, j>=256->Wb_{j-256} at staging.
__global__ __launch_bounds__(256) void zgemm4_mfma(const float* __restrict__ xtcat,
                                                   const float* __restrict__ w4,
                                                   float* __restrict__ zf) {
    __shared__ __hip_bfloat16 A[128][72];
    __shared__ __hip_bfloat16 W[128][72];
    int mt = blockIdx.x >> 2, nt = blockIdx.x & 3;
    int tid = threadIdx.x;
    int lane = tid & 63, wvx = tid >> 6;
    int mw = wvx >> 1, nw = wvx & 1;
    int m0 = lane & 15, qd = lane >> 4;
    int r = tid & 127, hf = tid >> 7;
    facc4 acc[4][4];
    facc4 zz = {0.f, 0.f, 0.f, 0.f};
#pragma unroll
    for (int mi = 0; mi < 4; mi++)
#pragma unroll
        for (int ni = 0; ni < 4; ni++) acc[mi][ni] = zz;
    int j = nt * 128 + r;
    const float* wsrc = w4 + (j < 256 ? (size_t)j * 256 : (size_t)(j - 256) * 256 + 128);
    const float* asrc = xtcat + (size_t)(mt * 128 + r) * 512 + 128;
    for (int kc = 0; kc < 2; kc++) {
#pragma unroll
        for (int u = 0; u < 4; u++) {
            int c0 = kc * 64 + hf * 32 + 8 * u;
            float4 a0 = *(const float4*)(asrc + c0);
            float4 a1 = *(const float4*)(asrc + c0 + 4);
            *(bh8*)&A[r][hf * 32 + 8 * u] = cvt8(a0, a1);
            float4 w0 = *(const float4*)(wsrc + c0);
            float4 w1 = *(const float4*)(wsrc + c0 + 4);
            *(bh8*)&W[r][hf * 32 + 8 * u] = cvt8(w0, w1);
        }
        __syncthreads();
#pragma unroll
        for (int kk = 0; kk < 2; kk++) {
            bfrag8 af[4], bf[4];
#pragma unroll
            for (int mi = 0; mi < 4; mi++)
                af[mi] = *(const bfrag8*)&A[64 * mw + 16 * mi + m0][32 * kk + 8 * qd];
#pragma unroll
            for (int ni = 0; ni < 4; ni++)
                bf[ni] = *(const bfrag8*)&W[64 * nw + 16 * ni + m0][32 * kk + 8 * qd];
#pragma unroll
            for (int mi = 0; mi < 4; mi++)
#pragma unroll
                for (int ni = 0; ni < 4; ni++)
                    acc[mi][ni] = __builtin_amdgcn_mfma_f32_16x16x32_bf16(af[mi], bf[ni], acc[mi][ni], 0, 0, 0);
        }
        __syncthreads();
    }
#pragma unroll
    for (int mi = 0; mi < 4; mi++)
#pragma unroll
        for (int ni = 0; ni < 4; ni++)
#pragma unroll
            for (int rg = 0; rg < 4; rg++) {
                int row = mt * 128 + mw * 64 + mi * 16 + qd * 4 + rg;
                int col = nt * 128 + nw * 64 + ni * 16 + m0;
                zf[(size_t)row * 512 + col] = acc[mi][ni][rg];
            }
}

// ---------------- gather + stats ----------------
template<int O2>
__global__ __launch_bounds__(256) void gatherstats_k(const float* __restrict__ zf,
                                                     const int* __restrict__ idx,
                                                     float* __restrict__ ymax, float* __restrict__ ymin,
                                                     float* __restrict__ psum, float* __restrict__ psumsq) {
    constexpr int O = O2 / 2;
    int wv = threadIdx.x >> 6, lane = threadIdx.x & 63;
    int n = blockIdx.x * 4 + wv;
    int b = n >> 10;
    const float* zbatch = zf + (size_t)b * NN * O2;
    int nb[KNNK];
#pragma unroll
    for (int k = 0; k < KNNK; k++) nb[k] = idx[n * KNNK + k];
#pragma unroll
    for (int ch = 0; ch < O / 64; ch++) {
        int o = ch * 64 + lane;
        float g[KNNK];
#pragma unroll
        for (int k = 0; k < KNNK; k++) g[k] = zbatch[(size_t)nb[k] * O2 + o];
        float mx = -INFINITY, mn = INFINITY, s = 0.f, ss = 0.f;
#pragma unroll
        for (int k = 0; k < KNNK; k++) {
            float v = g[k];
            mx = fmaxf(mx, v); mn = fminf(mn, v); s += v; ss += v * v;
        }
        float zn  = zf[(size_t)n * O2 + o];
        float zbn = zf[(size_t)n * O2 + O + o];
        float d = zbn - zn;
        mx += d; mn += d;
        ss = ss + 2.f * d * s + (float)KNNK * d * d;
        s  = s + (float)KNNK * d;
        ymax  [(size_t)n * O + o] = mx;
        ymin  [(size_t)n * O + o] = mn;
        psum  [(size_t)n * O + o] = s;
        psumsq[(size_t)n * O + o] = ss;
    }
}

// ---------------- BN reduce pass 1 ----------------
__global__ __launch_bounds__(256) void bnred1_k(const float* __restrict__ pn, const float* __restrict__ pq,
                                                int O, float* __restrict__ r1s, float* __restrict__ r1q) {
    __shared__ float ls[4][64], lq[4][64];
    int lane = threadIdx.x & 63, wv = threadIdx.x >> 6;
    int o = blockIdx.x * 64 + lane;
    int n0 = blockIdx.y * 256;
    float s = 0.f, q = 0.f;
    for (int r = wv; r < 256; r += 4) {
        s += pn[(size_t)(n0 + r) * O + o];
        q += pq[(size_t)(n0 + r) * O + o];
    }
    ls[wv][lane] = s; lq[wv][lane] = q;
    __syncthreads();
    if (wv == 0) {
        s = ls[0][lane] + ls[1][lane] + ls[2][lane] + ls[3][lane];
        q = lq[0][lane] + lq[1][lane] + lq[2][lane] + lq[3][lane];
        r1s[(size_t)blockIdx.y * O + o] = s;
        r1q[(size_t)blockIdx.y * O + o] = q;
    }
}

// ---------------- BN reduce pass 2 + scale/shift ----------------
__global__ __launch_bounds__(64) void bnred2_k(const float* __restrict__ r1s, const float* __restrict__ r1q,
                                               const float* __restrict__ g, const float* __restrict__ beta,
                                               int O, double invM,
                                               float* __restrict__ s_out, float* __restrict__ t_out) {
    int o = blockIdx.x, lane = threadIdx.x;
    double s = 0.0, q = 0.0;
    if (lane < 32) { s = r1s[(size_t)lane * O + o]; q = r1q[(size_t)lane * O + o]; }
#pragma unroll
    for (int m = 1; m < 32; m <<= 1) { s += __shfl_xor(s, m); q += __shfl_xor(q, m); }
    if (lane == 0) {
        double mean = s * invM;
        double var = q * invM - mean * mean;
        float inv = (float)(1.0 / sqrt(var + 1e-5));
        float sc = g[o] * inv;
        s_out[o] = sc;
        t_out[o] = beta[o] - (float)mean * sc;
    }
}

// ---------------- fused BN+lrelu epilogue + transpose: writes xtcat AND xT[b][c][n] ----------------
template<int O>
__global__ __launch_bounds__(256) void epitrans_k(const float* __restrict__ ymax, const float* __restrict__ ymin,
                                                  const float* __restrict__ s, const float* __restrict__ t,
                                                  float* __restrict__ xtcat, int off_out,
                                                  float* __restrict__ xT) {
    __shared__ float tile[64][O + 1];
    int n0 = blockIdx.x * 64;
    int b = n0 >> 10;
    int tid = threadIdx.x;
    for (int i = tid; i < 64 * O; i += 256) {
        int nl = i / O;
        int o = i & (O - 1);
        int n = n0 + nl;
        float sc = s[o];
        float v = sc >= 0.f ? ymax[(size_t)n * O + o] : ymin[(size_t)n * O + o];
        float y = sc * v + t[o];
        y = y >= 0.f ? y : 0.2f * y;
        xtcat[(size_t)n * LDC + off_out + o] = y;
        tile[nl][o] = y;
    }
    __syncthreads();
    int r = tid >> 4, cq = tid & 15;
#pragma unroll
    for (int ct = 0; ct < O / 16; ct++) {
        int c = ct * 16 + r;
        float4 ov;
        ov.x = tile[4 * cq + 0][c];
        ov.y = tile[4 * cq + 1][c];
        ov.z = tile[4 * cq + 2][c];
        ov.w = tile[4 * cq + 3][c];
        *(float4*)(xT + ((size_t)b * O + c) * 1024 + (n0 & (NN - 1)) + 4 * cq) = ov;
    }
}

// ---------------- plain epilogue (stage 4: no transpose needed) ----------------
template<int O>
__global__ void epilogue_k(const float* __restrict__ ymax, const float* __restrict__ ymin,
                           const float* __restrict__ s, const float* __restrict__ t,
                           float* __restrict__ xtcat, int off_out) {
    int i = blockIdx.x * blockDim.x + threadIdx.x;
    if (i >= BB * NN * O) return;
    int bn = i / O;
    int o = i & (O - 1);
    float sc = s[o];
    float v = sc >= 0.f ? ymax[i] : ymin[i];
    float y = sc * v + t[o];
    y = y >= 0.f ? y : 0.2f * y;
    xtcat[(size_t)bn * LDC + off_out + o] = y;
}

// ---------------- stage 5: bf16 MFMA GEMM w/ fused per-16-row stats ----------------
__global__ __launch_bounds__(256) void gemm5_mfma(const __hip_bfloat16* __restrict__ xbf,
                                                  const __hip_bfloat16* __restrict__ wbf,
                                                  float* __restrict__ pmax, float* __restrict__ pmn,
                                                  float* __restrict__ ps, float* __restrict__ pq) {
    __shared__ __hip_bfloat16 A[128][72];
    __shared__ __hip_bfloat16 W[128][72];
    int mt = blockIdx.x >> 2, nt = blockIdx.x & 3;
    int tid = threadIdx.x;
    int lane = tid & 63, wvx = tid >> 6;
    int mw = wvx >> 1, nw = wvx & 1;
    int m0 = lane & 15, qd = lane >> 4;
    int r = tid & 127, hf = tid >> 7;
    facc4 acc[4][4];
    facc4 zz = {0.f, 0.f, 0.f, 0.f};
#pragma unroll
    for (int mi = 0; mi < 4; mi++)
#pragma unroll
        for (int ni = 0; ni < 4; ni++) acc[mi][ni] = zz;
    for (int kc = 0; kc < 8; kc++) {
        const __hip_bfloat16* ap = xbf + (size_t)(mt * 128 + r) * 512 + kc * 64 + hf * 32;
        const __hip_bfloat16* wp = wbf + (size_t)(nt * 128 + r) * 512 + kc * 64 + hf * 32;
#pragma unroll
        for (int u = 0; u < 4; u++) {
            bh8 av = *(const bh8*)(ap + 8 * u);
            bh8 wv = *(const bh8*)(wp + 8 * u);
            *(bh8*)&A[r][hf * 32 + 8 * u] = av;
            *(bh8*)&W[r][hf * 32 + 8 * u] = wv;
        }
        __syncthreads();
#pragma unroll
        for (int kk = 0; kk < 2; kk++) {
            bfrag8 af[4], bf[4];
#pragma unroll
            for (int mi = 0; mi < 4; mi++)
                af[mi] = *(const bfrag8*)&A[64 * mw + 16 * mi + m0][32 * kk + 8 * qd];
#pragma unroll
            for (int ni = 0; ni < 4; ni++)
                bf[ni] = *(const bfrag8*)&W[64 * nw + 16 * ni + m0][32 * kk + 8 * qd];
#pragma unroll
            for (int mi = 0; mi < 4; mi++)
#pragma unroll
                for (int ni = 0; ni < 4; ni++)
                    acc[mi][ni] = __builtin_amdgcn_mfma_f32_16x16x32_bf16(af[mi], bf[ni], acc[mi][ni], 0, 0, 0);
        }
        __syncthreads();
    }
#pragma unroll
    for (int mi = 0; mi < 4; mi++) {
        int grp = mt * 8 + mw * 4 + mi;
#pragma unroll
        for (int ni = 0; ni < 4; ni++) {
            float mx = -INFINITY, mn = INFINITY, s = 0.f, ss = 0.f;
#pragma unroll
            for (int rg = 0; rg < 4; rg++) {
                float v = acc[mi][ni][rg];
                mx = fmaxf(mx, v); mn = fminf(mn, v); s += v; ss += v * v;
            }
#pragma unroll
            for (int m = 16; m < 64; m <<= 1) {
                mx = fmaxf(mx, __shfl_xor(mx, m));
                mn = fminf(mn, __shfl_xor(mn, m));
                s += __shfl_xor(s, m);
                ss += __shfl_xor(ss, m);
            }
            if (qd == 0) {
                int o = nt * 128 + nw * 64 + ni * 16 + m0;
                pmax[(size_t)grp * 512 + o] = mx;
                pmn [(size_t)grp * 512 + o] = mn;
                ps  [(size_t)grp * 512 + o] = s;
                pq  [(size_t)grp * 512 + o] = ss;
            }
        }
    }
}

// ---------------- stage-5 BN stats from the 512 per-group partials ----------------
__global__ __launch_bounds__(256) void bnstat5_k(const float* __restrict__ ps, const float* __restrict__ pq,
                                                 const float* __restrict__ g, const float* __restrict__ beta,
                                                 float* __restrict__ s_out, float* __restrict__ t_out) {
    __shared__ double lds_s[4][64], lds_q[4][64];
    int lane = threadIdx.x & 63, wv = threadIdx.x >> 6;
    int o = blockIdx.x * 64 + lane;
    double s = 0.0, q = 0.0;
    for (int r = wv; r < 512; r += 4) {
        s += ps[(size_t)r * 512 + o];
        q += pq[(size_t)r * 512 + o];
    }
    lds_s[wv][lane] = s; lds_q[wv][lane] = q;
    __syncthreads();
    if (wv == 0) {
        s = lds_s[0][lane] + lds_s[1][lane] + lds_s[2][lane] + lds_s[3][lane];
        q = lds_q[0][lane] + lds_q[1][lane] + lds_q[2][lane] + lds_q[3][lane];
        double invM = 1.0 / (BB * NN);
        double mean = s * invM;
        double var = q * invM - mean * mean;
        float inv = (float)(1.0 / sqrt(var + 1e-5));
        float sc = g[o] * inv;
        s_out[o] = sc;
        t_out[o] = beta[o] - (float)mean * sc;
    }
}

// ---------------- per-batch max/min reduce + BN + lrelu + feat @ wemb^T ----------------
__global__ __launch_bounds__(256) void featgemm_k(const float* __restrict__ pmax, const float* __restrict__ pmn,
                                                  const float* __restrict__ s, const float* __restrict__ t,
                                                  const float* __restrict__ wemb, float* __restrict__ out) {
    __shared__ __align__(16) float feat[512];
    int b = blockIdx.x, tid = threadIdx.x;
    for (int o = tid; o < 512; o += 256) {
        float mx = -INFINITY, mn = INFINITY;
        for (int r = b * 64; r < (b + 1) * 64; r++) {
            mx = fmaxf(mx, pmax[(size_t)r * 512 + o]);
            mn = fminf(mn, pmn [(size_t)r * 512 + o]);
        }
        float sc = s[o];
        float v = sc >= 0.f ? mx : mn;
        float y = sc * v + t[o];
        feat[o] = y >= 0.f ? y : 0.2f * y;
    }
    __syncthreads();
    const float4* wr = (const float4*)(wemb + (size_t)tid * 512);
    float acc = 0.f;
    for (int c4 = 0; c4 < 128; c4++) {
        float4 wv = wr[c4];
        float4 fv = *(const float4*)&feat[c4 * 4];
        acc += wv.x * fv.x + wv.y * fv.y + wv.z * fv.z + wv.w * fv.w;
    }
    out[(size_t)b * 256 + tid] = acc;
}

extern "C" void kernel_launch(void* const* d_in, const int* in_sizes, int n_in,
                              void* d_out, int out_size, void* d_ws, size_t ws_size,
                              hipStream_t stream) {
    const float* x    = (const float*)d_in[0];
    const float* w1   = (const float*)d_in[1];
    const float* g1   = (const float*)d_in[2];
    const float* b1   = (const float*)d_in[3];
    const float* w2   = (const float*)d_in[4];
    const float* g2   = (const float*)d_in[5];
    const float* b2   = (const float*)d_in[6];
    const float* w3   = (const float*)d_in[7];
    const float* g3   = (const float*)d_in[8];
    const float* b3   = (const float*)d_in[9];
    const float* w4   = (const float*)d_in[10];
    const float* g4   = (const float*)d_in[11];
    const float* b4   = (const float*)d_in[12];
    const float* w5   = (const float*)d_in[13];
    const float* g5   = (const float*)d_in[14];
    const float* b5   = (const float*)d_in[15];
    const float* wemb = (const float*)d_in[16];
    float* out = (float*)d_out;

    float* fws    = (float*)d_ws;
    float* xtcat  = fws;                                 // 4,194,304
    float* ymax   = xtcat + (size_t)BB * NN * 512;       // 2,097,152
    float* ymin   = ymax + (size_t)BB * NN * 256;        // 2,097,152
    float* psum   = ymin + (size_t)BB * NN * 256;        // 2,097,152
    float* psumsq = psum + (size_t)BB * NN * 256;        // 2,097,152
    float* xT     = psum;                                // alias: psum dead in epitrans->knn window
    float* pmax   = ymax;                                // alias: stage-5 partials, 512*512 each
    float* pmn    = pmax + 512 * 512;
    float* ps5    = pmn + 512 * 512;
    float* pq5    = ps5 + 512 * 512;
    float* sqn    = psumsq + (size_t)BB * NN * 256;      // 8192 (unused)
    float* s_arr  = sqn + BB * NN;                       // 512
    float* t_arr  = s_arr + 512;                         // 512
    float* r1s    = t_arr + 512;                         // 32*512
    float* r1q    = r1s + 32 * 512;                      // 32*512
    int*   idxb   = (int*)(r1q + 32 * 512);              // 8192*20 ints
    float* zfull  = (float*)(idxb + BB * NN * KNNK);     // 8192*512
    __hip_bfloat16* xbf  = (__hip_bfloat16*)(zfull + (size_t)BB * NN * 512);  // 8192*512 bf16
    __hip_bfloat16* w5bf = xbf + (size_t)BB * NN * 512;                       // 512*512 bf16

    const double invM_edge = 1.0 / ((double)BB * NN * KNNK);
    const int nbn = BB * NN;

    // ---- Stage 1: in = x (B,N,3), out ch [0,64) ----
    knn3_fused<<<nbn / 8, 256, 0, stream>>>(x, idxb);
    zgemm3_k<<<nbn * 128 / 256, 256, 0, stream>>>(x, w1, zfull);
    gatherstats_k<128><<<nbn / 4, 256, 0, stream>>>(zfull, idxb, ymax, ymin, psum, psumsq);
    bnred1_k<<<dim3(1, 32), 256, 0, stream>>>(psum, psumsq, 64, r1s, r1q);
    bnred2_k<<<64, 64, 0, stream>>>(r1s, r1q, g1, b1, 64, invM_edge, s_arr, t_arr);
    epitrans_k<64><<<128, 256, 0, stream>>>(ymax, ymin, s_arr, t_arr, xtcat, 0, xT);

    // ---- Stage 2: in ch [0,64), out [64,128) ----
    knn_fused<64><<<nbn / 8, 256, 0, stream>>>(xT, xtcat, 0, idxb);
    zgemm_k<64, 128><<<nbn / 16, 256, 0, stream>>>(xtcat, 0, w2, zfull);
    gatherstats_k<128><<<nbn / 4, 256, 0, stream>>>(zfull, idxb, ymax, ymin, psum, psumsq);
    bnred1_k<<<dim3(1, 32), 256, 0, stream>>>(psum, psumsq, 64, r1s, r1q);
    bnred2_k<<<64, 64, 0, stream>>>(r1s, r1q, g2, b2, 64, invM_edge, s_arr, t_arr);
    epitrans_k<64><<<128, 256, 0, stream>>>(ymax, ymin, s_arr, t_arr, xtcat, 64, xT);

    // ---- Stage 3: in ch [64,128), out [128,256) ----
    knn_fused<64><<<nbn / 8, 256, 0, stream>>>(xT, xtcat, 64, idxb);
    zgemm_k<64, 256><<<nbn / 16, 256, 0, stream>>>(xtcat, 64, w3, zfull);
    gatherstats_k<256><<<nbn / 4, 256, 0, stream>>>(zfull, idxb, ymax, ymin, psum, psumsq);
    bnred1_k<<<dim3(2, 32), 256, 0, stream>>>(psum, psumsq, 128, r1s, r1q);
    bnred2_k<<<128, 64, 0, stream>>>(r1s, r1q, g3, b3, 128, invM_edge, s_arr, t_arr);
    epitrans_k<128><<<128, 256, 0, stream>>>(ymax, ymin, s_arr, t_arr, xtcat, 128, xT);

    // ---- Stage 4: in ch [128,256), out [256,512) ----
    knn_fused<128><<<nbn / 8, 256, 0, stream>>>(xT, xtcat, 128, idxb);
    zgemm4_mfma<<<256, 256, 0, stream>>>(xtcat, w4, zfull);
    gatherstats_k<512><<<nbn / 4, 256, 0, stream>>>(zfull, idxb, ymax, ymin, psum, psumsq);
    bnred1_k<<<dim3(4, 32), 256, 0, stream>>>(psum, psumsq, 256, r1s, r1q);
    bnred2_k<<<256, 64, 0, stream>>>(r1s, r1q, g4, b4, 256, invM_edge, s_arr, t_arr);
    epilogue_k<256><<<(nbn * 256 + 255) / 256, 256, 0, stream>>>(ymax, ymin, s_arr, t_arr, xtcat, 256);

    // ---- Stage 5: bf16 converts, MFMA GEMM+stats, tiny reductions ----
    f2bf_k<<<512 * 512 / (256 * 8), 256, 0, stream>>>(w5, w5bf, 512 * 512);
    f2bf_k<<<nbn * 512 / (256 * 8), 256, 0, stream>>>(xtcat, xbf, nbn * 512);
    gemm5_mfma<<<256, 256, 0, stream>>>(xbf, w5bf, pmax, pmn, ps5, pq5);
    bnstat5_k<<<8, 256, 0, stream>>>(ps5, pq5, g5, b5, s_arr, t_arr);
    featgemm_k<<<BB, 256, 0, stream>>>(pmax, pmn, s_arr, t_arr, wemb, out);
}

// Round 9
// 577.026 us; speedup vs baseline: 1.3846x; 1.0824x over previous
//
#include <hip/hip_runtime.h>
#include <hip/hip_bf16.h>
#include <math.h>

#define BB 8
#define NN 1024
#define KNNK 20
#define LDC 512

typedef __attribute__((ext_vector_type(8))) short bfrag8;
typedef __attribute__((ext_vector_type(4))) float facc4;

struct bh8 { __hip_bfloat16 h[8]; };

__device__ __forceinline__ bh8 cvt8(float4 a, float4 b) {
    bh8 v;
    v.h[0] = __float2bfloat16(a.x); v.h[1] = __float2bfloat16(a.y);
    v.h[2] = __float2bfloat16(a.z); v.h[3] = __float2bfloat16(a.w);
    v.h[4] = __float2bfloat16(b.x); v.h[5] = __float2bfloat16(b.y);
    v.h[6] = __float2bfloat16(b.z); v.h[7] = __float2bfloat16(b.w);
    return v;
}

// ---------------- fp32 -> bf16 convert (w5 only now) ----------------
__global__ __launch_bounds__(256) void f2bf_k(const float* __restrict__ in,
                                              __hip_bfloat16* __restrict__ out, int n) {
    int i = (blockIdx.x * 256 + threadIdx.x) * 8;
    if (i >= n) return;
    float4 a = *(const float4*)(in + i);
    float4 b = *(const float4*)(in + i + 4);
    *(bh8*)(out + i) = cvt8(a, b);
}

// ---------------- top-20 selection: max-only butterfly + ballot index recovery ----------------
// Value path identical to prior rounds (fmaxf chains are exact); index tie-break differs only on
// exact fp32 ties (measure-zero here).
__device__ __forceinline__ void select20_x2(const float (*dist)[1024], int q0, int w, int lane,
                                            int* __restrict__ idxout) {
    float d[2][16];
#pragma unroll
    for (int qi = 0; qi < 2; qi++)
#pragma unroll
        for (int j = 0; j < 16; j++) d[qi][j] = dist[w * 2 + qi][lane + 64 * j];
    for (int t = 0; t < KNNK; t++) {
#pragma unroll
        for (int qi = 0; qi < 2; qi++) {
            float lm = d[qi][0];
#pragma unroll
            for (int j = 1; j < 16; j++) lm = fmaxf(lm, d[qi][j]);
            float bv = lm;
#pragma unroll
            for (int s = 1; s < 64; s <<= 1) bv = fmaxf(bv, __shfl_xor(bv, s));
            unsigned long long ball = __ballot(lm == bv);
            int wl = (int)__builtin_ctzll(ball);        // lowest winning lane
            int slot = 31;
#pragma unroll
            for (int j = 15; j >= 0; j--) if (d[qi][j] == bv) slot = j;   // lowest slot
            int bm = slot * 64 + lane;
            int win = __shfl(bm, wl);
            if (lane == 0) idxout[(q0 + w * 2 + qi) * KNNK + t] = win;
            bool isw = (lane == wl);
#pragma unroll
            for (int j = 0; j < 16; j++) if (isw && j == slot) d[qi][j] = -INFINITY;
        }
    }
}

// ---------------- fused kNN stage 1 (C=3), 8 queries/block ----------------
__global__ __launch_bounds__(256, 4) void knn3_fused(const float* __restrict__ x,
                                                     int* __restrict__ idxout) {
    __shared__ float dist[8][1024];
    int tid = threadIdx.x;
    int q0 = blockIdx.x * 8;
    int b = q0 >> 10;
    const float* xb = x + (size_t)b * NN * 3;
    int lane = tid & 63, w = tid >> 6;
    float qx[8], qy[8], qz[8];
#pragma unroll
    for (int q = 0; q < 8; q++) {
        const float* qr = xb + (size_t)((q0 & (NN - 1)) + q) * 3;
        qx[q] = qr[0]; qy[q] = qr[1]; qz[q] = qr[2];
    }
#pragma unroll
    for (int cq = 0; cq < 4; cq++) {
        int cand = w * 256 + cq * 64 + lane;
        const float* cr = xb + (size_t)cand * 3;
        float cx = cr[0], cy = cr[1], cz = cr[2];
        float sqc = 0.f;
        sqc += cx * cx; sqc += cy * cy; sqc += cz * cz;
#pragma unroll
        for (int q = 0; q < 8; q++) {
            float d = qx[q] * cx + qy[q] * cy + qz[q] * cz;
            dist[q][cand] = 2.f * d - sqc;
        }
    }
    __syncthreads();
    select20_x2(dist, q0, w, lane, idxout);
}

// ---------------- fused kNN stages 2-4, 8 queries/block, coalesced from xT, sq precomputed ----------------
template<int C>
__global__ __launch_bounds__(256, 4) void knn_fused(const float* __restrict__ xT,
                                                    const float* __restrict__ xt, int off,
                                                    const float* __restrict__ sqn,
                                                    int* __restrict__ idxout) {
    __shared__ float dist[8][1024];
    __shared__ __align__(16) float qs[8][C];
    int tid = threadIdx.x;
    int q0 = blockIdx.x * 8;
    int b = q0 >> 10;
    const float* xb = xt + (size_t)b * NN * LDC + off;
    for (int j = tid; j < 8 * (C / 4); j += 256) {
        int p = j / (C / 4), c4 = j % (C / 4);
        *(float4*)&qs[p][4 * c4] = *(const float4*)(xb + (size_t)((q0 & (NN - 1)) + p) * LDC + 4 * c4);
    }
    __syncthreads();
    int lane = tid & 63, w = tid >> 6;
    int cand0 = w * 256 + 4 * lane;
    const float* xTb = xT + (size_t)b * C * 1024;
    float4 sq4 = *(const float4*)(sqn + b * NN + cand0);
    float acc[4][8];
#pragma unroll
    for (int j = 0; j < 4; j++)
#pragma unroll
        for (int q = 0; q < 8; q++) acc[j][q] = 0.f;
    for (int cg = 0; cg < C / 4; cg++) {
        float4 r0 = *(const float4*)(xTb + (size_t)(4 * cg + 0) * 1024 + cand0);
        float4 r1 = *(const float4*)(xTb + (size_t)(4 * cg + 1) * 1024 + cand0);
        float4 r2 = *(const float4*)(xTb + (size_t)(4 * cg + 2) * 1024 + cand0);
        float4 r3 = *(const float4*)(xTb + (size_t)(4 * cg + 3) * 1024 + cand0);
        float rc[4][4] = {{r0.x, r1.x, r2.x, r3.x}, {r0.y, r1.y, r2.y, r3.y},
                          {r0.z, r1.z, r2.z, r3.z}, {r0.w, r1.w, r2.w, r3.w}};
#pragma unroll
        for (int q = 0; q < 8; q++) {
            float4 qv = *(const float4*)&qs[q][4 * cg];
#pragma unroll
            for (int j = 0; j < 4; j++)
                acc[j][q] += rc[j][0] * qv.x + rc[j][1] * qv.y + rc[j][2] * qv.z + rc[j][3] * qv.w;
        }
    }
#pragma unroll
    for (int q = 0; q < 8; q++) {
        float4 dv;
        dv.x = 2.f * acc[0][q] - sq4.x;
        dv.y = 2.f * acc[1][q] - sq4.y;
        dv.z = 2.f * acc[2][q] - sq4.z;
        dv.w = 2.f * acc[3][q] - sq4.w;
        *(float4*)&dist[q][cand0] = dv;
    }
    __syncthreads();
    select20_x2(dist, q0, w, lane, idxout);
}

// ---------------- stage-1 z-gemm (C=3) ----------------
__global__ __launch_bounds__(256) void zgemm3_k(const float* __restrict__ x, const float* __restrict__ w1,
                                                float* __restrict__ zf) {
    int i = blockIdx.x * 256 + threadIdx.x;
    int n = i >> 7, j = i & 127;
    const float* wr = w1 + (j < 64 ? j * 6 : (j - 64) * 6 + 3);
    const float* xr = x + n * 3;
    zf[(size_t)n * 128 + j] = wr[0] * xr[0] + wr[1] * xr[1] + wr[2] * xr[2];
}

// ---------------- z-gemm (fp32, stages 2-3) ----------------
template<int C, int O2>
__global__ __launch_bounds__(256) void zgemm_k(const float* __restrict__ xt, int off,
                                               const float* __restrict__ w,
                                               float* __restrict__ zf) {
    constexpr int O = O2 / 2;
    __shared__ __align__(16) float xs[16][C];
    int p0 = blockIdx.x * 16;
    int tid = threadIdx.x;
    for (int j = tid; j < 16 * (C / 4); j += 256) {
        int p = j / (C / 4), c4 = j % (C / 4);
        *(float4*)&xs[p][4 * c4] = *(const float4*)(xt + (size_t)(p0 + p) * LDC + off + 4 * c4);
    }
    __syncthreads();
    for (int j = tid; j < O2; j += 256) {
        const float* wr = w + (j < O ? (size_t)j * 2 * C : (size_t)(j - O) * 2 * C + C);
        float acc[16];
#pragma unroll
        for (int p = 0; p < 16; p++) acc[p] = 0.f;
        for (int c4 = 0; c4 < C / 4; c4++) {
            float4 wv = *(const float4*)(wr + 4 * c4);
#pragma unroll
            for (int p = 0; p < 16; p++) {
                float4 xv = *(const float4*)&xs[p][4 * c4];
                acc[p] += wv.x * xv.x + wv.y * xv.y + wv.z * xv.z + wv.w * xv.w;
            }
        }
#pragma unroll
        for (int p = 0; p < 16; p++) zf[(size_t)(p0 + p) * O2 + j] = acc[p];
    }
}

// ---------------- stage-4 z-gemm: bf16 MFMA ----------------
__global__ __launch_bounds__(256) void zgemm4_mfma(const float* __restrict__ xtcat,
                                                   const float* __restrict__ w4,
                                                   float* __restrict__ zf) {
    __shared__ __hip_bfloat16 A[128][72];
    __shared__ __hip_bfloat16 W[128][72];
    int mt = blockIdx.x >> 2, nt = blockIdx.x & 3;
    int tid = threadIdx.x;
    int lane = tid & 63, wvx = tid >> 6;
    int mw = wvx >> 1, nw = wvx & 1;
    int m0 = lane & 15, qd = lane >> 4;
    int r = tid & 127, hf = tid >> 7;
    facc4 acc[4][4];
    facc4 zz = {0.f, 0.f, 0.f, 0.f};
#pragma unroll
    for (int mi = 0; mi < 4; mi++)
#pragma unroll
        for (int ni = 0; ni < 4; ni++) acc[mi][ni] = zz;
    int j = nt * 128 + r;
    const float* wsrc = w4 + (j < 256 ? (size_t)j * 256 : (size_t)(j - 256) * 256 + 128);
    const float* asrc = xtcat + (size_t)(mt * 128 + r) * 512 + 128;
    for (int kc = 0; kc < 2; kc++) {
#pragma unroll
        for (int u = 0; u < 4; u++) {
            int c0 = kc * 64 + hf * 32 + 8 * u;
            float4 a0 = *(const float4*)(asrc + c0);
            float4 a1 = *(const float4*)(asrc + c0 + 4);
            *(bh8*)&A[r][hf * 32 + 8 * u] = cvt8(a0, a1);
            float4 w0 = *(const float4*)(wsrc + c0);
            float4 w1 = *(const float4*)(wsrc + c0 + 4);
            *(bh8*)&W[r][hf * 32 + 8 * u] = cvt8(w0, w1);
        }
        __syncthreads();
#pragma unroll
        for (int kk = 0; kk < 2; kk++) {
            bfrag8 af[4], bf[4];
#pragma unroll
            for (int mi = 0; mi < 4; mi++)
                af[mi] = *(const bfrag8*)&A[64 * mw + 16 * mi + m0][32 * kk + 8 * qd];
#pragma unroll
            for (int ni = 0; ni < 4; ni++)
                bf[ni] = *(const bfrag8*)&W[64 * nw + 16 * ni + m0][32 * kk + 8 * qd];
#pragma unroll
            for (int mi = 0; mi < 4; mi++)
#pragma unroll
                for (int ni = 0; ni < 4; ni++)
                    acc[mi][ni] = __builtin_amdgcn_mfma_f32_16x16x32_bf16(af[mi], bf[ni], acc[mi][ni], 0, 0, 0);
        }
        __syncthreads();
    }
#pragma unroll
    for (int mi = 0; mi < 4; mi++)
#pragma unroll
        for (int ni = 0; ni < 4; ni++)
#pragma unroll
            for (int rg = 0; rg < 4; rg++) {
                int row = mt * 128 + mw * 64 + mi * 16 + qd * 4 + rg;
                int col = nt * 128 + nw * 64 + ni * 16 + m0;
                zf[(size_t)row * 512 + col] = acc[mi][ni][rg];
            }
}

// ---------------- gather + stats ----------------
template<int O2>
__global__ __launch_bounds__(256) void gatherstats_k(const float* __restrict__ zf,
                                                     const int* __restrict__ idx,
                                                     float* __restrict__ ymax, float* __restrict__ ymin,
                                                     float* __restrict__ psum, float* __restrict__ psumsq) {
    constexpr int O = O2 / 2;
    int wv = threadIdx.x >> 6, lane = threadIdx.x & 63;
    int n = blockIdx.x * 4 + wv;
    int b = n >> 10;
    const float* zbatch = zf + (size_t)b * NN * O2;
    int nb[KNNK];
#pragma unroll
    for (int k = 0; k < KNNK; k++) nb[k] = idx[n * KNNK + k];
#pragma unroll
    for (int ch = 0; ch < O / 64; ch++) {
        int o = ch * 64 + lane;
        float g[KNNK];
#pragma unroll
        for (int k = 0; k < KNNK; k++) g[k] = zbatch[(size_t)nb[k] * O2 + o];
        float mx = -INFINITY, mn = INFINITY, s = 0.f, ss = 0.f;
#pragma unroll
        for (int k = 0; k < KNNK; k++) {
            float v = g[k];
            mx = fmaxf(mx, v); mn = fminf(mn, v); s += v; ss += v * v;
        }
        float zn  = zf[(size_t)n * O2 + o];
        float zbn = zf[(size_t)n * O2 + O + o];
        float d = zbn - zn;
        mx += d; mn += d;
        ss = ss + 2.f * d * s + (float)KNNK * d * d;
        s  = s + (float)KNNK * d;
        ymax  [(size_t)n * O + o] = mx;
        ymin  [(size_t)n * O + o] = mn;
        psum  [(size_t)n * O + o] = s;
        psumsq[(size_t)n * O + o] = ss;
    }
}

// ---------------- BN reduce pass 1 ----------------
__global__ __launch_bounds__(256) void bnred1_k(const float* __restrict__ pn, const float* __restrict__ pq,
                                                int O, float* __restrict__ r1s, float* __restrict__ r1q) {
    __shared__ float ls[4][64], lq[4][64];
    int lane = threadIdx.x & 63, wv = threadIdx.x >> 6;
    int o = blockIdx.x * 64 + lane;
    int n0 = blockIdx.y * 256;
    float s = 0.f, q = 0.f;
    for (int r = wv; r < 256; r += 4) {
        s += pn[(size_t)(n0 + r) * O + o];
        q += pq[(size_t)(n0 + r) * O + o];
    }
    ls[wv][lane] = s; lq[wv][lane] = q;
    __syncthreads();
    if (wv == 0) {
        s = ls[0][lane] + ls[1][lane] + ls[2][lane] + ls[3][lane];
        q = lq[0][lane] + lq[1][lane] + lq[2][lane] + lq[3][lane];
        r1s[(size_t)blockIdx.y * O + o] = s;
        r1q[(size_t)blockIdx.y * O + o] = q;
    }
}

// ---------------- BN reduce pass 2 + scale/shift ----------------
__global__ __launch_bounds__(64) void bnred2_k(const float* __restrict__ r1s, const float* __restrict__ r1q,
                                               const float* __restrict__ g, const float* __restrict__ beta,
                                               int O, double invM,
                                               float* __restrict__ s_out, float* __restrict__ t_out) {
    int o = blockIdx.x, lane = threadIdx.x;
    double s = 0.0, q = 0.0;
    if (lane < 32) { s = r1s[(size_t)lane * O + o]; q = r1q[(size_t)lane * O + o]; }
#pragma unroll
    for (int m = 1; m < 32; m <<= 1) { s += __shfl_xor(s, m); q += __shfl_xor(q, m); }
    if (lane == 0) {
        double mean = s * invM;
        double var = q * invM - mean * mean;
        float inv = (float)(1.0 / sqrt(var + 1e-5));
        float sc = g[o] * inv;
        s_out[o] = sc;
        t_out[o] = beta[o] - (float)mean * sc;
    }
}

// ---------------- fused BN+lrelu epilogue + transpose + next-stage |c|^2 + bf16 copy ----------------
template<int O>
__global__ __launch_bounds__(256) void epitrans_k(const float* __restrict__ ymax, const float* __restrict__ ymin,
                                                  const float* __restrict__ s, const float* __restrict__ t,
                                                  float* __restrict__ xtcat, int off_out,
                                                  float* __restrict__ xT, float* __restrict__ sqn,
                                                  __hip_bfloat16* __restrict__ xbf) {
    __shared__ float tile[64][O + 1];
    int n0 = blockIdx.x * 64;
    int b = n0 >> 10;
    int tid = threadIdx.x;
    for (int i = tid; i < 64 * O; i += 256) {
        int nl = i / O;
        int o = i & (O - 1);
        int n = n0 + nl;
        float sc = s[o];
        float v = sc >= 0.f ? ymax[(size_t)n * O + o] : ymin[(size_t)n * O + o];
        float y = sc * v + t[o];
        y = y >= 0.f ? y : 0.2f * y;
        xtcat[(size_t)n * LDC + off_out + o] = y;
        xbf[(size_t)n * LDC + off_out + o] = __float2bfloat16(y);
        tile[nl][o] = y;
    }
    __syncthreads();
    // |c|^2 over this stage's slice, c ascending (same order as prior in-kernel sq)
    if (tid < 64) {
        float sq = 0.f;
        for (int c = 0; c < O; c++) { float v = tile[tid][c]; sq += v * v; }
        sqn[n0 + tid] = sq;
    }
    int r = tid >> 4, cq = tid & 15;
#pragma unroll
    for (int ct = 0; ct < O / 16; ct++) {
        int c = ct * 16 + r;
        float4 ov;
        ov.x = tile[4 * cq + 0][c];
        ov.y = tile[4 * cq + 1][c];
        ov.z = tile[4 * cq + 2][c];
        ov.w = tile[4 * cq + 3][c];
        *(float4*)(xT + ((size_t)b * O + c) * 1024 + (n0 & (NN - 1)) + 4 * cq) = ov;
    }
}

// ---------------- plain epilogue (stage 4) + bf16 copy ----------------
template<int O>
__global__ void epilogue_k(const float* __restrict__ ymax, const float* __restrict__ ymin,
                           const float* __restrict__ s, const float* __restrict__ t,
                           float* __restrict__ xtcat, int off_out,
                           __hip_bfloat16* __restrict__ xbf) {
    int i = blockIdx.x * blockDim.x + threadIdx.x;
    if (i >= BB * NN * O) return;
    int bn = i / O;
    int o = i & (O - 1);
    float sc = s[o];
    float v = sc >= 0.f ? ymax[i] : ymin[i];
    float y = sc * v + t[o];
    y = y >= 0.f ? y : 0.2f * y;
    xtcat[(size_t)bn * LDC + off_out + o] = y;
    xbf[(size_t)bn * LDC + off_out + o] = __float2bfloat16(y);
}

// ---------------- stage 5: bf16 MFMA GEMM w/ fused per-16-row stats ----------------
__global__ __launch_bounds__(256) void gemm5_mfma(const __hip_bfloat16* __restrict__ xbf,
                                                  const __hip_bfloat16* __restrict__ wbf,
                                                  float* __restrict__ pmax, float* __restrict__ pmn,
                                                  float* __restrict__ ps, float* __restrict__ pq) {
    __shared__ __hip_bfloat16 A[128][72];
    __shared__ __hip_bfloat16 W[128][72];
    int mt = blockIdx.x >> 2, nt = blockIdx.x & 3;
    int tid = threadIdx.x;
    int lane = tid & 63, wvx = tid >> 6;
    int mw = wvx >> 1, nw = wvx & 1;
    int m0 = lane & 15, qd = lane >> 4;
    int r = tid & 127, hf = tid >> 7;
    facc4 acc[4][4];
    facc4 zz = {0.f, 0.f, 0.f, 0.f};
#pragma unroll
    for (int mi = 0; mi < 4; mi++)
#pragma unroll
        for (int ni = 0; ni < 4; ni++) acc[mi][ni] = zz;
    for (int kc = 0; kc < 8; kc++) {
        const __hip_bfloat16* ap = xbf + (size_t)(mt * 128 + r) * 512 + kc * 64 + hf * 32;
        const __hip_bfloat16* wp = wbf + (size_t)(nt * 128 + r) * 512 + kc * 64 + hf * 32;
#pragma unroll
        for (int u = 0; u < 4; u++) {
            bh8 av = *(const bh8*)(ap + 8 * u);
            bh8 wv = *(const bh8*)(wp + 8 * u);
            *(bh8*)&A[r][hf * 32 + 8 * u] = av;
            *(bh8*)&W[r][hf * 32 + 8 * u] = wv;
        }
        __syncthreads();
#pragma unroll
        for (int kk = 0; kk < 2; kk++) {
            bfrag8 af[4], bf[4];
#pragma unroll
            for (int mi = 0; mi < 4; mi++)
                af[mi] = *(const bfrag8*)&A[64 * mw + 16 * mi + m0][32 * kk + 8 * qd];
#pragma unroll
            for (int ni = 0; ni < 4; ni++)
                bf[ni] = *(const bfrag8*)&W[64 * nw + 16 * ni + m0][32 * kk + 8 * qd];
#pragma unroll
            for (int mi = 0; mi < 4; mi++)
#pragma unroll
                for (int ni = 0; ni < 4; ni++)
                    acc[mi][ni] = __builtin_amdgcn_mfma_f32_16x16x32_bf16(af[mi], bf[ni], acc[mi][ni], 0, 0, 0);
        }
        __syncthreads();
    }
#pragma unroll
    for (int mi = 0; mi < 4; mi++) {
        int grp = mt * 8 + mw * 4 + mi;
#pragma unroll
        for (int ni = 0; ni < 4; ni++) {
            float mx = -INFINITY, mn = INFINITY, s = 0.f, ss = 0.f;
#pragma unroll
            for (int rg = 0; rg < 4; rg++) {
                float v = acc[mi][ni][rg];
                mx = fmaxf(mx, v); mn = fminf(mn, v); s += v; ss += v * v;
            }
#pragma unroll
            for (int m = 16; m < 64; m <<= 1) {
                mx = fmaxf(mx, __shfl_xor(mx, m));
                mn = fminf(mn, __shfl_xor(mn, m));
                s += __shfl_xor(s, m);
                ss += __shfl_xor(ss, m);
            }
            if (qd == 0) {
                int o = nt * 128 + nw * 64 + ni * 16 + m0;
                pmax[(size_t)grp * 512 + o] = mx;
                pmn [(size_t)grp * 512 + o] = mn;
                ps  [(size_t)grp * 512 + o] = s;
                pq  [(size_t)grp * 512 + o] = ss;
            }
        }
    }
}

// ---------------- stage-5 BN stats ----------------
__global__ __launch_bounds__(256) void bnstat5_k(const float* __restrict__ ps, const float* __restrict__ pq,
                                                 const float* __restrict__ g, const float* __restrict__ beta,
                                                 float* __restrict__ s_out, float* __restrict__ t_out) {
    __shared__ double lds_s[4][64], lds_q[4][64];
    int lane = threadIdx.x & 63, wv = threadIdx.x >> 6;
    int o = blockIdx.x * 64 + lane;
    double s = 0.0, q = 0.0;
    for (int r = wv; r < 512; r += 4) {
        s += ps[(size_t)r * 512 + o];
        q += pq[(size_t)r * 512 + o];
    }
    lds_s[wv][lane] = s; lds_q[wv][lane] = q;
    __syncthreads();
    if (wv == 0) {
        s = lds_s[0][lane] + lds_s[1][lane] + lds_s[2][lane] + lds_s[3][lane];
        q = lds_q[0][lane] + lds_q[1][lane] + lds_q[2][lane] + lds_q[3][lane];
        double invM = 1.0 / (BB * NN);
        double mean = s * invM;
        double var = q * invM - mean * mean;
        float inv = (float)(1.0 / sqrt(var + 1e-5));
        float sc = g[o] * inv;
        s_out[o] = sc;
        t_out[o] = beta[o] - (float)mean * sc;
    }
}

// ---------------- per-batch max/min reduce + BN + lrelu + feat @ wemb^T ----------------
__global__ __launch_bounds__(256) void featgemm_k(const float* __restrict__ pmax, const float* __restrict__ pmn,
                                                  const float* __restrict__ s, const float* __restrict__ t,
                                                  const float* __restrict__ wemb, float* __restrict__ out) {
    __shared__ __align__(16) float feat[512];
    int b = blockIdx.x, tid = threadIdx.x;
    for (int o = tid; o < 512; o += 256) {
        float mx = -INFINITY, mn = INFINITY;
        for (int r = b * 64; r < (b + 1) * 64; r++) {
            mx = fmaxf(mx, pmax[(size_t)r * 512 + o]);
            mn = fminf(mn, pmn [(size_t)r * 512 + o]);
        }
        float sc = s[o];
        float v = sc >= 0.f ? mx : mn;
        float y = sc * v + t[o];
        feat[o] = y >= 0.f ? y : 0.2f * y;
    }
    __syncthreads();
    const float4* wr = (const float4*)(wemb + (size_t)tid * 512);
    float acc = 0.f;
    for (int c4 = 0; c4 < 128; c4++) {
        float4 wv = wr[c4];
        float4 fv = *(const float4*)&feat[c4 * 4];
        acc += wv.x * fv.x + wv.y * fv.y + wv.z * fv.z + wv.w * fv.w;
    }
    out[(size_t)b * 256 + tid] = acc;
}

extern "C" void kernel_launch(void* const* d_in, const int* in_sizes, int n_in,
                              void* d_out, int out_size, void* d_ws, size_t ws_size,
                              hipStream_t stream) {
    const float* x    = (const float*)d_in[0];
    const float* w1   = (const float*)d_in[1];
    const float* g1   = (const float*)d_in[2];
    const float* b1   = (const float*)d_in[3];
    const float* w2   = (const float*)d_in[4];
    const float* g2   = (const float*)d_in[5];
    const float* b2   = (const float*)d_in[6];
    const float* w3   = (const float*)d_in[7];
    const float* g3   = (const float*)d_in[8];
    const float* b3   = (const float*)d_in[9];
    const float* w4   = (const float*)d_in[10];
    const float* g4   = (const float*)d_in[11];
    const float* b4   = (const float*)d_in[12];
    const float* w5   = (const float*)d_in[13];
    const float* g5   = (const float*)d_in[14];
    const float* b5   = (const float*)d_in[15];
    const float* wemb = (const float*)d_in[16];
    float* out = (float*)d_out;

    float* fws    = (float*)d_ws;
    float* xtcat  = fws;                                 // 4,194,304
    float* ymax   = xtcat + (size_t)BB * NN * 512;       // 2,097,152
    float* ymin   = ymax + (size_t)BB * NN * 256;        // 2,097,152
    float* psum   = ymin + (size_t)BB * NN * 256;        // 2,097,152
    float* psumsq = psum + (size_t)BB * NN * 256;        // 2,097,152
    float* xT     = psum;                                // alias: psum dead in epitrans->knn window
    float* pmax   = ymax;                                // alias: stage-5 partials
    float* pmn    = pmax + 512 * 512;
    float* ps5    = pmn + 512 * 512;
    float* pq5    = ps5 + 512 * 512;
    float* sqn    = psumsq + (size_t)BB * NN * 256;      // 8192
    float* s_arr  = sqn + BB * NN;                       // 512
    float* t_arr  = s_arr + 512;                         // 512
    float* r1s    = t_arr + 512;                         // 32*512
    float* r1q    = r1s + 32 * 512;                      // 32*512
    int*   idxb   = (int*)(r1q + 32 * 512);              // 8192*20 ints
    float* zfull  = (float*)(idxb + BB * NN * KNNK);     // 8192*512
    __hip_bfloat16* xbf  = (__hip_bfloat16*)(zfull + (size_t)BB * NN * 512);  // 8192*512 bf16
    __hip_bfloat16* w5bf = xbf + (size_t)BB * NN * 512;                       // 512*512 bf16

    const double invM_edge = 1.0 / ((double)BB * NN * KNNK);
    const int nbn = BB * NN;

    // ---- Stage 1: in = x (B,N,3), out ch [0,64) ----
    knn3_fused<<<nbn / 8, 256, 0, stream>>>(x, idxb);
    zgemm3_k<<<nbn * 128 / 256, 256, 0, stream>>>(x, w1, zfull);
    gatherstats_k<128><<<nbn / 4, 256, 0, stream>>>(zfull, idxb, ymax, ymin, psum, psumsq);
    bnred1_k<<<dim3(1, 32), 256, 0, stream>>>(psum, psumsq, 64, r1s, r1q);
    bnred2_k<<<64, 64, 0, stream>>>(r1s, r1q, g1, b1, 64, invM_edge, s_arr, t_arr);
    epitrans_k<64><<<128, 256, 0, stream>>>(ymax, ymin, s_arr, t_arr, xtcat, 0, xT, sqn, xbf);

    // ---- Stage 2: in ch [0,64), out [64,128) ----
    knn_fused<64><<<nbn / 8, 256, 0, stream>>>(xT, xtcat, 0, sqn, idxb);
    zgemm_k<64, 128><<<nbn / 16, 256, 0, stream>>>(xtcat, 0, w2, zfull);
    gatherstats_k<128><<<nbn / 4, 256, 0, stream>>>(zfull, idxb, ymax, ymin, psum, psumsq);
    bnred1_k<<<dim3(1, 32), 256, 0, stream>>>(psum, psumsq, 64, r1s, r1q);
    bnred2_k<<<64, 64, 0, stream>>>(r1s, r1q, g2, b2, 64, invM_edge, s_arr, t_arr);
    epitrans_k<64><<<128, 256, 0, stream>>>(ymax, ymin, s_arr, t_arr, xtcat, 64, xT, sqn, xbf);

    // ---- Stage 3: in ch [64,128), out [128,256) ----
    knn_fused<64><<<nbn / 8, 256, 0, stream>>>(xT, xtcat, 64, sqn, idxb);
    zgemm_k<64, 256><<<nbn / 16, 256, 0, stream>>>(xtcat, 64, w3, zfull);
    gatherstats_k<256><<<nbn / 4, 256, 0, stream>>>(zfull, idxb, ymax, ymin, psum, psumsq);
    bnred1_k<<<dim3(2, 32), 256, 0, stream>>>(psum, psumsq, 128, r1s, r1q);
    bnred2_k<<<128, 64, 0, stream>>>(r1s, r1q, g3, b3, 128, invM_edge, s_arr, t_arr);
    epitrans_k<128><<<128, 256, 0, stream>>>(ymax, ymin, s_arr, t_arr, xtcat, 128, xT, sqn, xbf);

    // ---- Stage 4: in ch [128,256), out [256,512) ----
    knn_fused<128><<<nbn / 8, 256, 0, stream>>>(xT, xtcat, 128, sqn, idxb);
    zgemm4_mfma<<<256, 256, 0, stream>>>(xtcat, w4, zfull);
    gatherstats_k<512><<<nbn / 4, 256, 0, stream>>>(zfull, idxb, ymax, ymin, psum, psumsq);
    bnred1_k<<<dim3(4, 32), 256, 0, stream>>>(psum, psumsq, 256, r1s, r1q);
    bnred2_k<<<256, 64, 0, stream>>>(r1s, r1q, g4, b4, 256, invM_edge, s_arr, t_arr);
    epilogue_k<256><<<(nbn * 256 + 255) / 256, 256, 0, stream>>>(ymax, ymin, s_arr, t_arr, xtcat, 256, xbf);

    // ---- Stage 5 ----
    f2bf_k<<<512 * 512 / (256 * 8), 256, 0, stream>>>(w5, w5bf, 512 * 512);
    gemm5_mfma<<<256, 256, 0, stream>>>(xbf, w5bf, pmax, pmn, ps5, pq5);
    bnstat5_k<<<8, 256, 0, stream>>>(ps5, pq5, g5, b5, s_arr, t_arr);
    featgemm_k<<<BB, 256, 0, stream>>>(pmax, pmn, s_arr, t_arr, wemb, out);
}

// Round 11
// 519.577 us; speedup vs baseline: 1.5377x; 1.1106x over previous
//
#include <hip/hip_runtime.h>
#include <hip/hip_bf16.h>
#include <math.h>

#define BB 8
#define NN 1024
#define KNNK 20
#define LDC 512

typedef __attribute__((ext_vector_type(8))) short bfrag8;
typedef __attribute__((ext_vector_type(4))) float facc4;

struct bh8 { __hip_bfloat16 h[8]; };

__device__ __forceinline__ bh8 cvt8(float4 a, float4 b) {
    bh8 v;
    v.h[0] = __float2bfloat16(a.x); v.h[1] = __float2bfloat16(a.y);
    v.h[2] = __float2bfloat16(a.z); v.h[3] = __float2bfloat16(a.w);
    v.h[4] = __float2bfloat16(b.x); v.h[5] = __float2bfloat16(b.y);
    v.h[6] = __float2bfloat16(b.z); v.h[7] = __float2bfloat16(b.w);
    return v;
}

// ---------------- top-20 selection: per-lane sort + head-merge (exact values) ----------------
// Each lane Batcher-sorts its 16 values descending (explicit 63-comparator network, verified),
// writes sorted values + packed slot nibbles to LDS; 20 rounds of register-head max-butterfly;
// only the winning lane advances its pointer. Exact fp32 compares throughout.
__device__ __forceinline__ void select20_srt(float (*dist)[1024],
                                             unsigned char (*slotpk)[512],
                                             int q0, int w, int lane,
                                             int* __restrict__ idxout) {
    float d[2][16];
    int   sl[2][16];
#pragma unroll
    for (int qi = 0; qi < 2; qi++) {
        int row = w * 2 + qi;
#pragma unroll
        for (int j = 0; j < 16; j++) { d[qi][j] = dist[row][lane + 64 * j]; sl[qi][j] = j; }
    }
    // Batcher odd-even mergesort, n=16, 63 comparators (layers: 4-sorters, merge-8, merge-16)
    constexpr unsigned char CA[63] = {
        0,2,4,6,8,10,12,14,
        0,1,4,5,8,9,12,13,
        1,5,9,13,
        0,1,2,3,8,9,10,11,
        2,3,10,11,
        1,3,5,9,11,13,
        0,1,2,3,4,5,6,7,
        4,5,6,7,
        2,3,6,7,10,11,
        1,3,5,7,9,11,13};
    constexpr unsigned char CB[63] = {
        1,3,5,7,9,11,13,15,
        2,3,6,7,10,11,14,15,
        2,6,10,14,
        4,5,6,7,12,13,14,15,
        4,5,12,13,
        2,4,6,10,12,14,
        8,9,10,11,12,13,14,15,
        8,9,10,11,
        4,5,8,9,12,13,
        2,4,6,8,10,12,14};
#pragma unroll
    for (int c = 0; c < 63; c++) {
        const int a = CA[c], bq = CB[c];
#pragma unroll
        for (int qi = 0; qi < 2; qi++) {
            bool sw = d[qi][a] < d[qi][bq];
            float dmx = sw ? d[qi][bq] : d[qi][a];
            float dmn = sw ? d[qi][a]  : d[qi][bq];
            d[qi][a] = dmx; d[qi][bq] = dmn;
            int smx = sw ? sl[qi][bq] : sl[qi][a];
            int smn = sw ? sl[qi][a]  : sl[qi][bq];
            sl[qi][a] = smx; sl[qi][bq] = smn;
        }
    }
    // write sorted values (layout lane*16+j) + packed slot nibbles
#pragma unroll
    for (int qi = 0; qi < 2; qi++) {
        int row = w * 2 + qi;
#pragma unroll
        for (int j = 0; j < 16; j += 4) {
            float4 v = {d[qi][j], d[qi][j + 1], d[qi][j + 2], d[qi][j + 3]};
            *(float4*)&dist[row][lane * 16 + j] = v;
        }
        unsigned int pk0 = 0, pk1 = 0;
#pragma unroll
        for (int j = 0; j < 8; j++) pk0 |= (unsigned)sl[qi][j] << (4 * j);
#pragma unroll
        for (int j = 0; j < 8; j++) pk1 |= (unsigned)sl[qi][8 + j] << (4 * j);
        *(unsigned int*)&slotpk[row][lane * 8]     = pk0;
        *(unsigned int*)&slotpk[row][lane * 8 + 4] = pk1;
    }
    float head[2] = {d[0][0], d[1][0]};
    int ptr[2] = {0, 0};
    for (int t = 0; t < KNNK; t++) {
#pragma unroll
        for (int qi = 0; qi < 2; qi++) {
            int row = w * 2 + qi;
            float bv = head[qi];
#pragma unroll
            for (int s = 1; s < 64; s <<= 1) bv = fmaxf(bv, __shfl_xor(bv, s));
            unsigned long long ball = __ballot(head[qi] == bv);
            int wl = (int)__builtin_ctzll(ball);
            if (lane == wl) {
                int pp = ptr[qi];
                int slot = (slotpk[row][lane * 8 + (pp >> 1)] >> (4 * (pp & 1))) & 15;
                idxout[(q0 + row) * KNNK + t] = slot * 64 + lane;
                pp++;
                ptr[qi] = pp;
                int a = lane * 16 + (pp < 16 ? pp : 15);
                float nv = dist[row][a];
                head[qi] = (pp < 16) ? nv : -INFINITY;
            }
        }
    }
}

// ---------------- fused kNN stage 1 (C=3) + stage-1 z-gemm, 8 queries/block ----------------
__global__ __launch_bounds__(256, 4) void knn3_fused(const float* __restrict__ x,
                                                     const float* __restrict__ w1,
                                                     float* __restrict__ zf,
                                                     int* __restrict__ idxout) {
    __shared__ float dist[8][1024];
    __shared__ __align__(8) unsigned char slotpk[8][512];
    int tid = threadIdx.x;
    int q0 = blockIdx.x * 8;
    int b = q0 >> 10;
    const float* xb = x + (size_t)b * NN * 3;
    int lane = tid & 63, w = tid >> 6;
    float qx[8], qy[8], qz[8];
#pragma unroll
    for (int q = 0; q < 8; q++) {
        const float* qr = xb + (size_t)((q0 & (NN - 1)) + q) * 3;
        qx[q] = qr[0]; qy[q] = qr[1]; qz[q] = qr[2];
    }
#pragma unroll
    for (int cq = 0; cq < 4; cq++) {
        int cand = w * 256 + cq * 64 + lane;
        const float* cr = xb + (size_t)cand * 3;
        float cx = cr[0], cy = cr[1], cz = cr[2];
        float sqc = 0.f;
        sqc += cx * cx; sqc += cy * cy; sqc += cz * cz;
#pragma unroll
        for (int q = 0; q < 8; q++) {
            float d = qx[q] * cx + qy[q] * cy + qz[q] * cz;
            dist[q][cand] = 2.f * d - sqc;
        }
    }
    // fused stage-1 z-gemm for this block's 8 queries
    for (int i = tid; i < 8 * 128; i += 256) {
        int lq = i >> 7, j = i & 127;
        const float* wr = w1 + (j < 64 ? j * 6 : (j - 64) * 6 + 3);
        const float* xr = x + (size_t)(q0 + lq) * 3;
        zf[(size_t)(q0 + lq) * 128 + j] = wr[0] * xr[0] + wr[1] * xr[1] + wr[2] * xr[2];
    }
    __syncthreads();
    select20_srt(dist, slotpk, q0, w, lane, idxout);
}

// ---------------- fused kNN stages 2-4, 8 queries/block, coalesced from xT ----------------
template<int C>
__global__ __launch_bounds__(256, 4) void knn_fused(const float* __restrict__ xT,
                                                    const float* __restrict__ xt, int off,
                                                    const float* __restrict__ sqn,
                                                    int* __restrict__ idxout) {
    __shared__ float dist[8][1024];
    __shared__ __align__(8) unsigned char slotpk[8][512];
    __shared__ __align__(16) float qs[8][C];
    int tid = threadIdx.x;
    int q0 = blockIdx.x * 8;
    int b = q0 >> 10;
    const float* xb = xt + (size_t)b * NN * LDC + off;
    for (int j = tid; j < 8 * (C / 4); j += 256) {
        int p = j / (C / 4), c4 = j % (C / 4);
        *(float4*)&qs[p][4 * c4] = *(const float4*)(xb + (size_t)((q0 & (NN - 1)) + p) * LDC + 4 * c4);
    }
    __syncthreads();
    int lane = tid & 63, w = tid >> 6;
    int cand0 = w * 256 + 4 * lane;
    const float* xTb = xT + (size_t)b * C * 1024;
    float4 sq4 = *(const float4*)(sqn + b * NN + cand0);
    float acc[4][8];
#pragma unroll
    for (int j = 0; j < 4; j++)
#pragma unroll
        for (int q = 0; q < 8; q++) acc[j][q] = 0.f;
    for (int cg = 0; cg < C / 4; cg++) {
        float4 r0 = *(const float4*)(xTb + (size_t)(4 * cg + 0) * 1024 + cand0);
        float4 r1 = *(const float4*)(xTb + (size_t)(4 * cg + 1) * 1024 + cand0);
        float4 r2 = *(const float4*)(xTb + (size_t)(4 * cg + 2) * 1024 + cand0);
        float4 r3 = *(const float4*)(xTb + (size_t)(4 * cg + 3) * 1024 + cand0);
        float rc[4][4] = {{r0.x, r1.x, r2.x, r3.x}, {r0.y, r1.y, r2.y, r3.y},
                          {r0.z, r1.z, r2.z, r3.z}, {r0.w, r1.w, r2.w, r3.w}};
#pragma unroll
        for (int q = 0; q < 8; q++) {
            float4 qv = *(const float4*)&qs[q][4 * cg];
#pragma unroll
            for (int j = 0; j < 4; j++)
                acc[j][q] += rc[j][0] * qv.x + rc[j][1] * qv.y + rc[j][2] * qv.z + rc[j][3] * qv.w;
        }
    }
#pragma unroll
    for (int q = 0; q < 8; q++) {
        float4 dv;
        dv.x = 2.f * acc[0][q] - sq4.x;
        dv.y = 2.f * acc[1][q] - sq4.y;
        dv.z = 2.f * acc[2][q] - sq4.z;
        dv.w = 2.f * acc[3][q] - sq4.w;
        *(float4*)&dist[q][cand0] = dv;
    }
    __syncthreads();
    select20_srt(dist, slotpk, q0, w, lane, idxout);
}

// ---------------- z-gemm (fp32, stages 2-3) ----------------
template<int C, int O2>
__global__ __launch_bounds__(256) void zgemm_k(const float* __restrict__ xt, int off,
                                               const float* __restrict__ w,
                                               float* __restrict__ zf) {
    constexpr int O = O2 / 2;
    __shared__ __align__(16) float xs[16][C];
    int p0 = blockIdx.x * 16;
    int tid = threadIdx.x;
    for (int j = tid; j < 16 * (C / 4); j += 256) {
        int p = j / (C / 4), c4 = j % (C / 4);
        *(float4*)&xs[p][4 * c4] = *(const float4*)(xt + (size_t)(p0 + p) * LDC + off + 4 * c4);
    }
    __syncthreads();
    for (int j = tid; j < O2; j += 256) {
        const float* wr = w + (j < O ? (size_t)j * 2 * C : (size_t)(j - O) * 2 * C + C);
        float acc[16];
#pragma unroll
        for (int p = 0; p < 16; p++) acc[p] = 0.f;
        for (int c4 = 0; c4 < C / 4; c4++) {
            float4 wv = *(const float4*)(wr + 4 * c4);
#pragma unroll
            for (int p = 0; p < 16; p++) {
                float4 xv = *(const float4*)&xs[p][4 * c4];
                acc[p] += wv.x * xv.x + wv.y * xv.y + wv.z * xv.z + wv.w * xv.w;
            }
        }
#pragma unroll
        for (int p = 0; p < 16; p++) zf[(size_t)(p0 + p) * O2 + j] = acc[p];
    }
}

// ---------------- stage-4 z-gemm: bf16 MFMA, bf16 output ----------------
__global__ __launch_bounds__(256) void zgemm4_mfma(const float* __restrict__ xtcat,
                                                   const float* __restrict__ w4,
                                                   __hip_bfloat16* __restrict__ zf4) {
    __shared__ __hip_bfloat16 A[128][72];
    __shared__ __hip_bfloat16 W[128][72];
    int mt = blockIdx.x >> 2, nt = blockIdx.x & 3;
    int tid = threadIdx.x;
    int lane = tid & 63, wvx = tid >> 6;
    int mw = wvx >> 1, nw = wvx & 1;
    int m0 = lane & 15, qd = lane >> 4;
    int r = tid & 127, hf = tid >> 7;
    facc4 acc[4][4];
    facc4 zz = {0.f, 0.f, 0.f, 0.f};
#pragma unroll
    for (int mi = 0; mi < 4; mi++)
#pragma unroll
        for (int ni = 0; ni < 4; ni++) acc[mi][ni] = zz;
    int j = nt * 128 + r;
    const float* wsrc = w4 + (j < 256 ? (size_t)j * 256 : (size_t)(j - 256) * 256 + 128);
    const float* asrc = xtcat + (size_t)(mt * 128 + r) * 512 + 128;
    for (int kc = 0; kc < 2; kc++) {
#pragma unroll
        for (int u = 0; u < 4; u++) {
            int c0 = kc * 64 + hf * 32 + 8 * u;
            float4 a0 = *(const float4*)(asrc + c0);
            float4 a1 = *(const float4*)(asrc + c0 + 4);
            *(bh8*)&A[r][hf * 32 + 8 * u] = cvt8(a0, a1);
            float4 w0 = *(const float4*)(wsrc + c0);
            float4 w1 = *(const float4*)(wsrc + c0 + 4);
            *(bh8*)&W[r][hf * 32 + 8 * u] = cvt8(w0, w1);
        }
        __syncthreads();
#pragma unroll
        for (int kk = 0; kk < 2; kk++) {
            bfrag8 af[4], bf[4];
#pragma unroll
            for (int mi = 0; mi < 4; mi++)
                af[mi] = *(const bfrag8*)&A[64 * mw + 16 * mi + m0][32 * kk + 8 * qd];
#pragma unroll
            for (int ni = 0; ni < 4; ni++)
                bf[ni] = *(const bfrag8*)&W[64 * nw + 16 * ni + m0][32 * kk + 8 * qd];
#pragma unroll
            for (int mi = 0; mi < 4; mi++)
#pragma unroll
                for (int ni = 0; ni < 4; ni++)
                    acc[mi][ni] = __builtin_amdgcn_mfma_f32_16x16x32_bf16(af[mi], bf[ni], acc[mi][ni], 0, 0, 0);
        }
        __syncthreads();
    }
#pragma unroll
    for (int mi = 0; mi < 4; mi++)
#pragma unroll
        for (int ni = 0; ni < 4; ni++)
#pragma unroll
            for (int rg = 0; rg < 4; rg++) {
                int row = mt * 128 + mw * 64 + mi * 16 + qd * 4 + rg;
                int col = nt * 128 + nw * 64 + ni * 16 + m0;
                zf4[(size_t)row * 512 + col] = __float2bfloat16(acc[mi][ni][rg]);
            }
}

// ---------------- gather + stats (fp32 zf, stages 1-3) ----------------
template<int O2>
__global__ __launch_bounds__(256) void gatherstats_k(const float* __restrict__ zf,
                                                     const int* __restrict__ idx,
                                                     float* __restrict__ ymax, float* __restrict__ ymin,
                                                     float* __restrict__ psum, float* __restrict__ psumsq) {
    constexpr int O = O2 / 2;
    int wv = threadIdx.x >> 6, lane = threadIdx.x & 63;
    int n = blockIdx.x * 4 + wv;
    int b = n >> 10;
    const float* zbatch = zf + (size_t)b * NN * O2;
    int nb[KNNK];
#pragma unroll
    for (int k = 0; k < KNNK; k++) nb[k] = idx[n * KNNK + k];
#pragma unroll
    for (int ch = 0; ch < O / 64; ch++) {
        int o = ch * 64 + lane;
        float g[KNNK];
#pragma unroll
        for (int k = 0; k < KNNK; k++) g[k] = zbatch[(size_t)nb[k] * O2 + o];
        float mx = -INFINITY, mn = INFINITY, s = 0.f, ss = 0.f;
#pragma unroll
        for (int k = 0; k < KNNK; k++) {
            float v = g[k];
            mx = fmaxf(mx, v); mn = fminf(mn, v); s += v; ss += v * v;
        }
        float zn  = zf[(size_t)n * O2 + o];
        float zbn = zf[(size_t)n * O2 + O + o];
        float d = zbn - zn;
        mx += d; mn += d;
        ss = ss + 2.f * d * s + (float)KNNK * d * d;
        s  = s + (float)KNNK * d;
        ymax  [(size_t)n * O + o] = mx;
        ymin  [(size_t)n * O + o] = mn;
        psum  [(size_t)n * O + o] = s;
        psumsq[(size_t)n * O + o] = ss;
    }
}

// ---------------- gather + stats, bf16 zf4 (stage 4) ----------------
__global__ __launch_bounds__(256) void gatherstats4_k(const __hip_bfloat16* __restrict__ zf4,
                                                      const int* __restrict__ idx,
                                                      float* __restrict__ ymax, float* __restrict__ ymin,
                                                      float* __restrict__ psum, float* __restrict__ psumsq) {
    int wv = threadIdx.x >> 6, lane = threadIdx.x & 63;
    int n = blockIdx.x * 4 + wv;
    int b = n >> 10;
    const __hip_bfloat16* zbatch = zf4 + (size_t)b * NN * 512;
    int nb[KNNK];
#pragma unroll
    for (int k = 0; k < KNNK; k++) nb[k] = idx[n * KNNK + k];
#pragma unroll
    for (int ch = 0; ch < 4; ch++) {
        int o = ch * 64 + lane;
        float g[KNNK];
#pragma unroll
        for (int k = 0; k < KNNK; k++) g[k] = __bfloat162float(zbatch[(size_t)nb[k] * 512 + o]);
        float mx = -INFINITY, mn = INFINITY, s = 0.f, ss = 0.f;
#pragma unroll
        for (int k = 0; k < KNNK; k++) {
            float v = g[k];
            mx = fmaxf(mx, v); mn = fminf(mn, v); s += v; ss += v * v;
        }
        float zn  = __bfloat162float(zf4[(size_t)n * 512 + o]);
        float zbn = __bfloat162float(zf4[(size_t)n * 512 + 256 + o]);
        float d = zbn - zn;
        mx += d; mn += d;
        ss = ss + 2.f * d * s + (float)KNNK * d * d;
        s  = s + (float)KNNK * d;
        ymax  [(size_t)n * 256 + o] = mx;
        ymin  [(size_t)n * 256 + o] = mn;
        psum  [(size_t)n * 256 + o] = s;
        psumsq[(size_t)n * 256 + o] = ss;
    }
}

// ---------------- BN reduce pass 1 ----------------
__global__ __launch_bounds__(256) void bnred1_k(const float* __restrict__ pn, const float* __restrict__ pq,
                                                int O, float* __restrict__ r1s, float* __restrict__ r1q) {
    __shared__ float ls[4][64], lq[4][64];
    int lane = threadIdx.x & 63, wv = threadIdx.x >> 6;
    int o = blockIdx.x * 64 + lane;
    int n0 = blockIdx.y * 256;
    float s = 0.f, q = 0.f;
    for (int r = wv; r < 256; r += 4) {
        s += pn[(size_t)(n0 + r) * O + o];
        q += pq[(size_t)(n0 + r) * O + o];
    }
    ls[wv][lane] = s; lq[wv][lane] = q;
    __syncthreads();
    if (wv == 0) {
        s = ls[0][lane] + ls[1][lane] + ls[2][lane] + ls[3][lane];
        q = lq[0][lane] + lq[1][lane] + lq[2][lane] + lq[3][lane];
        r1s[(size_t)blockIdx.y * O + o] = s;
        r1q[(size_t)blockIdx.y * O + o] = q;
    }
}

// ---------------- BN+lrelu epilogue + transpose + |c|^2 + bf16 copy, s/t computed in-block ----------------
template<int O>
__global__ __launch_bounds__(256) void epitrans2_k(const float* __restrict__ ymax, const float* __restrict__ ymin,
                                                   const float* __restrict__ r1s, const float* __restrict__ r1q,
                                                   const float* __restrict__ g, const float* __restrict__ beta,
                                                   double invM,
                                                   float* __restrict__ xtcat, int off_out,
                                                   float* __restrict__ xT, float* __restrict__ sqn,
                                                   __hip_bfloat16* __restrict__ xbf) {
    __shared__ float tile[64][O + 1];
    __shared__ float ssh[O], tth[O];
    int n0 = blockIdx.x * 64;
    int b = n0 >> 10;
    int tid = threadIdx.x;
    for (int o = tid; o < O; o += 256) {
        double sd = 0.0, qd = 0.0;
        for (int r = 0; r < 32; r++) { sd += r1s[(size_t)r * O + o]; qd += r1q[(size_t)r * O + o]; }
        double mean = sd * invM;
        double var = qd * invM - mean * mean;
        float inv = (float)(1.0 / sqrt(var + 1e-5));
        float sc = g[o] * inv;
        ssh[o] = sc;
        tth[o] = beta[o] - (float)mean * sc;
    }
    __syncthreads();
    for (int i = tid; i < 64 * O; i += 256) {
        int nl = i / O;
        int o = i & (O - 1);
        int n = n0 + nl;
        float sc = ssh[o];
        float v = sc >= 0.f ? ymax[(size_t)n * O + o] : ymin[(size_t)n * O + o];
        float y = sc * v + tth[o];
        y = y >= 0.f ? y : 0.2f * y;
        xtcat[(size_t)n * LDC + off_out + o] = y;
        xbf[(size_t)n * LDC + off_out + o] = __float2bfloat16(y);
        tile[nl][o] = y;
    }
    __syncthreads();
    if (tid < 64) {
        float sq = 0.f;
        for (int c = 0; c < O; c++) { float v = tile[tid][c]; sq += v * v; }
        sqn[n0 + tid] = sq;
    }
    int r = tid >> 4, cq = tid & 15;
#pragma unroll
    for (int ct = 0; ct < O / 16; ct++) {
        int c = ct * 16 + r;
        float4 ov;
        ov.x = tile[4 * cq + 0][c];
        ov.y = tile[4 * cq + 1][c];
        ov.z = tile[4 * cq + 2][c];
        ov.w = tile[4 * cq + 3][c];
        *(float4*)(xT + ((size_t)b * O + c) * 1024 + (n0 & (NN - 1)) + 4 * cq) = ov;
    }
}

// ---------------- stage-4 epilogue: s/t in-block, writes xbf ONLY ----------------
__global__ __launch_bounds__(256) void epilogue4_k(const float* __restrict__ ymax, const float* __restrict__ ymin,
                                                   const float* __restrict__ r1s, const float* __restrict__ r1q,
                                                   const float* __restrict__ g, const float* __restrict__ beta,
                                                   double invM,
                                                   __hip_bfloat16* __restrict__ xbf) {
    __shared__ float ssh[256], tth[256];
    int n0 = blockIdx.x * 64;
    int tid = threadIdx.x;
    {
        int o = tid;
        double sd = 0.0, qd = 0.0;
        for (int r = 0; r < 32; r++) { sd += r1s[(size_t)r * 256 + o]; qd += r1q[(size_t)r * 256 + o]; }
        double mean = sd * invM;
        double var = qd * invM - mean * mean;
        float inv = (float)(1.0 / sqrt(var + 1e-5));
        float sc = g[o] * inv;
        ssh[o] = sc;
        tth[o] = beta[o] - (float)mean * sc;
    }
    __syncthreads();
    for (int i = tid; i < 64 * 256; i += 256) {
        int nl = i >> 8;
        int o = i & 255;
        int n = n0 + nl;
        float sc = ssh[o];
        float v = sc >= 0.f ? ymax[(size_t)n * 256 + o] : ymin[(size_t)n * 256 + o];
        float y = sc * v + tth[o];
        y = y >= 0.f ? y : 0.2f * y;
        xbf[(size_t)n * LDC + 256 + o] = __float2bfloat16(y);
    }
}

// ---------------- stage 5: bf16 MFMA GEMM (W staged from fp32 w5) w/ fused stats ----------------
__global__ __launch_bounds__(256) void gemm5_mfma(const __hip_bfloat16* __restrict__ xbf,
                                                  const float* __restrict__ w5,
                                                  float* __restrict__ pmax, float* __restrict__ pmn,
                                                  float* __restrict__ ps, float* __restrict__ pq) {
    __shared__ __hip_bfloat16 A[128][72];
    __shared__ __hip_bfloat16 W[128][72];
    int mt = blockIdx.x >> 2, nt = blockIdx.x & 3;
    int tid = threadIdx.x;
    int lane = tid & 63, wvx = tid >> 6;
    int mw = wvx >> 1, nw = wvx & 1;
    int m0 = lane & 15, qd = lane >> 4;
    int r = tid & 127, hf = tid >> 7;
    facc4 acc[4][4];
    facc4 zz = {0.f, 0.f, 0.f, 0.f};
#pragma unroll
    for (int mi = 0; mi < 4; mi++)
#pragma unroll
        for (int ni = 0; ni < 4; ni++) acc[mi][ni] = zz;
    for (int kc = 0; kc < 8; kc++) {
        const __hip_bfloat16* ap = xbf + (size_t)(mt * 128 + r) * 512 + kc * 64 + hf * 32;
        const float* wp = w5 + (size_t)(nt * 128 + r) * 512 + kc * 64 + hf * 32;
#pragma unroll
        for (int u = 0; u < 4; u++) {
            bh8 av = *(const bh8*)(ap + 8 * u);
            *(bh8*)&A[r][hf * 32 + 8 * u] = av;
            float4 w0 = *(const float4*)(wp + 8 * u);
            float4 w1 = *(const float4*)(wp + 8 * u + 4);
            *(bh8*)&W[r][hf * 32 + 8 * u] = cvt8(w0, w1);
        }
        __syncthreads();
#pragma unroll
        for (int kk = 0; kk < 2; kk++) {
            bfrag8 af[4], bf[4];
#pragma unroll
            for (int mi = 0; mi < 4; mi++)
                af[mi] = *(const bfrag8*)&A[64 * mw + 16 * mi + m0][32 * kk + 8 * qd];
#pragma unroll
            for (int ni = 0; ni < 4; ni++)
                bf[ni] = *(const bfrag8*)&W[64 * nw + 16 * ni + m0][32 * kk + 8 * qd];
#pragma unroll
            for (int mi = 0; mi < 4; mi++)
#pragma unroll
                for (int ni = 0; ni < 4; ni++)
                    acc[mi][ni] = __builtin_amdgcn_mfma_f32_16x16x32_bf16(af[mi], bf[ni], acc[mi][ni], 0, 0, 0);
        }
        __syncthreads();
    }
#pragma unroll
    for (int mi = 0; mi < 4; mi++) {
        int grp = mt * 8 + mw * 4 + mi;
#pragma unroll
        for (int ni = 0; ni < 4; ni++) {
            float mx = -INFINITY, mn = INFINITY, s = 0.f, ss = 0.f;
#pragma unroll
            for (int rg = 0; rg < 4; rg++) {
                float v = acc[mi][ni][rg];
                mx = fmaxf(mx, v); mn = fminf(mn, v); s += v; ss += v * v;
            }
#pragma unroll
            for (int m = 16; m < 64; m <<= 1) {
                mx = fmaxf(mx, __shfl_xor(mx, m));
                mn = fminf(mn, __shfl_xor(mn, m));
                s += __shfl_xor(s, m);
                ss += __shfl_xor(ss, m);
            }
            if (qd == 0) {
                int o = nt * 128 + nw * 64 + ni * 16 + m0;
                pmax[(size_t)grp * 512 + o] = mx;
                pmn [(size_t)grp * 512 + o] = mn;
                ps  [(size_t)grp * 512 + o] = s;
                pq  [(size_t)grp * 512 + o] = ss;
            }
        }
    }
}

// ---------------- stage-5 BN stats ----------------
__global__ __launch_bounds__(256) void bnstat5_k(const float* __restrict__ ps, const float* __restrict__ pq,
                                                 const float* __restrict__ g, const float* __restrict__ beta,
                                                 float* __restrict__ s_out, float* __restrict__ t_out) {
    __shared__ double lds_s[4][64], lds_q[4][64];
    int lane = threadIdx.x & 63, wv = threadIdx.x >> 6;
    int o = blockIdx.x * 64 + lane;
    double s = 0.0, q = 0.0;
    for (int r = wv; r < 512; r += 4) {
        s += ps[(size_t)r * 512 + o];
        q += pq[(size_t)r * 512 + o];
    }
    lds_s[wv][lane] = s; lds_q[wv][lane] = q;
    __syncthreads();
    if (wv == 0) {
        s = lds_s[0][lane] + lds_s[1][lane] + lds_s[2][lane] + lds_s[3][lane];
        q = lds_q[0][lane] + lds_q[1][lane] + lds_q[2][lane] + lds_q[3][lane];
        double invM = 1.0 / (BB * NN);
        double mean = s * invM;
        double var = q * invM - mean * mean;
        float inv = (float)(1.0 / sqrt(var + 1e-5));
        float sc = g[o] * inv;
        s_out[o] = sc;
        t_out[o] = beta[o] - (float)mean * sc;
    }
}

// ---------------- per-batch max/min reduce + BN + lrelu + feat @ wemb^T ----------------
__global__ __launch_bounds__(256) void featgemm_k(const float* __restrict__ pmax, const float* __restrict__ pmn,
                                                  const float* __restrict__ s, const float* __restrict__ t,
                                                  const float* __restrict__ wemb, float* __restrict__ out) {
    __shared__ __align__(16) float feat[512];
    int b = blockIdx.x, tid = threadIdx.x;
    for (int o = tid; o < 512; o += 256) {
        float mx = -INFINITY, mn = INFINITY;
        for (int r = b * 64; r < (b + 1) * 64; r++) {
            mx = fmaxf(mx, pmax[(size_t)r * 512 + o]);
            mn = fminf(mn, pmn [(size_t)r * 512 + o]);
        }
        float sc = s[o];
        float v = sc >= 0.f ? mx : mn;
        float y = sc * v + t[o];
        feat[o] = y >= 0.f ? y : 0.2f * y;
    }
    __syncthreads();
    const float4* wr = (const float4*)(wemb + (size_t)tid * 512);
    float acc = 0.f;
    for (int c4 = 0; c4 < 128; c4++) {
        float4 wv = wr[c4];
        float4 fv = *(const float4*)&feat[c4 * 4];
        acc += wv.x * fv.x + wv.y * fv.y + wv.z * fv.z + wv.w * fv.w;
    }
    out[(size_t)b * 256 + tid] = acc;
}

extern "C" void kernel_launch(void* const* d_in, const int* in_sizes, int n_in,
                              void* d_out, int out_size, void* d_ws, size_t ws_size,
                              hipStream_t stream) {
    const float* x    = (const float*)d_in[0];
    const float* w1   = (const float*)d_in[1];
    const float* g1   = (const float*)d_in[2];
    const float* b1   = (const float*)d_in[3];
    const float* w2   = (const float*)d_in[4];
    const float* g2   = (const float*)d_in[5];
    const float* b2   = (const float*)d_in[6];
    const float* w3   = (const float*)d_in[7];
    const float* g3   = (const float*)d_in[8];
    const float* b3   = (const float*)d_in[9];
    const float* w4   = (const float*)d_in[10];
    const float* g4   = (const float*)d_in[11];
    const float* b4   = (const float*)d_in[12];
    const float* w5   = (const float*)d_in[13];
    const float* g5   = (const float*)d_in[14];
    const float* b5   = (const float*)d_in[15];
    const float* wemb = (const float*)d_in[16];
    float* out = (float*)d_out;

    float* fws    = (float*)d_ws;
    float* xtcat  = fws;                                 // 4,194,304
    float* ymax   = xtcat + (size_t)BB * NN * 512;       // 2,097,152
    float* ymin   = ymax + (size_t)BB * NN * 256;        // 2,097,152
    float* psum   = ymin + (size_t)BB * NN * 256;        // 2,097,152
    float* psumsq = psum + (size_t)BB * NN * 256;        // 2,097,152
    float* xT     = psum;                                // alias: psum dead in epitrans->knn window
    float* pmax   = ymax;                                // alias: stage-5 partials
    float* pmn    = pmax + 512 * 512;
    float* ps5    = pmn + 512 * 512;
    float* pq5    = ps5 + 512 * 512;
    float* sqn    = psumsq + (size_t)BB * NN * 256;      // 8192
    float* s_arr  = sqn + BB * NN;                       // 512
    float* t_arr  = s_arr + 512;                         // 512
    float* r1s    = t_arr + 512;                         // 32*512
    float* r1q    = r1s + 32 * 512;                      // 32*512
    int*   idxb   = (int*)(r1q + 32 * 512);              // 8192*20 ints
    float* zfull  = (float*)(idxb + BB * NN * KNNK);     // 8192*512 fp32 (stages 1-3)
    __hip_bfloat16* zf4 = (__hip_bfloat16*)zfull;        // alias: stage-4 z, bf16
    __hip_bfloat16* xbf = (__hip_bfloat16*)(zfull + (size_t)BB * NN * 512);   // 8192*512 bf16

    const double invM_edge = 1.0 / ((double)BB * NN * KNNK);
    const int nbn = BB * NN;

    // ---- Stage 1: in = x (B,N,3), out ch [0,64) ----
    knn3_fused<<<nbn / 8, 256, 0, stream>>>(x, w1, zfull, idxb);
    gatherstats_k<128><<<nbn / 4, 256, 0, stream>>>(zfull, idxb, ymax, ymin, psum, psumsq);
    bnred1_k<<<dim3(1, 32), 256, 0, stream>>>(psum, psumsq, 64, r1s, r1q);
    epitrans2_k<64><<<128, 256, 0, stream>>>(ymax, ymin, r1s, r1q, g1, b1, invM_edge, xtcat, 0, xT, sqn, xbf);

    // ---- Stage 2: in ch [0,64), out [64,128) ----
    knn_fused<64><<<nbn / 8, 256, 0, stream>>>(xT, xtcat, 0, sqn, idxb);
    zgemm_k<64, 128><<<nbn / 16, 256, 0, stream>>>(xtcat, 0, w2, zfull);
    gatherstats_k<128><<<nbn / 4, 256, 0, stream>>>(zfull, idxb, ymax, ymin, psum, psumsq);
    bnred1_k<<<dim3(1, 32), 256, 0, stream>>>(psum, psumsq, 64, r1s, r1q);
    epitrans2_k<64><<<128, 256, 0, stream>>>(ymax, ymin, r1s, r1q, g2, b2, invM_edge, xtcat, 64, xT, sqn, xbf);

    // ---- Stage 3: in ch [64,128), out [128,256) ----
    knn_fused<64><<<nbn / 8, 256, 0, stream>>>(xT, xtcat, 64, sqn, idxb);
    zgemm_k<64, 256><<<nbn / 16, 256, 0, stream>>>(xtcat, 64, w3, zfull);
    gatherstats_k<256><<<nbn / 4, 256, 0, stream>>>(zfull, idxb, ymax, ymin, psum, psumsq);
    bnred1_k<<<dim3(2, 32), 256, 0, stream>>>(psum, psumsq, 128, r1s, r1q);
    epitrans2_k<128><<<128, 256, 0, stream>>>(ymax, ymin, r1s, r1q, g3, b3, invM_edge, xtcat, 128, xT, sqn, xbf);

    // ---- Stage 4: in ch [128,256), out [256,512) ----
    knn_fused<128><<<nbn / 8, 256, 0, stream>>>(xT, xtcat, 128, sqn, idxb);
    zgemm4_mfma<<<256, 256, 0, stream>>>(xtcat, w4, zf4);
    gatherstats4_k<<<nbn / 4, 256, 0, stream>>>(zf4, idxb, ymax, ymin, psum, psumsq);
    bnred1_k<<<dim3(4, 32), 256, 0, stream>>>(psum, psumsq, 256, r1s, r1q);
    epilogue4_k<<<128, 256, 0, stream>>>(ymax, ymin, r1s, r1q, g4, b4, invM_edge, xbf);

    // ---- Stage 5 ----
    gemm5_mfma<<<256, 256, 0, stream>>>(xbf, w5, pmax, pmn, ps5, pq5);
    bnstat5_k<<<8, 256, 0, stream>>>(ps5, pq5, g5, b5, s_arr, t_arr);
    featgemm_k<<<BB, 256, 0, stream>>>(pmax, pmn, s_arr, t_arr, wemb, out);
}

// Round 12
// 509.634 us; speedup vs baseline: 1.5677x; 1.0195x over previous
//
#include <hip/hip_runtime.h>
#include <hip/hip_bf16.h>
#include <math.h>

#define BB 8
#define NN 1024
#define KNNK 20
#define LDC 512

typedef __attribute__((ext_vector_type(8))) short bfrag8;
typedef __attribute__((ext_vector_type(4))) float facc4;
typedef __attribute__((ext_vector_type(2))) float v2f;

struct bh8 { __hip_bfloat16 h[8]; };

__device__ __forceinline__ bh8 cvt8(float4 a, float4 b) {
    bh8 v;
    v.h[0] = __float2bfloat16(a.x); v.h[1] = __float2bfloat16(a.y);
    v.h[2] = __float2bfloat16(a.z); v.h[3] = __float2bfloat16(a.w);
    v.h[4] = __float2bfloat16(b.x); v.h[5] = __float2bfloat16(b.y);
    v.h[6] = __float2bfloat16(b.z); v.h[7] = __float2bfloat16(b.w);
    return v;
}

// ---------------- top-20 selection: per-lane sort + head-merge (exact values) ----------------
// Sorted values stored conflict-free at [j*64+lane] (scalar writes); head-merge reads are
// single-lane. Exact fp32 compares throughout.
__device__ __forceinline__ void select20_srt(float (*dist)[1024],
                                             unsigned char (*slotpk)[512],
                                             int q0, int w, int lane,
                                             int* __restrict__ idxout) {
    float d[2][16];
    int   sl[2][16];
#pragma unroll
    for (int qi = 0; qi < 2; qi++) {
        int row = w * 2 + qi;
#pragma unroll
        for (int j = 0; j < 16; j++) { d[qi][j] = dist[row][lane + 64 * j]; sl[qi][j] = j; }
    }
    // Batcher odd-even mergesort, n=16, 63 comparators
    constexpr unsigned char CA[63] = {
        0,2,4,6,8,10,12,14,
        0,1,4,5,8,9,12,13,
        1,5,9,13,
        0,1,2,3,8,9,10,11,
        2,3,10,11,
        1,3,5,9,11,13,
        0,1,2,3,4,5,6,7,
        4,5,6,7,
        2,3,6,7,10,11,
        1,3,5,7,9,11,13};
    constexpr unsigned char CB[63] = {
        1,3,5,7,9,11,13,15,
        2,3,6,7,10,11,14,15,
        2,6,10,14,
        4,5,6,7,12,13,14,15,
        4,5,12,13,
        2,4,6,10,12,14,
        8,9,10,11,12,13,14,15,
        8,9,10,11,
        4,5,8,9,12,13,
        2,4,6,8,10,12,14};
#pragma unroll
    for (int c = 0; c < 63; c++) {
        const int a = CA[c], bq = CB[c];
#pragma unroll
        for (int qi = 0; qi < 2; qi++) {
            bool sw = d[qi][a] < d[qi][bq];
            float dmx = sw ? d[qi][bq] : d[qi][a];
            float dmn = sw ? d[qi][a]  : d[qi][bq];
            d[qi][a] = dmx; d[qi][bq] = dmn;
            int smx = sw ? sl[qi][bq] : sl[qi][a];
            int smn = sw ? sl[qi][a]  : sl[qi][bq];
            sl[qi][a] = smx; sl[qi][bq] = smn;
        }
    }
    // write sorted values (conflict-free layout j*64+lane) + packed slot nibbles
#pragma unroll
    for (int qi = 0; qi < 2; qi++) {
        int row = w * 2 + qi;
#pragma unroll
        for (int j = 0; j < 16; j++) dist[row][j * 64 + lane] = d[qi][j];
        unsigned int pk0 = 0, pk1 = 0;
#pragma unroll
        for (int j = 0; j < 8; j++) pk0 |= (unsigned)sl[qi][j] << (4 * j);
#pragma unroll
        for (int j = 0; j < 8; j++) pk1 |= (unsigned)sl[qi][8 + j] << (4 * j);
        *(unsigned int*)&slotpk[row][lane * 8]     = pk0;
        *(unsigned int*)&slotpk[row][lane * 8 + 4] = pk1;
    }
    float head[2] = {d[0][0], d[1][0]};
    int ptr[2] = {0, 0};
    for (int t = 0; t < KNNK; t++) {
#pragma unroll
        for (int qi = 0; qi < 2; qi++) {
            int row = w * 2 + qi;
            float bv = head[qi];
#pragma unroll
            for (int s = 1; s < 64; s <<= 1) bv = fmaxf(bv, __shfl_xor(bv, s));
            unsigned long long ball = __ballot(head[qi] == bv);
            int wl = (int)__builtin_ctzll(ball);
            if (lane == wl) {
                int pp = ptr[qi];
                int slot = (slotpk[row][lane * 8 + (pp >> 1)] >> (4 * (pp & 1))) & 15;
                idxout[(q0 + row) * KNNK + t] = slot * 64 + lane;
                pp++;
                ptr[qi] = pp;
                int a = (pp < 16 ? pp : 15) * 64 + lane;
                float nv = dist[row][a];
                head[qi] = (pp < 16) ? nv : -INFINITY;
            }
        }
    }
}

// ---------------- fused kNN stage 1 (C=3) + stage-1 z-gemm, 8 queries/block ----------------
__global__ __launch_bounds__(256, 4) void knn3_fused(const float* __restrict__ x,
                                                     const float* __restrict__ w1,
                                                     float* __restrict__ zf,
                                                     int* __restrict__ idxout) {
    __shared__ float dist[8][1024];
    __shared__ __align__(8) unsigned char slotpk[8][512];
    int tid = threadIdx.x;
    int q0 = blockIdx.x * 8;
    int b = q0 >> 10;
    const float* xb = x + (size_t)b * NN * 3;
    int lane = tid & 63, w = tid >> 6;
    float qx[8], qy[8], qz[8];
#pragma unroll
    for (int q = 0; q < 8; q++) {
        const float* qr = xb + (size_t)((q0 & (NN - 1)) + q) * 3;
        qx[q] = qr[0]; qy[q] = qr[1]; qz[q] = qr[2];
    }
#pragma unroll
    for (int cq = 0; cq < 4; cq++) {
        int cand = w * 256 + cq * 64 + lane;
        const float* cr = xb + (size_t)cand * 3;
        float cx = cr[0], cy = cr[1], cz = cr[2];
        float sqc = 0.f;
        sqc += cx * cx; sqc += cy * cy; sqc += cz * cz;
#pragma unroll
        for (int q = 0; q < 8; q++) {
            float d = qx[q] * cx + qy[q] * cy + qz[q] * cz;
            dist[q][cand] = 2.f * d - sqc;
        }
    }
    // fused stage-1 z-gemm for this block's 8 queries
    for (int i = tid; i < 8 * 128; i += 256) {
        int lq = i >> 7, j = i & 127;
        const float* wr = w1 + (j < 64 ? j * 6 : (j - 64) * 6 + 3);
        const float* xr = x + (size_t)(q0 + lq) * 3;
        zf[(size_t)(q0 + lq) * 128 + j] = wr[0] * xr[0] + wr[1] * xr[1] + wr[2] * xr[2];
    }
    __syncthreads();
    select20_srt(dist, slotpk, q0, w, lane, idxout);
}

// ---------------- fused kNN stages 2-4, 8 queries/block, packed-fp32 (v_pk_fma_f32) ----------------
// qsT channel-major so query-pairs are adjacent; acc2[cand][qpair] in float2 registers.
template<int C>
__global__ __launch_bounds__(256, 4) void knn_fused(const float* __restrict__ xT,
                                                    const float* __restrict__ xt, int off,
                                                    const float* __restrict__ sqn,
                                                    int* __restrict__ idxout) {
    __shared__ float dist[8][1024];
    __shared__ __align__(8) unsigned char slotpk[8][512];
    __shared__ __align__(16) float qsT[C][8];
    int tid = threadIdx.x;
    int q0 = blockIdx.x * 8;
    int b = q0 >> 10;
    const float* xb = xt + (size_t)b * NN * LDC + off;
    for (int j = tid; j < 2 * C; j += 256) {
        int c = j % C, ph = j / C;
        int pb = (q0 & (NN - 1)) + ph * 4;
        float4 v;
        v.x = xb[(size_t)(pb + 0) * LDC + c];
        v.y = xb[(size_t)(pb + 1) * LDC + c];
        v.z = xb[(size_t)(pb + 2) * LDC + c];
        v.w = xb[(size_t)(pb + 3) * LDC + c];
        *(float4*)&qsT[c][ph * 4] = v;
    }
    __syncthreads();
    int lane = tid & 63, w = tid >> 6;
    int cand0 = w * 256 + 4 * lane;
    const float* xTb = xT + (size_t)b * C * 1024;
    float4 sq4 = *(const float4*)(sqn + b * NN + cand0);
    v2f acc2[4][4];          // [cand j][query-pair p]
#pragma unroll
    for (int j = 0; j < 4; j++)
#pragma unroll
        for (int p = 0; p < 4; p++) acc2[j][p] = (v2f){0.f, 0.f};
    for (int cg = 0; cg < C / 4; cg++) {
        float4 rch[4];
#pragma unroll
        for (int c = 0; c < 4; c++)
            rch[c] = *(const float4*)(xTb + (size_t)(4 * cg + c) * 1024 + cand0);
#pragma unroll
        for (int c = 0; c < 4; c++) {
            float4 qa = *(const float4*)&qsT[4 * cg + c][0];
            float4 qb = *(const float4*)&qsT[4 * cg + c][4];
            v2f qp[4] = {{qa.x, qa.y}, {qa.z, qa.w}, {qb.x, qb.y}, {qb.z, qb.w}};
            float rj[4] = {rch[c].x, rch[c].y, rch[c].z, rch[c].w};
#pragma unroll
            for (int j = 0; j < 4; j++) {
                v2f rr = {rj[j], rj[j]};
                acc2[j][0] += rr * qp[0];
                acc2[j][1] += rr * qp[1];
                acc2[j][2] += rr * qp[2];
                acc2[j][3] += rr * qp[3];
            }
        }
    }
#pragma unroll
    for (int p = 0; p < 4; p++)
#pragma unroll
        for (int half = 0; half < 2; half++) {
            int q = 2 * p + half;
            float4 dv;
            dv.x = 2.f * acc2[0][p][half] - sq4.x;
            dv.y = 2.f * acc2[1][p][half] - sq4.y;
            dv.z = 2.f * acc2[2][p][half] - sq4.z;
            dv.w = 2.f * acc2[3][p][half] - sq4.w;
            *(float4*)&dist[q][cand0] = dv;
        }
    __syncthreads();
    select20_srt(dist, slotpk, q0, w, lane, idxout);
}

// ---------------- z-gemm (fp32, stages 2-3) ----------------
template<int C, int O2>
__global__ __launch_bounds__(256) void zgemm_k(const float* __restrict__ xt, int off,
                                               const float* __restrict__ w,
                                               float* __restrict__ zf) {
    constexpr int O = O2 / 2;
    __shared__ __align__(16) float xs[16][C];
    int p0 = blockIdx.x * 16;
    int tid = threadIdx.x;
    for (int j = tid; j < 16 * (C / 4); j += 256) {
        int p = j / (C / 4), c4 = j % (C / 4);
        *(float4*)&xs[p][4 * c4] = *(const float4*)(xt + (size_t)(p0 + p) * LDC + off + 4 * c4);
    }
    __syncthreads();
    for (int j = tid; j < O2; j += 256) {
        const float* wr = w + (j < O ? (size_t)j * 2 * C : (size_t)(j - O) * 2 * C + C);
        float acc[16];
#pragma unroll
        for (int p = 0; p < 16; p++) acc[p] = 0.f;
        for (int c4 = 0; c4 < C / 4; c4++) {
            float4 wv = *(const float4*)(wr + 4 * c4);
#pragma unroll
            for (int p = 0; p < 16; p++) {
                float4 xv = *(const float4*)&xs[p][4 * c4];
                acc[p] += wv.x * xv.x + wv.y * xv.y + wv.z * xv.z + wv.w * xv.w;
            }
        }
#pragma unroll
        for (int p = 0; p < 16; p++) zf[(size_t)(p0 + p) * O2 + j] = acc[p];
    }
}

// ---------------- stage-4 z-gemm: bf16 MFMA, bf16 output ----------------
__global__ __launch_bounds__(256) void zgemm4_mfma(const float* __restrict__ xtcat,
                                                   const float* __restrict__ w4,
                                                   __hip_bfloat16* __restrict__ zf4) {
    __shared__ __hip_bfloat16 A[128][72];
    __shared__ __hip_bfloat16 W[128][72];
    int mt = blockIdx.x >> 2, nt = blockIdx.x & 3;
    int tid = threadIdx.x;
    int lane = tid & 63, wvx = tid >> 6;
    int mw = wvx >> 1, nw = wvx & 1;
    int m0 = lane & 15, qd = lane >> 4;
    int r = tid & 127, hf = tid >> 7;
    facc4 acc[4][4];
    facc4 zz = {0.f, 0.f, 0.f, 0.f};
#pragma unroll
    for (int mi = 0; mi < 4; mi++)
#pragma unroll
        for (int ni = 0; ni < 4; ni++) acc[mi][ni] = zz;
    int j = nt * 128 + r;
    const float* wsrc = w4 + (j < 256 ? (size_t)j * 256 : (size_t)(j - 256) * 256 + 128);
    const float* asrc = xtcat + (size_t)(mt * 128 + r) * 512 + 128;
    for (int kc = 0; kc < 2; kc++) {
#pragma unroll
        for (int u = 0; u < 4; u++) {
            int c0 = kc * 64 + hf * 32 + 8 * u;
            float4 a0 = *(const float4*)(asrc + c0);
            float4 a1 = *(const float4*)(asrc + c0 + 4);
            *(bh8*)&A[r][hf * 32 + 8 * u] = cvt8(a0, a1);
            float4 w0 = *(const float4*)(wsrc + c0);
            float4 w1 = *(const float4*)(wsrc + c0 + 4);
            *(bh8*)&W[r][hf * 32 + 8 * u] = cvt8(w0, w1);
        }
        __syncthreads();
#pragma unroll
        for (int kk = 0; kk < 2; kk++) {
            bfrag8 af[4], bf[4];
#pragma unroll
            for (int mi = 0; mi < 4; mi++)
                af[mi] = *(const bfrag8*)&A[64 * mw + 16 * mi + m0][32 * kk + 8 * qd];
#pragma unroll
            for (int ni = 0; ni < 4; ni++)
                bf[ni] = *(const bfrag8*)&W[64 * nw + 16 * ni + m0][32 * kk + 8 * qd];
#pragma unroll
            for (int mi = 0; mi < 4; mi++)
#pragma unroll
                for (int ni = 0; ni < 4; ni++)
                    acc[mi][ni] = __builtin_amdgcn_mfma_f32_16x16x32_bf16(af[mi], bf[ni], acc[mi][ni], 0, 0, 0);
        }
        __syncthreads();
    }
#pragma unroll
    for (int mi = 0; mi < 4; mi++)
#pragma unroll
        for (int ni = 0; ni < 4; ni++)
#pragma unroll
            for (int rg = 0; rg < 4; rg++) {
                int row = mt * 128 + mw * 64 + mi * 16 + qd * 4 + rg;
                int col = nt * 128 + nw * 64 + ni * 16 + m0;
                zf4[(size_t)row * 512 + col] = __float2bfloat16(acc[mi][ni][rg]);
            }
}

// ---------------- gather + stats (fp32 zf, stages 1-3) ----------------
template<int O2>
__global__ __launch_bounds__(256) void gatherstats_k(const float* __restrict__ zf,
                                                     const int* __restrict__ idx,
                                                     float* __restrict__ ymax, float* __restrict__ ymin,
                                                     float* __restrict__ psum, float* __restrict__ psumsq) {
    constexpr int O = O2 / 2;
    int wv = threadIdx.x >> 6, lane = threadIdx.x & 63;
    int n = blockIdx.x * 4 + wv;
    int b = n >> 10;
    const float* zbatch = zf + (size_t)b * NN * O2;
    int nb[KNNK];
#pragma unroll
    for (int k = 0; k < KNNK; k++) nb[k] = idx[n * KNNK + k];
#pragma unroll
    for (int ch = 0; ch < O / 64; ch++) {
        int o = ch * 64 + lane;
        float g[KNNK];
#pragma unroll
        for (int k = 0; k < KNNK; k++) g[k] = zbatch[(size_t)nb[k] * O2 + o];
        float mx = -INFINITY, mn = INFINITY, s = 0.f, ss = 0.f;
#pragma unroll
        for (int k = 0; k < KNNK; k++) {
            float v = g[k];
            mx = fmaxf(mx, v); mn = fminf(mn, v); s += v; ss += v * v;
        }
        float zn  = zf[(size_t)n * O2 + o];
        float zbn = zf[(size_t)n * O2 + O + o];
        float d = zbn - zn;
        mx += d; mn += d;
        ss = ss + 2.f * d * s + (float)KNNK * d * d;
        s  = s + (float)KNNK * d;
        ymax  [(size_t)n * O + o] = mx;
        ymin  [(size_t)n * O + o] = mn;
        psum  [(size_t)n * O + o] = s;
        psumsq[(size_t)n * O + o] = ss;
    }
}

// ---------------- gather + stats, bf16 zf4 (stage 4) ----------------
__global__ __launch_bounds__(256) void gatherstats4_k(const __hip_bfloat16* __restrict__ zf4,
                                                      const int* __restrict__ idx,
                                                      float* __restrict__ ymax, float* __restrict__ ymin,
                                                      float* __restrict__ psum, float* __restrict__ psumsq) {
    int wv = threadIdx.x >> 6, lane = threadIdx.x & 63;
    int n = blockIdx.x * 4 + wv;
    int b = n >> 10;
    const __hip_bfloat16* zbatch = zf4 + (size_t)b * NN * 512;
    int nb[KNNK];
#pragma unroll
    for (int k = 0; k < KNNK; k++) nb[k] = idx[n * KNNK + k];
#pragma unroll
    for (int ch = 0; ch < 4; ch++) {
        int o = ch * 64 + lane;
        float g[KNNK];
#pragma unroll
        for (int k = 0; k < KNNK; k++) g[k] = __bfloat162float(zbatch[(size_t)nb[k] * 512 + o]);
        float mx = -INFINITY, mn = INFINITY, s = 0.f, ss = 0.f;
#pragma unroll
        for (int k = 0; k < KNNK; k++) {
            float v = g[k];
            mx = fmaxf(mx, v); mn = fminf(mn, v); s += v; ss += v * v;
        }
        float zn  = __bfloat162float(zf4[(size_t)n * 512 + o]);
        float zbn = __bfloat162float(zf4[(size_t)n * 512 + 256 + o]);
        float d = zbn - zn;
        mx += d; mn += d;
        ss = ss + 2.f * d * s + (float)KNNK * d * d;
        s  = s + (float)KNNK * d;
        ymax  [(size_t)n * 256 + o] = mx;
        ymin  [(size_t)n * 256 + o] = mn;
        psum  [(size_t)n * 256 + o] = ss * 0.f + s;
        psumsq[(size_t)n * 256 + o] = ss;
    }
}

// ---------------- BN reduce pass 1 ----------------
__global__ __launch_bounds__(256) void bnred1_k(const float* __restrict__ pn, const float* __restrict__ pq,
                                                int O, float* __restrict__ r1s, float* __restrict__ r1q) {
    __shared__ float ls[4][64], lq[4][64];
    int lane = threadIdx.x & 63, wv = threadIdx.x >> 6;
    int o = blockIdx.x * 64 + lane;
    int n0 = blockIdx.y * 256;
    float s = 0.f, q = 0.f;
    for (int r = wv; r < 256; r += 4) {
        s += pn[(size_t)(n0 + r) * O + o];
        q += pq[(size_t)(n0 + r) * O + o];
    }
    ls[wv][lane] = s; lq[wv][lane] = q;
    __syncthreads();
    if (wv == 0) {
        s = ls[0][lane] + ls[1][lane] + ls[2][lane] + ls[3][lane];
        q = lq[0][lane] + lq[1][lane] + lq[2][lane] + lq[3][lane];
        r1s[(size_t)blockIdx.y * O + o] = s;
        r1q[(size_t)blockIdx.y * O + o] = q;
    }
}

// ---------------- BN+lrelu epilogue + transpose + |c|^2 + bf16 copy, s/t computed in-block ----------------
template<int O>
__global__ __launch_bounds__(256) void epitrans2_k(const float* __restrict__ ymax, const float* __restrict__ ymin,
                                                   const float* __restrict__ r1s, const float* __restrict__ r1q,
                                                   const float* __restrict__ g, const float* __restrict__ beta,
                                                   double invM,
                                                   float* __restrict__ xtcat, int off_out,
                                                   float* __restrict__ xT, float* __restrict__ sqn,
                                                   __hip_bfloat16* __restrict__ xbf) {
    __shared__ float tile[64][O + 1];
    __shared__ float ssh[O], tth[O];
    int n0 = blockIdx.x * 64;
    int b = n0 >> 10;
    int tid = threadIdx.x;
    for (int o = tid; o < O; o += 256) {
        double sd = 0.0, qd = 0.0;
        for (int r = 0; r < 32; r++) { sd += r1s[(size_t)r * O + o]; qd += r1q[(size_t)r * O + o]; }
        double mean = sd * invM;
        double var = qd * invM - mean * mean;
        float inv = (float)(1.0 / sqrt(var + 1e-5));
        float sc = g[o] * inv;
        ssh[o] = sc;
        tth[o] = beta[o] - (float)mean * sc;
    }
    __syncthreads();
    for (int i = tid; i < 64 * O; i += 256) {
        int nl = i / O;
        int o = i & (O - 1);
        int n = n0 + nl;
        float sc = ssh[o];
        float v = sc >= 0.f ? ymax[(size_t)n * O + o] : ymin[(size_t)n * O + o];
        float y = sc * v + tth[o];
        y = y >= 0.f ? y : 0.2f * y;
        xtcat[(size_t)n * LDC + off_out + o] = y;
        xbf[(size_t)n * LDC + off_out + o] = __float2bfloat16(y);
        tile[nl][o] = y;
    }
    __syncthreads();
    if (tid < 64) {
        float sq = 0.f;
        for (int c = 0; c < O; c++) { float v = tile[tid][c]; sq += v * v; }
        sqn[n0 + tid] = sq;
    }
    int r = tid >> 4, cq = tid & 15;
#pragma unroll
    for (int ct = 0; ct < O / 16; ct++) {
        int c = ct * 16 + r;
        float4 ov;
        ov.x = tile[4 * cq + 0][c];
        ov.y = tile[4 * cq + 1][c];
        ov.z = tile[4 * cq + 2][c];
        ov.w = tile[4 * cq + 3][c];
        *(float4*)(xT + ((size_t)b * O + c) * 1024 + (n0 & (NN - 1)) + 4 * cq) = ov;
    }
}

// ---------------- stage-4 epilogue: s/t in-block, writes xbf ONLY ----------------
__global__ __launch_bounds__(256) void epilogue4_k(const float* __restrict__ ymax, const float* __restrict__ ymin,
                                                   const float* __restrict__ r1s, const float* __restrict__ r1q,
                                                   const float* __restrict__ g, const float* __restrict__ beta,
                                                   double invM,
                                                   __hip_bfloat16* __restrict__ xbf) {
    __shared__ float ssh[256], tth[256];
    int n0 = blockIdx.x * 64;
    int tid = threadIdx.x;
    {
        int o = tid;
        double sd = 0.0, qd = 0.0;
        for (int r = 0; r < 32; r++) { sd += r1s[(size_t)r * 256 + o]; qd += r1q[(size_t)r * 256 + o]; }
        double mean = sd * invM;
        double var = qd * invM - mean * mean;
        float inv = (float)(1.0 / sqrt(var + 1e-5));
        float sc = g[o] * inv;
        ssh[o] = sc;
        tth[o] = beta[o] - (float)mean * sc;
    }
    __syncthreads();
    for (int i = tid; i < 64 * 256; i += 256) {
        int nl = i >> 8;
        int o = i & 255;
        int n = n0 + nl;
        float sc = ssh[o];
        float v = sc >= 0.f ? ymax[(size_t)n * 256 + o] : ymin[(size_t)n * 256 + o];
        float y = sc * v + tth[o];
        y = y >= 0.f ? y : 0.2f * y;
        xbf[(size_t)n * LDC + 256 + o] = __float2bfloat16(y);
    }
}

// ---------------- stage 5: bf16 MFMA GEMM (W staged from fp32 w5) w/ fused stats ----------------
__global__ __launch_bounds__(256) void gemm5_mfma(const __hip_bfloat16* __restrict__ xbf,
                                                  const float* __restrict__ w5,
                                                  float* __restrict__ pmax, float* __restrict__ pmn,
                                                  float* __restrict__ ps, float* __restrict__ pq) {
    __shared__ __hip_bfloat16 A[128][72];
    __shared__ __hip_bfloat16 W[128][72];
    int mt = blockIdx.x >> 2, nt = blockIdx.x & 3;
    int tid = threadIdx.x;
    int lane = tid & 63, wvx = tid >> 6;
    int mw = wvx >> 1, nw = wvx & 1;
    int m0 = lane & 15, qd = lane >> 4;
    int r = tid & 127, hf = tid >> 7;
    facc4 acc[4][4];
    facc4 zz = {0.f, 0.f, 0.f, 0.f};
#pragma unroll
    for (int mi = 0; mi < 4; mi++)
#pragma unroll
        for (int ni = 0; ni < 4; ni++) acc[mi][ni] = zz;
    for (int kc = 0; kc < 8; kc++) {
        const __hip_bfloat16* ap = xbf + (size_t)(mt * 128 + r) * 512 + kc * 64 + hf * 32;
        const float* wp = w5 + (size_t)(nt * 128 + r) * 512 + kc * 64 + hf * 32;
#pragma unroll
        for (int u = 0; u < 4; u++) {
            bh8 av = *(const bh8*)(ap + 8 * u);
            *(bh8*)&A[r][hf * 32 + 8 * u] = av;
            float4 w0 = *(const float4*)(wp + 8 * u);
            float4 w1 = *(const float4*)(wp + 8 * u + 4);
            *(bh8*)&W[r][hf * 32 + 8 * u] = cvt8(w0, w1);
        }
        __syncthreads();
#pragma unroll
        for (int kk = 0; kk < 2; kk++) {
            bfrag8 af[4], bf[4];
#pragma unroll
            for (int mi = 0; mi < 4; mi++)
                af[mi] = *(const bfrag8*)&A[64 * mw + 16 * mi + m0][32 * kk + 8 * qd];
#pragma unroll
            for (int ni = 0; ni < 4; ni++)
                bf[ni] = *(const bfrag8*)&W[64 * nw + 16 * ni + m0][32 * kk + 8 * qd];
#pragma unroll
            for (int mi = 0; mi < 4; mi++)
#pragma unroll
                for (int ni = 0; ni < 4; ni++)
                    acc[mi][ni] = __builtin_amdgcn_mfma_f32_16x16x32_bf16(af[mi], bf[ni], acc[mi][ni], 0, 0, 0);
        }
        __syncthreads();
    }
#pragma unroll
    for (int mi = 0; mi < 4; mi++) {
        int grp = mt * 8 + mw * 4 + mi;
#pragma unroll
        for (int ni = 0; ni < 4; ni++) {
            float mx = -INFINITY, mn = INFINITY, s = 0.f, ss = 0.f;
#pragma unroll
            for (int rg = 0; rg < 4; rg++) {
                float v = acc[mi][ni][rg];
                mx = fmaxf(mx, v); mn = fminf(mn, v); s += v; ss += v * v;
            }
#pragma unroll
            for (int m = 16; m < 64; m <<= 1) {
                mx = fmaxf(mx, __shfl_xor(mx, m));
                mn = fminf(mn, __shfl_xor(mn, m));
                s += __shfl_xor(s, m);
                ss += __shfl_xor(ss, m);
            }
            if (qd == 0) {
                int o = nt * 128 + nw * 64 + ni * 16 + m0;
                pmax[(size_t)grp * 512 + o] = mx;
                pmn [(size_t)grp * 512 + o] = mn;
                ps  [(size_t)grp * 512 + o] = s;
                pq  [(size_t)grp * 512 + o] = ss;
            }
        }
    }
}

// ---------------- stage-5 BN stats ----------------
__global__ __launch_bounds__(256) void bnstat5_k(const float* __restrict__ ps, const float* __restrict__ pq,
                                                 const float* __restrict__ g, const float* __restrict__ beta,
                                                 float* __restrict__ s_out, float* __restrict__ t_out) {
    __shared__ double lds_s[4][64], lds_q[4][64];
    int lane = threadIdx.x & 63, wv = threadIdx.x >> 6;
    int o = blockIdx.x * 64 + lane;
    double s = 0.0, q = 0.0;
    for (int r = wv; r < 512; r += 4) {
        s += ps[(size_t)r * 512 + o];
        q += pq[(size_t)r * 512 + o];
    }
    lds_s[wv][lane] = s; lds_q[wv][lane] = q;
    __syncthreads();
    if (wv == 0) {
        s = lds_s[0][lane] + lds_s[1][lane] + lds_s[2][lane] + lds_s[3][lane];
        q = lds_q[0][lane] + lds_q[1][lane] + lds_q[2][lane] + lds_q[3][lane];
        double invM = 1.0 / (BB * NN);
        double mean = s * invM;
        double var = q * invM - mean * mean;
        float inv = (float)(1.0 / sqrt(var + 1e-5));
        float sc = g[o] * inv;
        s_out[o] = sc;
        t_out[o] = beta[o] - (float)mean * sc;
    }
}

// ---------------- per-batch max/min reduce + BN + lrelu + feat @ wemb^T ----------------
__global__ __launch_bounds__(256) void featgemm_k(const float* __restrict__ pmax, const float* __restrict__ pmn,
                                                  const float* __restrict__ s, const float* __restrict__ t,
                                                  const float* __restrict__ wemb, float* __restrict__ out) {
    __shared__ __align__(16) float feat[512];
    int b = blockIdx.x, tid = threadIdx.x;
    for (int o = tid; o < 512; o += 256) {
        float mx = -INFINITY, mn = INFINITY;
        for (int r = b * 64; r < (b + 1) * 64; r++) {
            mx = fmaxf(mx, pmax[(size_t)r * 512 + o]);
            mn = fminf(mn, pmn [(size_t)r * 512 + o]);
        }
        float sc = s[o];
        float v = sc >= 0.f ? mx : mn;
        float y = sc * v + t[o];
        feat[o] = y >= 0.f ? y : 0.2f * y;
    }
    __syncthreads();
    const float4* wr = (const float4*)(wemb + (size_t)tid * 512);
    float acc = 0.f;
    for (int c4 = 0; c4 < 128; c4++) {
        float4 wv = wr[c4];
        float4 fv = *(const float4*)&feat[c4 * 4];
        acc += wv.x * fv.x + wv.y * fv.y + wv.z * fv.z + wv.w * fv.w;
    }
    out[(size_t)b * 256 + tid] = acc;
}

extern "C" void kernel_launch(void* const* d_in, const int* in_sizes, int n_in,
                              void* d_out, int out_size, void* d_ws, size_t ws_size,
                              hipStream_t stream) {
    const float* x    = (const float*)d_in[0];
    const float* w1   = (const float*)d_in[1];
    const float* g1   = (const float*)d_in[2];
    const float* b1   = (const float*)d_in[3];
    const float* w2   = (const float*)d_in[4];
    const float* g2   = (const float*)d_in[5];
    const float* b2   = (const float*)d_in[6];
    const float* w3   = (const float*)d_in[7];
    const float* g3   = (const float*)d_in[8];
    const float* b3   = (const float*)d_in[9];
    const float* w4   = (const float*)d_in[10];
    const float* g4   = (const float*)d_in[11];
    const float* b4   = (const float*)d_in[12];
    const float* w5   = (const float*)d_in[13];
    const float* g5   = (const float*)d_in[14];
    const float* b5   = (const float*)d_in[15];
    const float* wemb = (const float*)d_in[16];
    float* out = (float*)d_out;

    float* fws    = (float*)d_ws;
    float* xtcat  = fws;                                 // 4,194,304
    float* ymax   = xtcat + (size_t)BB * NN * 512;       // 2,097,152
    float* ymin   = ymax + (size_t)BB * NN * 256;        // 2,097,152
    float* psum   = ymin + (size_t)BB * NN * 256;        // 2,097,152
    float* psumsq = psum + (size_t)BB * NN * 256;        // 2,097,152
    float* xT     = psum;                                // alias: psum dead in epitrans->knn window
    float* pmax   = ymax;                                // alias: stage-5 partials
    float* pmn    = pmax + 512 * 512;
    float* ps5    = pmn + 512 * 512;
    float* pq5    = ps5 + 512 * 512;
    float* sqn    = psumsq + (size_t)BB * NN * 256;      // 8192
    float* s_arr  = sqn + BB * NN;                       // 512
    float* t_arr  = s_arr + 512;                         // 512
    float* r1s    = t_arr + 512;                         // 32*512
    float* r1q    = r1s + 32 * 512;                      // 32*512
    int*   idxb   = (int*)(r1q + 32 * 512);              // 8192*20 ints
    float* zfull  = (float*)(idxb + BB * NN * KNNK);     // 8192*512 fp32 (stages 1-3)
    __hip_bfloat16* zf4 = (__hip_bfloat16*)zfull;        // alias: stage-4 z, bf16
    __hip_bfloat16* xbf = (__hip_bfloat16*)(zfull + (size_t)BB * NN * 512);   // 8192*512 bf16

    const double invM_edge = 1.0 / ((double)BB * NN * KNNK);
    const int nbn = BB * NN;

    // ---- Stage 1: in = x (B,N,3), out ch [0,64) ----
    knn3_fused<<<nbn / 8, 256, 0, stream>>>(x, w1, zfull, idxb);
    gatherstats_k<128><<<nbn / 4, 256, 0, stream>>>(zfull, idxb, ymax, ymin, psum, psumsq);
    bnred1_k<<<dim3(1, 32), 256, 0, stream>>>(psum, psumsq, 64, r1s, r1q);
    epitrans2_k<64><<<128, 256, 0, stream>>>(ymax, ymin, r1s, r1q, g1, b1, invM_edge, xtcat, 0, xT, sqn, xbf);

    // ---- Stage 2: in ch [0,64), out [64,128) ----
    knn_fused<64><<<nbn / 8, 256, 0, stream>>>(xT, xtcat, 0, sqn, idxb);
    zgemm_k<64, 128><<<nbn / 16, 256, 0, stream>>>(xtcat, 0, w2, zfull);
    gatherstats_k<128><<<nbn / 4, 256, 0, stream>>>(zfull, idxb, ymax, ymin, psum, psumsq);
    bnred1_k<<<dim3(1, 32), 256, 0, stream>>>(psum, psumsq, 64, r1s, r1q);
    epitrans2_k<64><<<128, 256, 0, stream>>>(ymax, ymin, r1s, r1q, g2, b2, invM_edge, xtcat, 64, xT, sqn, xbf);

    // ---- Stage 3: in ch [64,128), out [128,256) ----
    knn_fused<64><<<nbn / 8, 256, 0, stream>>>(xT, xtcat, 64, sqn, idxb);
    zgemm_k<64, 256><<<nbn / 16, 256, 0, stream>>>(xtcat, 64, w3, zfull);
    gatherstats_k<256><<<nbn / 4, 256, 0, stream>>>(zfull, idxb, ymax, ymin, psum, psumsq);
    bnred1_k<<<dim3(2, 32), 256, 0, stream>>>(psum, psumsq, 128, r1s, r1q);
    epitrans2_k<128><<<128, 256, 0, stream>>>(ymax, ymin, r1s, r1q, g3, b3, invM_edge, xtcat, 128, xT, sqn, xbf);

    // ---- Stage 4: in ch [128,256), out [256,512) ----
    knn_fused<128><<<nbn / 8, 256, 0, stream>>>(xT, xtcat, 128, sqn, idxb);
    zgemm4_mfma<<<256, 256, 0, stream>>>(xtcat, w4, zf4);
    gatherstats4_k<<<nbn / 4, 256, 0, stream>>>(zf4, idxb, ymax, ymin, psum, psumsq);
    bnred1_k<<<dim3(4, 32), 256, 0, stream>>>(psum, psumsq, 256, r1s, r1q);
    epilogue4_k<<<128, 256, 0, stream>>>(ymax, ymin, r1s, r1q, g4, b4, invM_edge, xbf);

    // ---- Stage 5 ----
    gemm5_mfma<<<256, 256, 0, stream>>>(xbf, w5, pmax, pmn, ps5, pq5);
    bnstat5_k<<<8, 256, 0, stream>>>(ps5, pq5, g5, b5, s_arr, t_arr);
    featgemm_k<<<BB, 256, 0, stream>>>(pmax, pmn, s_arr, t_arr, wemb, out);
}

// Round 13
// 436.287 us; speedup vs baseline: 1.8312x; 1.1681x over previous
//
#include <hip/hip_runtime.h>
#include <hip/hip_bf16.h>
#include <math.h>

#define BB 8
#define NN 1024
#define KNNK 20
#define LDC 512

typedef __attribute__((ext_vector_type(8))) short bfrag8;
typedef __attribute__((ext_vector_type(4))) float facc4;
typedef __attribute__((ext_vector_type(2))) float v2f;

struct bh8 { __hip_bfloat16 h[8]; };

__device__ __forceinline__ bh8 cvt8(float4 a, float4 b) {
    bh8 v;
    v.h[0] = __float2bfloat16(a.x); v.h[1] = __float2bfloat16(a.y);
    v.h[2] = __float2bfloat16(a.z); v.h[3] = __float2bfloat16(a.w);
    v.h[4] = __float2bfloat16(b.x); v.h[5] = __float2bfloat16(b.y);
    v.h[6] = __float2bfloat16(b.z); v.h[7] = __float2bfloat16(b.w);
    return v;
}

// ---------------- top-20 selection: per-lane Batcher sort + head-merge (exact fp32) ----------------
__device__ __forceinline__ void select20_srt(float (*dist)[1024],
                                             unsigned char (*slotpk)[512],
                                             int q0, int w, int lane,
                                             int* __restrict__ idxout) {
    float d[2][16];
    int   sl[2][16];
#pragma unroll
    for (int qi = 0; qi < 2; qi++) {
        int row = w * 2 + qi;
#pragma unroll
        for (int j = 0; j < 16; j++) { d[qi][j] = dist[row][lane + 64 * j]; sl[qi][j] = j; }
    }
    constexpr unsigned char CA[63] = {
        0,2,4,6,8,10,12,14,
        0,1,4,5,8,9,12,13,
        1,5,9,13,
        0,1,2,3,8,9,10,11,
        2,3,10,11,
        1,3,5,9,11,13,
        0,1,2,3,4,5,6,7,
        4,5,6,7,
        2,3,6,7,10,11,
        1,3,5,7,9,11,13};
    constexpr unsigned char CB[63] = {
        1,3,5,7,9,11,13,15,
        2,3,6,7,10,11,14,15,
        2,6,10,14,
        4,5,6,7,12,13,14,15,
        4,5,12,13,
        2,4,6,10,12,14,
        8,9,10,11,12,13,14,15,
        8,9,10,11,
        4,5,8,9,12,13,
        2,4,6,8,10,12,14};
#pragma unroll
    for (int c = 0; c < 63; c++) {
        const int a = CA[c], bq = CB[c];
#pragma unroll
        for (int qi = 0; qi < 2; qi++) {
            bool sw = d[qi][a] < d[qi][bq];
            float dmx = sw ? d[qi][bq] : d[qi][a];
            float dmn = sw ? d[qi][a]  : d[qi][bq];
            d[qi][a] = dmx; d[qi][bq] = dmn;
            int smx = sw ? sl[qi][bq] : sl[qi][a];
            int smn = sw ? sl[qi][a]  : sl[qi][bq];
            sl[qi][a] = smx; sl[qi][bq] = smn;
        }
    }
#pragma unroll
    for (int qi = 0; qi < 2; qi++) {
        int row = w * 2 + qi;
#pragma unroll
        for (int j = 0; j < 16; j++) dist[row][j * 64 + lane] = d[qi][j];
        unsigned int pk0 = 0, pk1 = 0;
#pragma unroll
        for (int j = 0; j < 8; j++) pk0 |= (unsigned)sl[qi][j] << (4 * j);
#pragma unroll
        for (int j = 0; j < 8; j++) pk1 |= (unsigned)sl[qi][8 + j] << (4 * j);
        *(unsigned int*)&slotpk[row][lane * 8]     = pk0;
        *(unsigned int*)&slotpk[row][lane * 8 + 4] = pk1;
    }
    float head[2] = {d[0][0], d[1][0]};
    int ptr[2] = {0, 0};
    for (int t = 0; t < KNNK; t++) {
#pragma unroll
        for (int qi = 0; qi < 2; qi++) {
            int row = w * 2 + qi;
            float bv = head[qi];
#pragma unroll
            for (int s = 1; s < 64; s <<= 1) bv = fmaxf(bv, __shfl_xor(bv, s));
            unsigned long long ball = __ballot(head[qi] == bv);
            int wl = (int)__builtin_ctzll(ball);
            if (lane == wl) {
                int pp = ptr[qi];
                int slot = (slotpk[row][lane * 8 + (pp >> 1)] >> (4 * (pp & 1))) & 15;
                idxout[(q0 + row) * KNNK + t] = slot * 64 + lane;
                pp++;
                ptr[qi] = pp;
                int a = (pp < 16 ? pp : 15) * 64 + lane;
                float nv = dist[row][a];
                head[qi] = (pp < 16) ? nv : -INFINITY;
            }
        }
    }
}

// r1 zeroing helper (done by one designated block of the kernel preceding the gather)
__device__ __forceinline__ void zero_r1(float* r1s, float* r1q, int O, int tid) {
    for (int i = tid; i < 32 * O; i += 256) { r1s[i] = 0.f; r1q[i] = 0.f; }
}

// ---------------- fused kNN stage 1 (C=3) + stage-1 z-gemm, 8 queries/block ----------------
__global__ __launch_bounds__(256, 4) void knn3_fused(const float* __restrict__ x,
                                                     const float* __restrict__ w1,
                                                     float* __restrict__ zf,
                                                     int* __restrict__ idxout,
                                                     float* __restrict__ r1s, float* __restrict__ r1q) {
    __shared__ float dist[8][1024];
    __shared__ __align__(8) unsigned char slotpk[8][512];
    int tid = threadIdx.x;
    int q0 = (blockIdx.x & 7) * 1024 + (blockIdx.x >> 3) * 8;   // XCD swizzle
    int b = q0 >> 10;
    if (blockIdx.x == 0) zero_r1(r1s, r1q, 64, tid);
    const float* xb = x + (size_t)b * NN * 3;
    int lane = tid & 63, w = tid >> 6;
    float qx[8], qy[8], qz[8];
#pragma unroll
    for (int q = 0; q < 8; q++) {
        const float* qr = xb + (size_t)((q0 & (NN - 1)) + q) * 3;
        qx[q] = qr[0]; qy[q] = qr[1]; qz[q] = qr[2];
    }
#pragma unroll
    for (int cq = 0; cq < 4; cq++) {
        int cand = w * 256 + cq * 64 + lane;
        const float* cr = xb + (size_t)cand * 3;
        float cx = cr[0], cy = cr[1], cz = cr[2];
        float sqc = 0.f;
        sqc += cx * cx; sqc += cy * cy; sqc += cz * cz;
#pragma unroll
        for (int q = 0; q < 8; q++) {
            float d = qx[q] * cx + qy[q] * cy + qz[q] * cz;
            dist[q][cand] = 2.f * d - sqc;
        }
    }
    for (int i = tid; i < 8 * 128; i += 256) {
        int lq = i >> 7, j = i & 127;
        const float* wr = w1 + (j < 64 ? j * 6 : (j - 64) * 6 + 3);
        const float* xr = x + (size_t)(q0 + lq) * 3;
        zf[(size_t)(q0 + lq) * 128 + j] = wr[0] * xr[0] + wr[1] * xr[1] + wr[2] * xr[2];
    }
    __syncthreads();
    select20_srt(dist, slotpk, q0, w, lane, idxout);
}

// ---------------- knn core (stages 2-4), packed-fp32 dist + sort-select ----------------
template<int C>
__device__ __forceinline__ void knn_body(const float* __restrict__ xT,
                                         const float* __restrict__ xt, int off,
                                         const float* __restrict__ sqn,
                                         int* __restrict__ idxout,
                                         float (*dist)[1024], unsigned char (*slotpk)[512],
                                         float* qsT_raw, int knnBlk) {
    float (*qsT)[8] = (float (*)[8])qsT_raw;
    int tid = threadIdx.x;
    int q0 = (knnBlk & 7) * 1024 + (knnBlk >> 3) * 8;           // XCD swizzle
    int b = q0 >> 10;
    const float* xb = xt + (size_t)b * NN * LDC + off;
    for (int j = tid; j < 2 * C; j += 256) {
        int c = j % C, ph = j / C;
        int pb = (q0 & (NN - 1)) + ph * 4;
        float4 v;
        v.x = xb[(size_t)(pb + 0) * LDC + c];
        v.y = xb[(size_t)(pb + 1) * LDC + c];
        v.z = xb[(size_t)(pb + 2) * LDC + c];
        v.w = xb[(size_t)(pb + 3) * LDC + c];
        *(float4*)&qsT[c][ph * 4] = v;
    }
    __syncthreads();
    int lane = tid & 63, w = tid >> 6;
    int cand0 = w * 256 + 4 * lane;
    const float* xTb = xT + (size_t)b * C * 1024;
    float4 sq4 = *(const float4*)(sqn + b * NN + cand0);
    v2f acc2[4][4];
#pragma unroll
    for (int j = 0; j < 4; j++)
#pragma unroll
        for (int p = 0; p < 4; p++) acc2[j][p] = (v2f){0.f, 0.f};
    for (int cg = 0; cg < C / 4; cg++) {
        float4 rch[4];
#pragma unroll
        for (int c = 0; c < 4; c++)
            rch[c] = *(const float4*)(xTb + (size_t)(4 * cg + c) * 1024 + cand0);
#pragma unroll
        for (int c = 0; c < 4; c++) {
            float4 qa = *(const float4*)&qsT[4 * cg + c][0];
            float4 qb = *(const float4*)&qsT[4 * cg + c][4];
            v2f qp[4] = {{qa.x, qa.y}, {qa.z, qa.w}, {qb.x, qb.y}, {qb.z, qb.w}};
            float rj[4] = {rch[c].x, rch[c].y, rch[c].z, rch[c].w};
#pragma unroll
            for (int j = 0; j < 4; j++) {
                v2f rr = {rj[j], rj[j]};
                acc2[j][0] += rr * qp[0];
                acc2[j][1] += rr * qp[1];
                acc2[j][2] += rr * qp[2];
                acc2[j][3] += rr * qp[3];
            }
        }
    }
#pragma unroll
    for (int p = 0; p < 4; p++)
#pragma unroll
        for (int half = 0; half < 2; half++) {
            int q = 2 * p + half;
            float4 dv;
            dv.x = 2.f * acc2[0][p][half] - sq4.x;
            dv.y = 2.f * acc2[1][p][half] - sq4.y;
            dv.z = 2.f * acc2[2][p][half] - sq4.z;
            dv.w = 2.f * acc2[3][p][half] - sq4.w;
            *(float4*)&dist[q][cand0] = dv;
        }
    __syncthreads();
    select20_srt(dist, slotpk, q0, w, lane, idxout);
}

// ---------------- FAT kernel stages 2-3: knn (blocks<1024) + zgemm (blocks>=1024) ----------------
template<int C, int ZO2>
__global__ __launch_bounds__(256, 4) void knnz_fat(const float* __restrict__ xT,
                                                   const float* __restrict__ xt, int off,
                                                   const float* __restrict__ sqn,
                                                   int* __restrict__ idxout,
                                                   const float* __restrict__ w,
                                                   float* __restrict__ zf,
                                                   float* __restrict__ r1s, float* __restrict__ r1q,
                                                   int Onext) {
    __shared__ float dist[8][1024];
    __shared__ __align__(8) unsigned char slotpk[8][512];
    __shared__ __align__(16) float qsT_raw[C * 8];
    int tid = threadIdx.x;
    if ((int)blockIdx.x < BB * NN / 8) {
        knn_body<C>(xT, xt, off, sqn, idxout, dist, slotpk, qsT_raw, blockIdx.x);
        return;
    }
    // ---- zgemm path ----
    constexpr int ZO = ZO2 / 2;
    int zblk = blockIdx.x - BB * NN / 8;
    if (zblk == 0) zero_r1(r1s, r1q, Onext, tid);
    float (*xs)[C] = (float (*)[C])&dist[0][0];
    int p0 = zblk * 16;
    for (int j = tid; j < 16 * (C / 4); j += 256) {
        int p = j / (C / 4), c4 = j % (C / 4);
        *(float4*)&xs[p][4 * c4] = *(const float4*)(xt + (size_t)(p0 + p) * LDC + off + 4 * c4);
    }
    __syncthreads();
    for (int j = tid; j < ZO2; j += 256) {
        const float* wr = w + (j < ZO ? (size_t)j * 2 * C : (size_t)(j - ZO) * 2 * C + C);
        float acc[16];
#pragma unroll
        for (int p = 0; p < 16; p++) acc[p] = 0.f;
        for (int c4 = 0; c4 < C / 4; c4++) {
            float4 wv = *(const float4*)(wr + 4 * c4);
#pragma unroll
            for (int p = 0; p < 16; p++) {
                float4 xv = *(const float4*)&xs[p][4 * c4];
                acc[p] += wv.x * xv.x + wv.y * xv.y + wv.z * xv.z + wv.w * xv.w;
            }
        }
#pragma unroll
        for (int p = 0; p < 16; p++) zf[(size_t)(p0 + p) * ZO2 + j] = acc[p];
    }
}

// ---------------- stage-4 knn (separate; zeroes r1 for stage 4) ----------------
template<int C>
__global__ __launch_bounds__(256, 4) void knn_fused(const float* __restrict__ xT,
                                                    const float* __restrict__ xt, int off,
                                                    const float* __restrict__ sqn,
                                                    int* __restrict__ idxout,
                                                    float* __restrict__ r1s, float* __restrict__ r1q,
                                                    int Onext) {
    __shared__ float dist[8][1024];
    __shared__ __align__(8) unsigned char slotpk[8][512];
    __shared__ __align__(16) float qsT_raw[C * 8];
    if (blockIdx.x == 0) zero_r1(r1s, r1q, Onext, threadIdx.x);
    knn_body<C>(xT, xt, off, sqn, idxout, dist, slotpk, qsT_raw, blockIdx.x);
}

// ---------------- stage-4 z-gemm: bf16 MFMA, bf16 output ----------------
__global__ __launch_bounds__(256) void zgemm4_mfma(const float* __restrict__ xtcat,
                                                   const float* __restrict__ w4,
                                                   __hip_bfloat16* __restrict__ zf4) {
    __shared__ __hip_bfloat16 A[128][72];
    __shared__ __hip_bfloat16 W[128][72];
    int mt = blockIdx.x >> 2, nt = blockIdx.x & 3;
    int tid = threadIdx.x;
    int lane = tid & 63, wvx = tid >> 6;
    int mw = wvx >> 1, nw = wvx & 1;
    int m0 = lane & 15, qd = lane >> 4;
    int r = tid & 127, hf = tid >> 7;
    facc4 acc[4][4];
    facc4 zz = {0.f, 0.f, 0.f, 0.f};
#pragma unroll
    for (int mi = 0; mi < 4; mi++)
#pragma unroll
        for (int ni = 0; ni < 4; ni++) acc[mi][ni] = zz;
    int j = nt * 128 + r;
    const float* wsrc = w4 + (j < 256 ? (size_t)j * 256 : (size_t)(j - 256) * 256 + 128);
    const float* asrc = xtcat + (size_t)(mt * 128 + r) * 512 + 128;
    for (int kc = 0; kc < 2; kc++) {
#pragma unroll
        for (int u = 0; u < 4; u++) {
            int c0 = kc * 64 + hf * 32 + 8 * u;
            float4 a0 = *(const float4*)(asrc + c0);
            float4 a1 = *(const float4*)(asrc + c0 + 4);
            *(bh8*)&A[r][hf * 32 + 8 * u] = cvt8(a0, a1);
            float4 w0 = *(const float4*)(wsrc + c0);
            float4 w1 = *(const float4*)(wsrc + c0 + 4);
            *(bh8*)&W[r][hf * 32 + 8 * u] = cvt8(w0, w1);
        }
        __syncthreads();
#pragma unroll
        for (int kk = 0; kk < 2; kk++) {
            bfrag8 af[4], bf[4];
#pragma unroll
            for (int mi = 0; mi < 4; mi++)
                af[mi] = *(const bfrag8*)&A[64 * mw + 16 * mi + m0][32 * kk + 8 * qd];
#pragma unroll
            for (int ni = 0; ni < 4; ni++)
                bf[ni] = *(const bfrag8*)&W[64 * nw + 16 * ni + m0][32 * kk + 8 * qd];
#pragma unroll
            for (int mi = 0; mi < 4; mi++)
#pragma unroll
                for (int ni = 0; ni < 4; ni++)
                    acc[mi][ni] = __builtin_amdgcn_mfma_f32_16x16x32_bf16(af[mi], bf[ni], acc[mi][ni], 0, 0, 0);
        }
        __syncthreads();
    }
#pragma unroll
    for (int mi = 0; mi < 4; mi++)
#pragma unroll
        for (int ni = 0; ni < 4; ni++)
#pragma unroll
            for (int rg = 0; rg < 4; rg++) {
                int row = mt * 128 + mw * 64 + mi * 16 + qd * 4 + rg;
                int col = nt * 128 + nw * 64 + ni * 16 + m0;
                zf4[(size_t)row * 512 + col] = __float2bfloat16(acc[mi][ni][rg]);
            }
}

// ---------------- gather + stats (fp32 zf, stages 1-3): in-block reduce + atomics ----------------
template<int O2>
__global__ __launch_bounds__(256) void gatherstats_k(const float* __restrict__ zf,
                                                     const int* __restrict__ idx,
                                                     float* __restrict__ ymax, float* __restrict__ ymin,
                                                     float* __restrict__ r1s, float* __restrict__ r1q) {
    constexpr int O = O2 / 2;
    __shared__ float red_s[4][O], red_q[4][O];
    int wv = threadIdx.x >> 6, lane = threadIdx.x & 63;
    int n = (blockIdx.x & 7) * 1024 + (blockIdx.x >> 3) * 4 + wv;   // XCD swizzle
    int b = n >> 10;
    const float* zbatch = zf + (size_t)b * NN * O2;
    int nb[KNNK];
#pragma unroll
    for (int k = 0; k < KNNK; k++) nb[k] = idx[n * KNNK + k];
#pragma unroll
    for (int ch = 0; ch < O / 64; ch++) {
        int o = ch * 64 + lane;
        float g[KNNK];
#pragma unroll
        for (int k = 0; k < KNNK; k++) g[k] = zbatch[(size_t)nb[k] * O2 + o];
        float mx = -INFINITY, mn = INFINITY, s = 0.f, ss = 0.f;
#pragma unroll
        for (int k = 0; k < KNNK; k++) {
            float v = g[k];
            mx = fmaxf(mx, v); mn = fminf(mn, v); s += v; ss += v * v;
        }
        float zn  = zf[(size_t)n * O2 + o];
        float zbn = zf[(size_t)n * O2 + O + o];
        float d = zbn - zn;
        mx += d; mn += d;
        ss = ss + 2.f * d * s + (float)KNNK * d * d;
        s  = s + (float)KNNK * d;
        ymax[(size_t)n * O + o] = mx;
        ymin[(size_t)n * O + o] = mn;
        red_s[wv][o] = s;
        red_q[wv][o] = ss;
    }
    __syncthreads();
    int bucket = blockIdx.x & 31;
    for (int o = threadIdx.x; o < O; o += 256) {
        float s4 = red_s[0][o] + red_s[1][o] + red_s[2][o] + red_s[3][o];
        float q4 = red_q[0][o] + red_q[1][o] + red_q[2][o] + red_q[3][o];
        atomicAdd(&r1s[(size_t)bucket * O + o], s4);
        atomicAdd(&r1q[(size_t)bucket * O + o], q4);
    }
}

// ---------------- gather + stats, bf16 zf4 (stage 4) ----------------
__global__ __launch_bounds__(256) void gatherstats4_k(const __hip_bfloat16* __restrict__ zf4,
                                                      const int* __restrict__ idx,
                                                      float* __restrict__ ymax, float* __restrict__ ymin,
                                                      float* __restrict__ r1s, float* __restrict__ r1q) {
    __shared__ float red_s[4][256], red_q[4][256];
    int wv = threadIdx.x >> 6, lane = threadIdx.x & 63;
    int n = (blockIdx.x & 7) * 1024 + (blockIdx.x >> 3) * 4 + wv;
    int b = n >> 10;
    const __hip_bfloat16* zbatch = zf4 + (size_t)b * NN * 512;
    int nb[KNNK];
#pragma unroll
    for (int k = 0; k < KNNK; k++) nb[k] = idx[n * KNNK + k];
#pragma unroll
    for (int ch = 0; ch < 4; ch++) {
        int o = ch * 64 + lane;
        float g[KNNK];
#pragma unroll
        for (int k = 0; k < KNNK; k++) g[k] = __bfloat162float(zbatch[(size_t)nb[k] * 512 + o]);
        float mx = -INFINITY, mn = INFINITY, s = 0.f, ss = 0.f;
#pragma unroll
        for (int k = 0; k < KNNK; k++) {
            float v = g[k];
            mx = fmaxf(mx, v); mn = fminf(mn, v); s += v; ss += v * v;
        }
        float zn  = __bfloat162float(zf4[(size_t)n * 512 + o]);
        float zbn = __bfloat162float(zf4[(size_t)n * 512 + 256 + o]);
        float d = zbn - zn;
        mx += d; mn += d;
        ss = ss + 2.f * d * s + (float)KNNK * d * d;
        s  = s + (float)KNNK * d;
        ymax[(size_t)n * 256 + o] = mx;
        ymin[(size_t)n * 256 + o] = mn;
        red_s[wv][o] = s;
        red_q[wv][o] = ss;
    }
    __syncthreads();
    int bucket = blockIdx.x & 31;
    for (int o = threadIdx.x; o < 256; o += 256) {
        float s4 = red_s[0][o] + red_s[1][o] + red_s[2][o] + red_s[3][o];
        float q4 = red_q[0][o] + red_q[1][o] + red_q[2][o] + red_q[3][o];
        atomicAdd(&r1s[(size_t)bucket * 256 + o], s4);
        atomicAdd(&r1q[(size_t)bucket * 256 + o], q4);
    }
}

// ---------------- BN+lrelu epilogue + transpose + |c|^2 + bf16 copy, s/t computed in-block ----------------
template<int O>
__global__ __launch_bounds__(256) void epitrans2_k(const float* __restrict__ ymax, const float* __restrict__ ymin,
                                                   const float* __restrict__ r1s, const float* __restrict__ r1q,
                                                   const float* __restrict__ g, const float* __restrict__ beta,
                                                   double invM,
                                                   float* __restrict__ xtcat, int off_out,
                                                   float* __restrict__ xT, float* __restrict__ sqn,
                                                   __hip_bfloat16* __restrict__ xbf) {
    __shared__ float tile[64][O + 1];
    __shared__ float ssh[O], tth[O];
    int n0 = blockIdx.x * 64;
    int b = n0 >> 10;
    int tid = threadIdx.x;
    for (int o = tid; o < O; o += 256) {
        double sd = 0.0, qd = 0.0;
        for (int r = 0; r < 32; r++) { sd += r1s[(size_t)r * O + o]; qd += r1q[(size_t)r * O + o]; }
        double mean = sd * invM;
        double var = qd * invM - mean * mean;
        float inv = (float)(1.0 / sqrt(var + 1e-5));
        float sc = g[o] * inv;
        ssh[o] = sc;
        tth[o] = beta[o] - (float)mean * sc;
    }
    __syncthreads();
    for (int i = tid; i < 64 * O; i += 256) {
        int nl = i / O;
        int o = i & (O - 1);
        int n = n0 + nl;
        float sc = ssh[o];
        float v = sc >= 0.f ? ymax[(size_t)n * O + o] : ymin[(size_t)n * O + o];
        float y = sc * v + tth[o];
        y = y >= 0.f ? y : 0.2f * y;
        xtcat[(size_t)n * LDC + off_out + o] = y;
        xbf[(size_t)n * LDC + off_out + o] = __float2bfloat16(y);
        tile[nl][o] = y;
    }
    __syncthreads();
    if (tid < 64) {
        float sq = 0.f;
        for (int c = 0; c < O; c++) { float v = tile[tid][c]; sq += v * v; }
        sqn[n0 + tid] = sq;
    }
    int r = tid >> 4, cq = tid & 15;
#pragma unroll
    for (int ct = 0; ct < O / 16; ct++) {
        int c = ct * 16 + r;
        float4 ov;
        ov.x = tile[4 * cq + 0][c];
        ov.y = tile[4 * cq + 1][c];
        ov.z = tile[4 * cq + 2][c];
        ov.w = tile[4 * cq + 3][c];
        *(float4*)(xT + ((size_t)b * O + c) * 1024 + (n0 & (NN - 1)) + 4 * cq) = ov;
    }
}

// ---------------- stage-4 epilogue: s/t in-block, writes xbf ONLY ----------------
__global__ __launch_bounds__(256) void epilogue4_k(const float* __restrict__ ymax, const float* __restrict__ ymin,
                                                   const float* __restrict__ r1s, const float* __restrict__ r1q,
                                                   const float* __restrict__ g, const float* __restrict__ beta,
                                                   double invM,
                                                   __hip_bfloat16* __restrict__ xbf) {
    __shared__ float ssh[256], tth[256];
    int n0 = blockIdx.x * 64;
    int tid = threadIdx.x;
    {
        int o = tid;
        double sd = 0.0, qd = 0.0;
        for (int r = 0; r < 32; r++) { sd += r1s[(size_t)r * 256 + o]; qd += r1q[(size_t)r * 256 + o]; }
        double mean = sd * invM;
        double var = qd * invM - mean * mean;
        float inv = (float)(1.0 / sqrt(var + 1e-5));
        float sc = g[o] * inv;
        ssh[o] = sc;
        tth[o] = beta[o] - (float)mean * sc;
    }
    __syncthreads();
    for (int i = tid; i < 64 * 256; i += 256) {
        int nl = i >> 8;
        int o = i & 255;
        int n = n0 + nl;
        float sc = ssh[o];
        float v = sc >= 0.f ? ymax[(size_t)n * 256 + o] : ymin[(size_t)n * 256 + o];
        float y = sc * v + tth[o];
        y = y >= 0.f ? y : 0.2f * y;
        xbf[(size_t)n * LDC + 256 + o] = __float2bfloat16(y);
    }
}

// ---------------- stage 5: bf16 MFMA GEMM (W staged from fp32 w5) w/ fused stats ----------------
__global__ __launch_bounds__(256) void gemm5_mfma(const __hip_bfloat16* __restrict__ xbf,
                                                  const float* __restrict__ w5,
                                                  float* __restrict__ pmax, float* __restrict__ pmn,
                                                  float* __restrict__ ps, float* __restrict__ pq) {
    __shared__ __hip_bfloat16 A[128][72];
    __shared__ __hip_bfloat16 W[128][72];
    int mt = blockIdx.x >> 2, nt = blockIdx.x & 3;
    int tid = threadIdx.x;
    int lane = tid & 63, wvx = tid >> 6;
    int mw = wvx >> 1, nw = wvx & 1;
    int m0 = lane & 15, qd = lane >> 4;
    int r = tid & 127, hf = tid >> 7;
    facc4 acc[4][4];
    facc4 zz = {0.f, 0.f, 0.f, 0.f};
#pragma unroll
    for (int mi = 0; mi < 4; mi++)
#pragma unroll
        for (int ni = 0; ni < 4; ni++) acc[mi][ni] = zz;
    for (int kc = 0; kc < 8; kc++) {
        const __hip_bfloat16* ap = xbf + (size_t)(mt * 128 + r) * 512 + kc * 64 + hf * 32;
        const float* wp = w5 + (size_t)(nt * 128 + r) * 512 + kc * 64 + hf * 32;
#pragma unroll
        for (int u = 0; u < 4; u++) {
            bh8 av = *(const bh8*)(ap + 8 * u);
            *(bh8*)&A[r][hf * 32 + 8 * u] = av;
            float4 w0 = *(const float4*)(wp + 8 * u);
            float4 w1 = *(const float4*)(wp + 8 * u + 4);
            *(bh8*)&W[r][hf * 32 + 8 * u] = cvt8(w0, w1);
        }
        __syncthreads();
#pragma unroll
        for (int kk = 0; kk < 2; kk++) {
            bfrag8 af[4], bf[4];
#pragma unroll
            for (int mi = 0; mi < 4; mi++)
                af[mi] = *(const bfrag8*)&A[64 * mw + 16 * mi + m0][32 * kk + 8 * qd];
#pragma unroll
            for (int ni = 0; ni < 4; ni++)
                bf[ni] = *(const bfrag8*)&W[64 * nw + 16 * ni + m0][32 * kk + 8 * qd];
#pragma unroll
            for (int mi = 0; mi < 4; mi++)
#pragma unroll
                for (int ni = 0; ni < 4; ni++)
                    acc[mi][ni] = __builtin_amdgcn_mfma_f32_16x16x32_bf16(af[mi], bf[ni], acc[mi][ni], 0, 0, 0);
        }
        __syncthreads();
    }
#pragma unroll
    for (int mi = 0; mi < 4; mi++) {
        int grp = mt * 8 + mw * 4 + mi;
#pragma unroll
        for (int ni = 0; ni < 4; ni++) {
            float mx = -INFINITY, mn = INFINITY, s = 0.f, ss = 0.f;
#pragma unroll
            for (int rg = 0; rg < 4; rg++) {
                float v = acc[mi][ni][rg];
                mx = fmaxf(mx, v); mn = fminf(mn, v); s += v; ss += v * v;
            }
#pragma unroll
            for (int m = 16; m < 64; m <<= 1) {
                mx = fmaxf(mx, __shfl_xor(mx, m));
                mn = fminf(mn, __shfl_xor(mn, m));
                s += __shfl_xor(s, m);
                ss += __shfl_xor(ss, m);
            }
            if (qd == 0) {
                int o = nt * 128 + nw * 64 + ni * 16 + m0;
                pmax[(size_t)grp * 512 + o] = mx;
                pmn [(size_t)grp * 512 + o] = mn;
                ps  [(size_t)grp * 512 + o] = s;
                pq  [(size_t)grp * 512 + o] = ss;
            }
        }
    }
}

// ---------------- per-batch reduce + in-block stage-5 BN stats + feat @ wemb^T ----------------
__global__ __launch_bounds__(256) void featgemm_k(const float* __restrict__ pmax, const float* __restrict__ pmn,
                                                  const float* __restrict__ ps, const float* __restrict__ pq,
                                                  const float* __restrict__ g, const float* __restrict__ beta,
                                                  const float* __restrict__ wemb, float* __restrict__ out) {
    __shared__ __align__(16) float feat[512];
    __shared__ float ssh[512], tth[512];
    int b = blockIdx.x, tid = threadIdx.x;
    // in-block BN stats (deterministic, redundant per block)
#pragma unroll
    for (int h = 0; h < 2; h++) {
        int o = tid + 256 * h;
        double sd = 0.0, qd = 0.0;
        for (int r = 0; r < 512; r++) { sd += ps[(size_t)r * 512 + o]; qd += pq[(size_t)r * 512 + o]; }
        double invM = 1.0 / (BB * NN);
        double mean = sd * invM;
        double var = qd * invM - mean * mean;
        float inv = (float)(1.0 / sqrt(var + 1e-5));
        float sc = g[o] * inv;
        ssh[o] = sc;
        tth[o] = beta[o] - (float)mean * sc;
    }
    __syncthreads();
    for (int o = tid; o < 512; o += 256) {
        float mx = -INFINITY, mn = INFINITY;
        for (int r = b * 64; r < (b + 1) * 64; r++) {
            mx = fmaxf(mx, pmax[(size_t)r * 512 + o]);
            mn = fminf(mn, pmn [(size_t)r * 512 + o]);
        }
        float sc = ssh[o];
        float v = sc >= 0.f ? mx : mn;
        float y = sc * v + tth[o];
        feat[o] = y >= 0.f ? y : 0.2f * y;
    }
    __syncthreads();
    const float4* wr = (const float4*)(wemb + (size_t)tid * 512);
    float acc = 0.f;
    for (int c4 = 0; c4 < 128; c4++) {
        float4 wv = wr[c4];
        float4 fv = *(const float4*)&feat[c4 * 4];
        acc += wv.x * fv.x + wv.y * fv.y + wv.z * fv.z + wv.w * fv.w;
    }
    out[(size_t)b * 256 + tid] = acc;
}

extern "C" void kernel_launch(void* const* d_in, const int* in_sizes, int n_in,
                              void* d_out, int out_size, void* d_ws, size_t ws_size,
                              hipStream_t stream) {
    const float* x    = (const float*)d_in[0];
    const float* w1   = (const float*)d_in[1];
    const float* g1   = (const float*)d_in[2];
    const float* b1   = (const float*)d_in[3];
    const float* w2   = (const float*)d_in[4];
    const float* g2   = (const float*)d_in[5];
    const float* b2   = (const float*)d_in[6];
    const float* w3   = (const float*)d_in[7];
    const float* g3   = (const float*)d_in[8];
    const float* b3   = (const float*)d_in[9];
    const float* w4   = (const float*)d_in[10];
    const float* g4   = (const float*)d_in[11];
    const float* b4   = (const float*)d_in[12];
    const float* w5   = (const float*)d_in[13];
    const float* g5   = (const float*)d_in[14];
    const float* b5   = (const float*)d_in[15];
    const float* wemb = (const float*)d_in[16];
    float* out = (float*)d_out;

    float* fws    = (float*)d_ws;
    float* xtcat  = fws;                                 // 4,194,304
    float* ymax   = xtcat + (size_t)BB * NN * 512;       // 2,097,152
    float* ymin   = ymax + (size_t)BB * NN * 256;        // 2,097,152
    float* psum   = ymin + (size_t)BB * NN * 256;        // 2,097,152 (now only xT alias)
    float* psumsq = psum + (size_t)BB * NN * 256;        // 2,097,152 (spare)
    float* xT     = psum;                                // alias
    float* pmax   = ymax;                                // alias: stage-5 partials
    float* pmn    = pmax + 512 * 512;
    float* ps5    = pmn + 512 * 512;
    float* pq5    = ps5 + 512 * 512;
    float* sqn    = psumsq + (size_t)BB * NN * 256;      // 8192
    float* s_arr  = sqn + BB * NN;                       // 512 (spare)
    float* t_arr  = s_arr + 512;                         // 512 (spare)
    float* r1s    = t_arr + 512;                         // 32*512
    float* r1q    = r1s + 32 * 512;                      // 32*512
    int*   idxb   = (int*)(r1q + 32 * 512);              // 8192*20 ints
    float* zfull  = (float*)(idxb + BB * NN * KNNK);     // 8192*512 fp32 (stages 1-3)
    __hip_bfloat16* zf4 = (__hip_bfloat16*)zfull;        // alias: stage-4 z, bf16
    __hip_bfloat16* xbf = (__hip_bfloat16*)(zfull + (size_t)BB * NN * 512);   // 8192*512 bf16

    const double invM_edge = 1.0 / ((double)BB * NN * KNNK);
    const int nbn = BB * NN;
    const int NK = nbn / 8;       // 1024 knn blocks
    const int NZ = nbn / 16;      // 512 zgemm blocks

    // ---- Stage 1 ----
    knn3_fused<<<NK, 256, 0, stream>>>(x, w1, zfull, idxb, r1s, r1q);
    gatherstats_k<128><<<nbn / 4, 256, 0, stream>>>(zfull, idxb, ymax, ymin, r1s, r1q);
    epitrans2_k<64><<<128, 256, 0, stream>>>(ymax, ymin, r1s, r1q, g1, b1, invM_edge, xtcat, 0, xT, sqn, xbf);

    // ---- Stage 2 ----
    knnz_fat<64, 128><<<NK + NZ, 256, 0, stream>>>(xT, xtcat, 0, sqn, idxb, w2, zfull, r1s, r1q, 64);
    gatherstats_k<128><<<nbn / 4, 256, 0, stream>>>(zfull, idxb, ymax, ymin, r1s, r1q);
    epitrans2_k<64><<<128, 256, 0, stream>>>(ymax, ymin, r1s, r1q, g2, b2, invM_edge, xtcat, 64, xT, sqn, xbf);

    // ---- Stage 3 ----
    knnz_fat<64, 256><<<NK + NZ, 256, 0, stream>>>(xT, xtcat, 64, sqn, idxb, w3, zfull, r1s, r1q, 128);
    gatherstats_k<256><<<nbn / 4, 256, 0, stream>>>(zfull, idxb, ymax, ymin, r1s, r1q);
    epitrans2_k<128><<<128, 256, 0, stream>>>(ymax, ymin, r1s, r1q, g3, b3, invM_edge, xtcat, 128, xT, sqn, xbf);

    // ---- Stage 4 ----
    knn_fused<128><<<NK, 256, 0, stream>>>(xT, xtcat, 128, sqn, idxb, r1s, r1q, 256);
    zgemm4_mfma<<<256, 256, 0, stream>>>(xtcat, w4, zf4);
    gatherstats4_k<<<nbn / 4, 256, 0, stream>>>(zf4, idxb, ymax, ymin, r1s, r1q);
    epilogue4_k<<<128, 256, 0, stream>>>(ymax, ymin, r1s, r1q, g4, b4, invM_edge, xbf);

    // ---- Stage 5 ----
    gemm5_mfma<<<256, 256, 0, stream>>>(xbf, w5, pmax, pmn, ps5, pq5);
    featgemm_k<<<BB, 256, 0, stream>>>(pmax, pmn, ps5, pq5, g5, b5, wemb, out);
}

// Round 14
// 414.839 us; speedup vs baseline: 1.9259x; 1.0517x over previous
//
#include <hip/hip_runtime.h>
#include <hip/hip_bf16.h>
#include <math.h>

#define BB 8
#define NN 1024
#define KNNK 20
#define LDC 512

typedef __attribute__((ext_vector_type(8))) short bfrag8;
typedef __attribute__((ext_vector_type(4))) float facc4;
typedef __attribute__((ext_vector_type(2))) float v2f;

struct bh8 { __hip_bfloat16 h[8]; };

__device__ __forceinline__ bh8 cvt8(float4 a, float4 b) {
    bh8 v;
    v.h[0] = __float2bfloat16(a.x); v.h[1] = __float2bfloat16(a.y);
    v.h[2] = __float2bfloat16(a.z); v.h[3] = __float2bfloat16(a.w);
    v.h[4] = __float2bfloat16(b.x); v.h[5] = __float2bfloat16(b.y);
    v.h[6] = __float2bfloat16(b.z); v.h[7] = __float2bfloat16(b.w);
    return v;
}

// ---------------- top-20 selection: per-lane Batcher sort + head-merge (exact fp32) ----------------
__device__ __forceinline__ void select20_srt(float (*dist)[1024],
                                             unsigned char (*slotpk)[512],
                                             int q0, int w, int lane,
                                             int* __restrict__ idxout) {
    float d[2][16];
    int   sl[2][16];
#pragma unroll
    for (int qi = 0; qi < 2; qi++) {
        int row = w * 2 + qi;
#pragma unroll
        for (int j = 0; j < 16; j++) { d[qi][j] = dist[row][lane + 64 * j]; sl[qi][j] = j; }
    }
    constexpr unsigned char CA[63] = {
        0,2,4,6,8,10,12,14,
        0,1,4,5,8,9,12,13,
        1,5,9,13,
        0,1,2,3,8,9,10,11,
        2,3,10,11,
        1,3,5,9,11,13,
        0,1,2,3,4,5,6,7,
        4,5,6,7,
        2,3,6,7,10,11,
        1,3,5,7,9,11,13};
    constexpr unsigned char CB[63] = {
        1,3,5,7,9,11,13,15,
        2,3,6,7,10,11,14,15,
        2,6,10,14,
        4,5,6,7,12,13,14,15,
        4,5,12,13,
        2,4,6,10,12,14,
        8,9,10,11,12,13,14,15,
        8,9,10,11,
        4,5,8,9,12,13,
        2,4,6,8,10,12,14};
#pragma unroll
    for (int c = 0; c < 63; c++) {
        const int a = CA[c], bq = CB[c];
#pragma unroll
        for (int qi = 0; qi < 2; qi++) {
            bool sw = d[qi][a] < d[qi][bq];
            float dmx = sw ? d[qi][bq] : d[qi][a];
            float dmn = sw ? d[qi][a]  : d[qi][bq];
            d[qi][a] = dmx; d[qi][bq] = dmn;
            int smx = sw ? sl[qi][bq] : sl[qi][a];
            int smn = sw ? sl[qi][a]  : sl[qi][bq];
            sl[qi][a] = smx; sl[qi][bq] = smn;
        }
    }
#pragma unroll
    for (int qi = 0; qi < 2; qi++) {
        int row = w * 2 + qi;
#pragma unroll
        for (int j = 0; j < 16; j++) dist[row][j * 64 + lane] = d[qi][j];
        unsigned int pk0 = 0, pk1 = 0;
#pragma unroll
        for (int j = 0; j < 8; j++) pk0 |= (unsigned)sl[qi][j] << (4 * j);
#pragma unroll
        for (int j = 0; j < 8; j++) pk1 |= (unsigned)sl[qi][8 + j] << (4 * j);
        *(unsigned int*)&slotpk[row][lane * 8]     = pk0;
        *(unsigned int*)&slotpk[row][lane * 8 + 4] = pk1;
    }
    float head[2] = {d[0][0], d[1][0]};
    int ptr[2] = {0, 0};
    for (int t = 0; t < KNNK; t++) {
#pragma unroll
        for (int qi = 0; qi < 2; qi++) {
            int row = w * 2 + qi;
            float bv = head[qi];
#pragma unroll
            for (int s = 1; s < 64; s <<= 1) bv = fmaxf(bv, __shfl_xor(bv, s));
            unsigned long long ball = __ballot(head[qi] == bv);
            int wl = (int)__builtin_ctzll(ball);
            if (lane == wl) {
                int pp = ptr[qi];
                int slot = (slotpk[row][lane * 8 + (pp >> 1)] >> (4 * (pp & 1))) & 15;
                idxout[(q0 + row) * KNNK + t] = slot * 64 + lane;
                pp++;
                ptr[qi] = pp;
                int a = (pp < 16 ? pp : 15) * 64 + lane;
                float nv = dist[row][a];
                head[qi] = (pp < 16) ? nv : -INFINITY;
            }
        }
    }
}

// r1 zeroing helper (done by one designated block of the kernel preceding the gather)
__device__ __forceinline__ void zero_r1(float* r1s, float* r1q, int O, int tid) {
    for (int i = tid; i < 32 * O; i += 256) { r1s[i] = 0.f; r1q[i] = 0.f; }
}

// ---------------- fused kNN stage 1 (C=3) + stage-1 z-gemm, 8 queries/block ----------------
__global__ __launch_bounds__(256, 4) void knn3_fused(const float* __restrict__ x,
                                                     const float* __restrict__ w1,
                                                     float* __restrict__ zf,
                                                     int* __restrict__ idxout,
                                                     float* __restrict__ r1s, float* __restrict__ r1q) {
    __shared__ float dist[8][1024];
    __shared__ __align__(8) unsigned char slotpk[8][512];
    int tid = threadIdx.x;
    int q0 = (blockIdx.x & 7) * 1024 + (blockIdx.x >> 3) * 8;   // XCD swizzle
    int b = q0 >> 10;
    if (blockIdx.x == 0) zero_r1(r1s, r1q, 64, tid);
    const float* xb = x + (size_t)b * NN * 3;
    int lane = tid & 63, w = tid >> 6;
    float qx[8], qy[8], qz[8];
#pragma unroll
    for (int q = 0; q < 8; q++) {
        const float* qr = xb + (size_t)((q0 & (NN - 1)) + q) * 3;
        qx[q] = qr[0]; qy[q] = qr[1]; qz[q] = qr[2];
    }
#pragma unroll
    for (int cq = 0; cq < 4; cq++) {
        int cand = w * 256 + cq * 64 + lane;
        const float* cr = xb + (size_t)cand * 3;
        float cx = cr[0], cy = cr[1], cz = cr[2];
        float sqc = 0.f;
        sqc += cx * cx; sqc += cy * cy; sqc += cz * cz;
#pragma unroll
        for (int q = 0; q < 8; q++) {
            float d = qx[q] * cx + qy[q] * cy + qz[q] * cz;
            dist[q][cand] = 2.f * d - sqc;
        }
    }
    for (int i = tid; i < 8 * 128; i += 256) {
        int lq = i >> 7, j = i & 127;
        const float* wr = w1 + (j < 64 ? j * 6 : (j - 64) * 6 + 3);
        const float* xr = x + (size_t)(q0 + lq) * 3;
        zf[(size_t)(q0 + lq) * 128 + j] = wr[0] * xr[0] + wr[1] * xr[1] + wr[2] * xr[2];
    }
    __syncthreads();
    select20_srt(dist, slotpk, q0, w, lane, idxout);
}

// ---------------- knn core (stages 2-4), packed-fp32 dist + sort-select ----------------
template<int C>
__device__ __forceinline__ void knn_body(const float* __restrict__ xT,
                                         const float* __restrict__ xt, int off,
                                         const float* __restrict__ sqn,
                                         int* __restrict__ idxout,
                                         float (*dist)[1024], unsigned char (*slotpk)[512],
                                         float* qsT_raw, int knnBlk) {
    float (*qsT)[8] = (float (*)[8])qsT_raw;
    int tid = threadIdx.x;
    int q0 = (knnBlk & 7) * 1024 + (knnBlk >> 3) * 8;           // XCD swizzle
    int b = q0 >> 10;
    const float* xb = xt + (size_t)b * NN * LDC + off;
    for (int j = tid; j < 2 * C; j += 256) {
        int c = j % C, ph = j / C;
        int pb = (q0 & (NN - 1)) + ph * 4;
        float4 v;
        v.x = xb[(size_t)(pb + 0) * LDC + c];
        v.y = xb[(size_t)(pb + 1) * LDC + c];
        v.z = xb[(size_t)(pb + 2) * LDC + c];
        v.w = xb[(size_t)(pb + 3) * LDC + c];
        *(float4*)&qsT[c][ph * 4] = v;
    }
    __syncthreads();
    int lane = tid & 63, w = tid >> 6;
    int cand0 = w * 256 + 4 * lane;
    const float* xTb = xT + (size_t)b * C * 1024;
    float4 sq4 = *(const float4*)(sqn + b * NN + cand0);
    v2f acc2[4][4];
#pragma unroll
    for (int j = 0; j < 4; j++)
#pragma unroll
        for (int p = 0; p < 4; p++) acc2[j][p] = (v2f){0.f, 0.f};
    for (int cg = 0; cg < C / 4; cg++) {
        float4 rch[4];
#pragma unroll
        for (int c = 0; c < 4; c++)
            rch[c] = *(const float4*)(xTb + (size_t)(4 * cg + c) * 1024 + cand0);
#pragma unroll
        for (int c = 0; c < 4; c++) {
            float4 qa = *(const float4*)&qsT[4 * cg + c][0];
            float4 qb = *(const float4*)&qsT[4 * cg + c][4];
            v2f qp[4] = {{qa.x, qa.y}, {qa.z, qa.w}, {qb.x, qb.y}, {qb.z, qb.w}};
            float rj[4] = {rch[c].x, rch[c].y, rch[c].z, rch[c].w};
#pragma unroll
            for (int j = 0; j < 4; j++) {
                v2f rr = {rj[j], rj[j]};
                acc2[j][0] += rr * qp[0];
                acc2[j][1] += rr * qp[1];
                acc2[j][2] += rr * qp[2];
                acc2[j][3] += rr * qp[3];
            }
        }
    }
#pragma unroll
    for (int p = 0; p < 4; p++)
#pragma unroll
        for (int half = 0; half < 2; half++) {
            int q = 2 * p + half;
            float4 dv;
            dv.x = 2.f * acc2[0][p][half] - sq4.x;
            dv.y = 2.f * acc2[1][p][half] - sq4.y;
            dv.z = 2.f * acc2[2][p][half] - sq4.z;
            dv.w = 2.f * acc2[3][p][half] - sq4.w;
            *(float4*)&dist[q][cand0] = dv;
        }
    __syncthreads();
    select20_srt(dist, slotpk, q0, w, lane, idxout);
}

// ---------------- FAT kernel stages 2-3: knn (blocks<1024) + zgemm (blocks>=1024) ----------------
template<int C, int ZO2>
__global__ __launch_bounds__(256, 4) void knnz_fat(const float* __restrict__ xT,
                                                   const float* __restrict__ xt, int off,
                                                   const float* __restrict__ sqn,
                                                   int* __restrict__ idxout,
                                                   const float* __restrict__ w,
                                                   float* __restrict__ zf,
                                                   float* __restrict__ r1s, float* __restrict__ r1q,
                                                   int Onext) {
    __shared__ float dist[8][1024];
    __shared__ __align__(8) unsigned char slotpk[8][512];
    __shared__ __align__(16) float qsT_raw[C * 8];
    int tid = threadIdx.x;
    if ((int)blockIdx.x < BB * NN / 8) {
        knn_body<C>(xT, xt, off, sqn, idxout, dist, slotpk, qsT_raw, blockIdx.x);
        return;
    }
    // ---- zgemm path ----
    constexpr int ZO = ZO2 / 2;
    int zblk = blockIdx.x - BB * NN / 8;
    if (zblk == 0) zero_r1(r1s, r1q, Onext, tid);
    float (*xs)[C] = (float (*)[C])&dist[0][0];
    int p0 = zblk * 16;
    for (int j = tid; j < 16 * (C / 4); j += 256) {
        int p = j / (C / 4), c4 = j % (C / 4);
        *(float4*)&xs[p][4 * c4] = *(const float4*)(xt + (size_t)(p0 + p) * LDC + off + 4 * c4);
    }
    __syncthreads();
    for (int j = tid; j < ZO2; j += 256) {
        const float* wr = w + (j < ZO ? (size_t)j * 2 * C : (size_t)(j - ZO) * 2 * C + C);
        float acc[16];
#pragma unroll
        for (int p = 0; p < 16; p++) acc[p] = 0.f;
        for (int c4 = 0; c4 < C / 4; c4++) {
            float4 wv = *(const float4*)(wr + 4 * c4);
#pragma unroll
            for (int p = 0; p < 16; p++) {
                float4 xv = *(const float4*)&xs[p][4 * c4];
                acc[p] += wv.x * xv.x + wv.y * xv.y + wv.z * xv.z + wv.w * xv.w;
            }
        }
#pragma unroll
        for (int p = 0; p < 16; p++) zf[(size_t)(p0 + p) * ZO2 + j] = acc[p];
    }
}

// ---------------- stage-4 knn (separate; zeroes r1 for stage 4) ----------------
template<int C>
__global__ __launch_bounds__(256, 4) void knn_fused(const float* __restrict__ xT,
                                                    const float* __restrict__ xt, int off,
                                                    const float* __restrict__ sqn,
                                                    int* __restrict__ idxout,
                                                    float* __restrict__ r1s, float* __restrict__ r1q,
                                                    int Onext) {
    __shared__ float dist[8][1024];
    __shared__ __align__(8) unsigned char slotpk[8][512];
    __shared__ __align__(16) float qsT_raw[C * 8];
    if (blockIdx.x == 0) zero_r1(r1s, r1q, Onext, threadIdx.x);
    knn_body<C>(xT, xt, off, sqn, idxout, dist, slotpk, qsT_raw, blockIdx.x);
}

// ---------------- stage-4 z-gemm: bf16 MFMA, bf16 output ----------------
__global__ __launch_bounds__(256) void zgemm4_mfma(const float* __restrict__ xtcat,
                                                   const float* __restrict__ w4,
                                                   __hip_bfloat16* __restrict__ zf4) {
    __shared__ __hip_bfloat16 A[128][72];
    __shared__ __hip_bfloat16 W[128][72];
    int mt = blockIdx.x >> 2, nt = blockIdx.x & 3;
    int tid = threadIdx.x;
    int lane = tid & 63, wvx = tid >> 6;
    int mw = wvx >> 1, nw = wvx & 1;
    int m0 = lane & 15, qd = lane >> 4;
    int r = tid & 127, hf = tid >> 7;
    facc4 acc[4][4];
    facc4 zz = {0.f, 0.f, 0.f, 0.f};
#pragma unroll
    for (int mi = 0; mi < 4; mi++)
#pragma unroll
        for (int ni = 0; ni < 4; ni++) acc[mi][ni] = zz;
    int j = nt * 128 + r;
    const float* wsrc = w4 + (j < 256 ? (size_t)j * 256 : (size_t)(j - 256) * 256 + 128);
    const float* asrc = xtcat + (size_t)(mt * 128 + r) * 512 + 128;
    for (int kc = 0; kc < 2; kc++) {
#pragma unroll
        for (int u = 0; u < 4; u++) {
            int c0 = kc * 64 + hf * 32 + 8 * u;
            float4 a0 = *(const float4*)(asrc + c0);
            float4 a1 = *(const float4*)(asrc + c0 + 4);
            *(bh8*)&A[r][hf * 32 + 8 * u] = cvt8(a0, a1);
            float4 w0 = *(const float4*)(wsrc + c0);
            float4 w1 = *(const float4*)(wsrc + c0 + 4);
            *(bh8*)&W[r][hf * 32 + 8 * u] = cvt8(w0, w1);
        }
        __syncthreads();
#pragma unroll
        for (int kk = 0; kk < 2; kk++) {
            bfrag8 af[4], bf[4];
#pragma unroll
            for (int mi = 0; mi < 4; mi++)
                af[mi] = *(const bfrag8*)&A[64 * mw + 16 * mi + m0][32 * kk + 8 * qd];
#pragma unroll
            for (int ni = 0; ni < 4; ni++)
                bf[ni] = *(const bfrag8*)&W[64 * nw + 16 * ni + m0][32 * kk + 8 * qd];
#pragma unroll
            for (int mi = 0; mi < 4; mi++)
#pragma unroll
                for (int ni = 0; ni < 4; ni++)
                    acc[mi][ni] = __builtin_amdgcn_mfma_f32_16x16x32_bf16(af[mi], bf[ni], acc[mi][ni], 0, 0, 0);
        }
        __syncthreads();
    }
#pragma unroll
    for (int mi = 0; mi < 4; mi++)
#pragma unroll
        for (int ni = 0; ni < 4; ni++)
#pragma unroll
            for (int rg = 0; rg < 4; rg++) {
                int row = mt * 128 + mw * 64 + mi * 16 + qd * 4 + rg;
                int col = nt * 128 + nw * 64 + ni * 16 + m0;
                zf4[(size_t)row * 512 + col] = __float2bfloat16(acc[mi][ni][rg]);
            }
}

// ---------------- gather + stats (fp32 zf, stages 1-3): in-block reduce + atomics ----------------
template<int O2>
__global__ __launch_bounds__(256) void gatherstats_k(const float* __restrict__ zf,
                                                     const int* __restrict__ idx,
                                                     float* __restrict__ ymax, float* __restrict__ ymin,
                                                     float* __restrict__ r1s, float* __restrict__ r1q) {
    constexpr int O = O2 / 2;
    __shared__ float red_s[4][O], red_q[4][O];
    int wv = threadIdx.x >> 6, lane = threadIdx.x & 63;
    int n = (blockIdx.x & 7) * 1024 + (blockIdx.x >> 3) * 4 + wv;   // XCD swizzle
    int b = n >> 10;
    const float* zbatch = zf + (size_t)b * NN * O2;
    int nb[KNNK];
#pragma unroll
    for (int k = 0; k < KNNK; k++) nb[k] = idx[n * KNNK + k];
#pragma unroll
    for (int ch = 0; ch < O / 64; ch++) {
        int o = ch * 64 + lane;
        float g[KNNK];
#pragma unroll
        for (int k = 0; k < KNNK; k++) g[k] = zbatch[(size_t)nb[k] * O2 + o];
        float mx = -INFINITY, mn = INFINITY, s = 0.f, ss = 0.f;
#pragma unroll
        for (int k = 0; k < KNNK; k++) {
            float v = g[k];
            mx = fmaxf(mx, v); mn = fminf(mn, v); s += v; ss += v * v;
        }
        float zn  = zf[(size_t)n * O2 + o];
        float zbn = zf[(size_t)n * O2 + O + o];
        float d = zbn - zn;
        mx += d; mn += d;
        ss = ss + 2.f * d * s + (float)KNNK * d * d;
        s  = s + (float)KNNK * d;
        ymax[(size_t)n * O + o] = mx;
        ymin[(size_t)n * O + o] = mn;
        red_s[wv][o] = s;
        red_q[wv][o] = ss;
    }
    __syncthreads();
    int bucket = blockIdx.x & 31;
    for (int o = threadIdx.x; o < O; o += 256) {
        float s4 = red_s[0][o] + red_s[1][o] + red_s[2][o] + red_s[3][o];
        float q4 = red_q[0][o] + red_q[1][o] + red_q[2][o] + red_q[3][o];
        atomicAdd(&r1s[(size_t)bucket * O + o], s4);
        atomicAdd(&r1q[(size_t)bucket * O + o], q4);
    }
}

// ---------------- gather + stats, bf16 zf4 (stage 4) ----------------
__global__ __launch_bounds__(256) void gatherstats4_k(const __hip_bfloat16* __restrict__ zf4,
                                                      const int* __restrict__ idx,
                                                      float* __restrict__ ymax, float* __restrict__ ymin,
                                                      float* __restrict__ r1s, float* __restrict__ r1q) {
    __shared__ float red_s[4][256], red_q[4][256];
    int wv = threadIdx.x >> 6, lane = threadIdx.x & 63;
    int n = (blockIdx.x & 7) * 1024 + (blockIdx.x >> 3) * 4 + wv;
    int b = n >> 10;
    const __hip_bfloat16* zbatch = zf4 + (size_t)b * NN * 512;
    int nb[KNNK];
#pragma unroll
    for (int k = 0; k < KNNK; k++) nb[k] = idx[n * KNNK + k];
#pragma unroll
    for (int ch = 0; ch < 4; ch++) {
        int o = ch * 64 + lane;
        float g[KNNK];
#pragma unroll
        for (int k = 0; k < KNNK; k++) g[k] = __bfloat162float(zbatch[(size_t)nb[k] * 512 + o]);
        float mx = -INFINITY, mn = INFINITY, s = 0.f, ss = 0.f;
#pragma unroll
        for (int k = 0; k < KNNK; k++) {
            float v = g[k];
            mx = fmaxf(mx, v); mn = fminf(mn, v); s += v; ss += v * v;
        }
        float zn  = __bfloat162float(zf4[(size_t)n * 512 + o]);
        float zbn = __bfloat162float(zf4[(size_t)n * 512 + 256 + o]);
        float d = zbn - zn;
        mx += d; mn += d;
        ss = ss + 2.f * d * s + (float)KNNK * d * d;
        s  = s + (float)KNNK * d;
        ymax[(size_t)n * 256 + o] = mx;
        ymin[(size_t)n * 256 + o] = mn;
        red_s[wv][o] = s;
        red_q[wv][o] = ss;
    }
    __syncthreads();
    int bucket = blockIdx.x & 31;
    for (int o = threadIdx.x; o < 256; o += 256) {
        float s4 = red_s[0][o] + red_s[1][o] + red_s[2][o] + red_s[3][o];
        float q4 = red_q[0][o] + red_q[1][o] + red_q[2][o] + red_q[3][o];
        atomicAdd(&r1s[(size_t)bucket * 256 + o], s4);
        atomicAdd(&r1q[(size_t)bucket * 256 + o], q4);
    }
}

// ---------------- BN+lrelu epilogue + transpose + |c|^2 + bf16 copy, s/t computed in-block ----------------
template<int O>
__global__ __launch_bounds__(256) void epitrans2_k(const float* __restrict__ ymax, const float* __restrict__ ymin,
                                                   const float* __restrict__ r1s, const float* __restrict__ r1q,
                                                   const float* __restrict__ g, const float* __restrict__ beta,
                                                   double invM,
                                                   float* __restrict__ xtcat, int off_out,
                                                   float* __restrict__ xT, float* __restrict__ sqn,
                                                   __hip_bfloat16* __restrict__ xbf) {
    __shared__ float tile[64][O + 1];
    __shared__ float ssh[O], tth[O];
    int n0 = blockIdx.x * 64;
    int b = n0 >> 10;
    int tid = threadIdx.x;
    for (int o = tid; o < O; o += 256) {
        double sd = 0.0, qd = 0.0;
        for (int r = 0; r < 32; r++) { sd += r1s[(size_t)r * O + o]; qd += r1q[(size_t)r * O + o]; }
        double mean = sd * invM;
        double var = qd * invM - mean * mean;
        float inv = (float)(1.0 / sqrt(var + 1e-5));
        float sc = g[o] * inv;
        ssh[o] = sc;
        tth[o] = beta[o] - (float)mean * sc;
    }
    __syncthreads();
    for (int i = tid; i < 64 * O; i += 256) {
        int nl = i / O;
        int o = i & (O - 1);
        int n = n0 + nl;
        float sc = ssh[o];
        float v = sc >= 0.f ? ymax[(size_t)n * O + o] : ymin[(size_t)n * O + o];
        float y = sc * v + tth[o];
        y = y >= 0.f ? y : 0.2f * y;
        xtcat[(size_t)n * LDC + off_out + o] = y;
        xbf[(size_t)n * LDC + off_out + o] = __float2bfloat16(y);
        tile[nl][o] = y;
    }
    __syncthreads();
    if (tid < 64) {
        float sq = 0.f;
        for (int c = 0; c < O; c++) { float v = tile[tid][c]; sq += v * v; }
        sqn[n0 + tid] = sq;
    }
    int r = tid >> 4, cq = tid & 15;
#pragma unroll
    for (int ct = 0; ct < O / 16; ct++) {
        int c = ct * 16 + r;
        float4 ov;
        ov.x = tile[4 * cq + 0][c];
        ov.y = tile[4 * cq + 1][c];
        ov.z = tile[4 * cq + 2][c];
        ov.w = tile[4 * cq + 3][c];
        *(float4*)(xT + ((size_t)b * O + c) * 1024 + (n0 & (NN - 1)) + 4 * cq) = ov;
    }
}

// ---------------- stage-4 epilogue: s/t in-block, writes xbf ONLY ----------------
__global__ __launch_bounds__(256) void epilogue4_k(const float* __restrict__ ymax, const float* __restrict__ ymin,
                                                   const float* __restrict__ r1s, const float* __restrict__ r1q,
                                                   const float* __restrict__ g, const float* __restrict__ beta,
                                                   double invM,
                                                   __hip_bfloat16* __restrict__ xbf) {
    __shared__ float ssh[256], tth[256];
    int n0 = blockIdx.x * 64;
    int tid = threadIdx.x;
    {
        int o = tid;
        double sd = 0.0, qd = 0.0;
        for (int r = 0; r < 32; r++) { sd += r1s[(size_t)r * 256 + o]; qd += r1q[(size_t)r * 256 + o]; }
        double mean = sd * invM;
        double var = qd * invM - mean * mean;
        float inv = (float)(1.0 / sqrt(var + 1e-5));
        float sc = g[o] * inv;
        ssh[o] = sc;
        tth[o] = beta[o] - (float)mean * sc;
    }
    __syncthreads();
    for (int i = tid; i < 64 * 256; i += 256) {
        int nl = i >> 8;
        int o = i & 255;
        int n = n0 + nl;
        float sc = ssh[o];
        float v = sc >= 0.f ? ymax[(size_t)n * 256 + o] : ymin[(size_t)n * 256 + o];
        float y = sc * v + tth[o];
        y = y >= 0.f ? y : 0.2f * y;
        xbf[(size_t)n * LDC + 256 + o] = __float2bfloat16(y);
    }
}

// ---------------- stage 5: bf16 MFMA GEMM (W staged from fp32 w5) w/ fused stats ----------------
__global__ __launch_bounds__(256) void gemm5_mfma(const __hip_bfloat16* __restrict__ xbf,
                                                  const float* __restrict__ w5,
                                                  float* __restrict__ pmax, float* __restrict__ pmn,
                                                  float* __restrict__ ps, float* __restrict__ pq) {
    __shared__ __hip_bfloat16 A[128][72];
    __shared__ __hip_bfloat16 W[128][72];
    int mt = blockIdx.x >> 2, nt = blockIdx.x & 3;
    int tid = threadIdx.x;
    int lane = tid & 63, wvx = tid >> 6;
    int mw = wvx >> 1, nw = wvx & 1;
    int m0 = lane & 15, qd = lane >> 4;
    int r = tid & 127, hf = tid >> 7;
    facc4 acc[4][4];
    facc4 zz = {0.f, 0.f, 0.f, 0.f};
#pragma unroll
    for (int mi = 0; mi < 4; mi++)
#pragma unroll
        for (int ni = 0; ni < 4; ni++) acc[mi][ni] = zz;
    for (int kc = 0; kc < 8; kc++) {
        const __hip_bfloat16* ap = xbf + (size_t)(mt * 128 + r) * 512 + kc * 64 + hf * 32;
        const float* wp = w5 + (size_t)(nt * 128 + r) * 512 + kc * 64 + hf * 32;
#pragma unroll
        for (int u = 0; u < 4; u++) {
            bh8 av = *(const bh8*)(ap + 8 * u);
            *(bh8*)&A[r][hf * 32 + 8 * u] = av;
            float4 w0 = *(const float4*)(wp + 8 * u);
            float4 w1 = *(const float4*)(wp + 8 * u + 4);
            *(bh8*)&W[r][hf * 32 + 8 * u] = cvt8(w0, w1);
        }
        __syncthreads();
#pragma unroll
        for (int kk = 0; kk < 2; kk++) {
            bfrag8 af[4], bf[4];
#pragma unroll
            for (int mi = 0; mi < 4; mi++)
                af[mi] = *(const bfrag8*)&A[64 * mw + 16 * mi + m0][32 * kk + 8 * qd];
#pragma unroll
            for (int ni = 0; ni < 4; ni++)
                bf[ni] = *(const bfrag8*)&W[64 * nw + 16 * ni + m0][32 * kk + 8 * qd];
#pragma unroll
            for (int mi = 0; mi < 4; mi++)
#pragma unroll
                for (int ni = 0; ni < 4; ni++)
                    acc[mi][ni] = __builtin_amdgcn_mfma_f32_16x16x32_bf16(af[mi], bf[ni], acc[mi][ni], 0, 0, 0);
        }
        __syncthreads();
    }
#pragma unroll
    for (int mi = 0; mi < 4; mi++) {
        int grp = mt * 8 + mw * 4 + mi;
#pragma unroll
        for (int ni = 0; ni < 4; ni++) {
            float mx = -INFINITY, mn = INFINITY, s = 0.f, ss = 0.f;
#pragma unroll
            for (int rg = 0; rg < 4; rg++) {
                float v = acc[mi][ni][rg];
                mx = fmaxf(mx, v); mn = fminf(mn, v); s += v; ss += v * v;
            }
#pragma unroll
            for (int m = 16; m < 64; m <<= 1) {
                mx = fmaxf(mx, __shfl_xor(mx, m));
                mn = fminf(mn, __shfl_xor(mn, m));
                s += __shfl_xor(s, m);
                ss += __shfl_xor(ss, m);
            }
            if (qd == 0) {
                int o = nt * 128 + nw * 64 + ni * 16 + m0;
                pmax[(size_t)grp * 512 + o] = mx;
                pmn [(size_t)grp * 512 + o] = mn;
                ps  [(size_t)grp * 512 + o] = s;
                pq  [(size_t)grp * 512 + o] = ss;
            }
        }
    }
}

// ---------------- stage-5 BN stats (separate kernel: coalesced 8-block reduce) ----------------
__global__ __launch_bounds__(256) void bnstat5_k(const float* __restrict__ ps, const float* __restrict__ pq,
                                                 const float* __restrict__ g, const float* __restrict__ beta,
                                                 float* __restrict__ s_out, float* __restrict__ t_out) {
    __shared__ double lds_s[4][64], lds_q[4][64];
    int lane = threadIdx.x & 63, wv = threadIdx.x >> 6;
    int o = blockIdx.x * 64 + lane;
    double s = 0.0, q = 0.0;
    for (int r = wv; r < 512; r += 4) {
        s += ps[(size_t)r * 512 + o];
        q += pq[(size_t)r * 512 + o];
    }
    lds_s[wv][lane] = s; lds_q[wv][lane] = q;
    __syncthreads();
    if (wv == 0) {
        s = lds_s[0][lane] + lds_s[1][lane] + lds_s[2][lane] + lds_s[3][lane];
        q = lds_q[0][lane] + lds_q[1][lane] + lds_q[2][lane] + lds_q[3][lane];
        double invM = 1.0 / (BB * NN);
        double mean = s * invM;
        double var = q * invM - mean * mean;
        float inv = (float)(1.0 / sqrt(var + 1e-5));
        float sc = g[o] * inv;
        s_out[o] = sc;
        t_out[o] = beta[o] - (float)mean * sc;
    }
}

// ---------------- per-batch max/min reduce + BN + lrelu + feat @ wemb^T ----------------
__global__ __launch_bounds__(256) void featgemm_k(const float* __restrict__ pmax, const float* __restrict__ pmn,
                                                  const float* __restrict__ s, const float* __restrict__ t,
                                                  const float* __restrict__ wemb, float* __restrict__ out) {
    __shared__ __align__(16) float feat[512];
    int b = blockIdx.x, tid = threadIdx.x;
    for (int o = tid; o < 512; o += 256) {
        float mx = -INFINITY, mn = INFINITY;
        for (int r = b * 64; r < (b + 1) * 64; r++) {
            mx = fmaxf(mx, pmax[(size_t)r * 512 + o]);
            mn = fminf(mn, pmn [(size_t)r * 512 + o]);
        }
        float sc = s[o];
        float v = sc >= 0.f ? mx : mn;
        float y = sc * v + t[o];
        feat[o] = y >= 0.f ? y : 0.2f * y;
    }
    __syncthreads();
    const float4* wr = (const float4*)(wemb + (size_t)tid * 512);
    float acc = 0.f;
    for (int c4 = 0; c4 < 128; c4++) {
        float4 wv = wr[c4];
        float4 fv = *(const float4*)&feat[c4 * 4];
        acc += wv.x * fv.x + wv.y * fv.y + wv.z * fv.z + wv.w * fv.w;
    }
    out[(size_t)b * 256 + tid] = acc;
}

extern "C" void kernel_launch(void* const* d_in, const int* in_sizes, int n_in,
                              void* d_out, int out_size, void* d_ws, size_t ws_size,
                              hipStream_t stream) {
    const float* x    = (const float*)d_in[0];
    const float* w1   = (const float*)d_in[1];
    const float* g1   = (const float*)d_in[2];
    const float* b1   = (const float*)d_in[3];
    const float* w2   = (const float*)d_in[4];
    const float* g2   = (const float*)d_in[5];
    const float* b2   = (const float*)d_in[6];
    const float* w3   = (const float*)d_in[7];
    const float* g3   = (const float*)d_in[8];
    const float* b3   = (const float*)d_in[9];
    const float* w4   = (const float*)d_in[10];
    const float* g4   = (const float*)d_in[11];
    const float* b4   = (const float*)d_in[12];
    const float* w5   = (const float*)d_in[13];
    const float* g5   = (const float*)d_in[14];
    const float* b5   = (const float*)d_in[15];
    const float* wemb = (const float*)d_in[16];
    float* out = (float*)d_out;

    float* fws    = (float*)d_ws;
    float* xtcat  = fws;                                 // 4,194,304
    float* ymax   = xtcat + (size_t)BB * NN * 512;       // 2,097,152
    float* ymin   = ymax + (size_t)BB * NN * 256;        // 2,097,152
    float* psum   = ymin + (size_t)BB * NN * 256;        // 2,097,152 (xT alias)
    float* psumsq = psum + (size_t)BB * NN * 256;        // 2,097,152 (spare)
    float* xT     = psum;                                // alias
    float* pmax   = ymax;                                // alias: stage-5 partials
    float* pmn    = pmax + 512 * 512;
    float* ps5    = pmn + 512 * 512;
    float* pq5    = ps5 + 512 * 512;
    float* sqn    = psumsq + (size_t)BB * NN * 256;      // 8192
    float* s_arr  = sqn + BB * NN;                       // 512
    float* t_arr  = s_arr + 512;                         // 512
    float* r1s    = t_arr + 512;                         // 32*512
    float* r1q    = r1s + 32 * 512;                      // 32*512
    int*   idxb   = (int*)(r1q + 32 * 512);              // 8192*20 ints
    float* zfull  = (float*)(idxb + BB * NN * KNNK);     // 8192*512 fp32 (stages 1-3)
    __hip_bfloat16* zf4 = (__hip_bfloat16*)zfull;        // alias: stage-4 z, bf16
    __hip_bfloat16* xbf = (__hip_bfloat16*)(zfull + (size_t)BB * NN * 512);   // 8192*512 bf16

    const double invM_edge = 1.0 / ((double)BB * NN * KNNK);
    const int nbn = BB * NN;
    const int NK = nbn / 8;       // 1024 knn blocks
    const int NZ = nbn / 16;      // 512 zgemm blocks

    // ---- Stage 1 ----
    knn3_fused<<<NK, 256, 0, stream>>>(x, w1, zfull, idxb, r1s, r1q);
    gatherstats_k<128><<<nbn / 4, 256, 0, stream>>>(zfull, idxb, ymax, ymin, r1s, r1q);
    epitrans2_k<64><<<128, 256, 0, stream>>>(ymax, ymin, r1s, r1q, g1, b1, invM_edge, xtcat, 0, xT, sqn, xbf);

    // ---- Stage 2 ----
    knnz_fat<64, 128><<<NK + NZ, 256, 0, stream>>>(xT, xtcat, 0, sqn, idxb, w2, zfull, r1s, r1q, 64);
    gatherstats_k<128><<<nbn / 4, 256, 0, stream>>>(zfull, idxb, ymax, ymin, r1s, r1q);
    epitrans2_k<64><<<128, 256, 0, stream>>>(ymax, ymin, r1s, r1q, g2, b2, invM_edge, xtcat, 64, xT, sqn, xbf);

    // ---- Stage 3 ----
    knnz_fat<64, 256><<<NK + NZ, 256, 0, stream>>>(xT, xtcat, 64, sqn, idxb, w3, zfull, r1s, r1q, 128);
    gatherstats_k<256><<<nbn / 4, 256, 0, stream>>>(zfull, idxb, ymax, ymin, r1s, r1q);
    epitrans2_k<128><<<128, 256, 0, stream>>>(ymax, ymin, r1s, r1q, g3, b3, invM_edge, xtcat, 128, xT, sqn, xbf);

    // ---- Stage 4 ----
    knn_fused<128><<<NK, 256, 0, stream>>>(xT, xtcat, 128, sqn, idxb, r1s, r1q, 256);
    zgemm4_mfma<<<256, 256, 0, stream>>>(xtcat, w4, zf4);
    gatherstats4_k<<<nbn / 4, 256, 0, stream>>>(zf4, idxb, ymax, ymin, r1s, r1q);
    epilogue4_k<<<128, 256, 0, stream>>>(ymax, ymin, r1s, r1q, g4, b4, invM_edge, xbf);

    // ---- Stage 5 ----
    gemm5_mfma<<<256, 256, 0, stream>>>(xbf, w5, pmax, pmn, ps5, pq5);
    bnstat5_k<<<8, 256, 0, stream>>>(ps5, pq5, g5, b5, s_arr, t_arr);
    featgemm_k<<<BB, 256, 0, stream>>>(pmax, pmn, s_arr, t_arr, wemb, out);
}